// Round 5
// baseline (1120.551 us; speedup 1.0000x reference)
//
#include <hip/hip_runtime.h>
#include <hip/hip_bf16.h>
#include <math.h>

// Problem constants
#define TT 1024
#define DIM 1024
#define HH 8
#define QLR 768
#define KVLR 512
#define DNOPE 128
#define DROPE 64
#define DV 128
#define DK 192            // DNOPE + DROPE
#define HDK (HH*DK)       // 1536
#define HKV (HH*(DNOPE+DV)) // 2048
#define TB 16             // scan tile (timesteps per LDS buffer)

// ---------------------------------------------------------------------------
// f32 GEMM: C = A(MxK) @ B(KxN), row-major. 128x128 tile, 8x8 acc/thread.
// Requires M%128==0, K%16==0, N%8==0 (N may be non-multiple of 128: B-loads
// and C-stores are predicated per float4 group).
// LDS: As[m][k] (A staged untransposed, read as float4 along k),
//      Bs[k][n] (natural), 16 KB total -> 2+ blocks/CU possible.
// ---------------------------------------------------------------------------
__global__ __launch_bounds__(256, 2) void gemm128(
    const float* __restrict__ A, const float* __restrict__ B,
    float* __restrict__ C, int M, int N, int K)
{
    __shared__ float As[128][16];
    __shared__ float Bs[16][128];
    const int tid = threadIdx.x;
    const int bm = blockIdx.y * 128, bn = blockIdx.x * 128;
    const int tm = tid >> 4, tn = tid & 15;       // 16x16 thread grid
    const int ar = tid >> 1, ak8 = (tid & 1) * 8; // A loader: 2 float4 along k
    const int bk = tid >> 4, bc8 = (tid & 15) * 8;// B loader: 2 float4 along n
    const bool bvalid = (bn + bc8) < N;           // N%8==0 -> all-or-nothing

    float acc[8][8];
#pragma unroll
    for (int i = 0; i < 8; i++)
#pragma unroll
        for (int j = 0; j < 8; j++) acc[i][j] = 0.f;

    float4 av0, av1, bv0, bv1;
    const float4 z4 = make_float4(0.f, 0.f, 0.f, 0.f);

    // prologue: load tile 0 into regs
    av0 = *(const float4*)&A[(size_t)(bm + ar) * K + 0 + ak8];
    av1 = *(const float4*)&A[(size_t)(bm + ar) * K + 0 + ak8 + 4];
    bv0 = bvalid ? *(const float4*)&B[(size_t)(0 + bk) * N + bn + bc8]     : z4;
    bv1 = bvalid ? *(const float4*)&B[(size_t)(0 + bk) * N + bn + bc8 + 4] : z4;

    for (int k0 = 0;; k0 += 16) {
        __syncthreads();
        *(float4*)&As[ar][ak8]     = av0;
        *(float4*)&As[ar][ak8 + 4] = av1;
        *(float4*)&Bs[bk][bc8]     = bv0;
        *(float4*)&Bs[bk][bc8 + 4] = bv1;
        __syncthreads();

        const bool more = (k0 + 16) < K;
        if (more) {
            const int kn = k0 + 16;
            av0 = *(const float4*)&A[(size_t)(bm + ar) * K + kn + ak8];
            av1 = *(const float4*)&A[(size_t)(bm + ar) * K + kn + ak8 + 4];
            bv0 = bvalid ? *(const float4*)&B[(size_t)(kn + bk) * N + bn + bc8]     : z4;
            bv1 = bvalid ? *(const float4*)&B[(size_t)(kn + bk) * N + bn + bc8 + 4] : z4;
        }

        // compute on staged tile: 4 groups of 4 k
#pragma unroll
        for (int g = 0; g < 4; g++) {
            float4 aR[8];
#pragma unroll
            for (int i = 0; i < 8; i++) {
                const int row = (i < 4) ? (tm * 4 + i) : (64 + tm * 4 + (i - 4));
                aR[i] = *(const float4*)&As[row][g * 4];
            }
#pragma unroll
            for (int kk = 0; kk < 4; kk++) {
                float4 b0 = *(const float4*)&Bs[g * 4 + kk][tn * 4];
                float4 b1 = *(const float4*)&Bs[g * 4 + kk][tn * 4 + 64];
                float bb[8] = {b0.x, b0.y, b0.z, b0.w, b1.x, b1.y, b1.z, b1.w};
#pragma unroll
                for (int i = 0; i < 8; i++) {
                    const float a = (kk == 0) ? aR[i].x : (kk == 1) ? aR[i].y
                                   : (kk == 2) ? aR[i].z : aR[i].w;
#pragma unroll
                    for (int j = 0; j < 8; j++)
                        acc[i][j] = fmaf(a, bb[j], acc[i][j]);
                }
            }
        }
        if (!more) break;
    }

    // epilogue: predicated stores (N%4==0)
#pragma unroll
    for (int i = 0; i < 8; i++) {
        const int row = bm + ((i < 4) ? (tm * 4 + i) : (64 + tm * 4 + (i - 4)));
        const int c0 = bn + tn * 4, c1 = bn + tn * 4 + 64;
        if (c0 < N) {
            float4 v = make_float4(acc[i][0], acc[i][1], acc[i][2], acc[i][3]);
            *(float4*)&C[(size_t)row * N + c0] = v;
        }
        if (c1 < N) {
            float4 v = make_float4(acc[i][4], acc[i][5], acc[i][6], acc[i][7]);
            *(float4*)&C[(size_t)row * N + c1] = v;
        }
    }
}

// ---------------------------------------------------------------------------
// RMSNorm rows (in-place safe: barrier between read and write phases)
// ---------------------------------------------------------------------------
__global__ __launch_bounds__(256) void rmsnorm_rows(
    const float* __restrict__ in, int in_stride, const float* __restrict__ w,
    float* __restrict__ out, int out_stride, int ncols, float inv_n)
{
    const int t = blockIdx.x;
    const int tid = threadIdx.x;
    const float* row = in + (size_t)t * in_stride;
    float ss = 0.f;
    for (int c = tid; c < ncols; c += 256) { float v = row[c]; ss += v * v; }
#pragma unroll
    for (int m = 1; m < 64; m <<= 1) ss += __shfl_xor(ss, m);
    __shared__ float red[4];
    if ((tid & 63) == 0) red[tid >> 6] = ss;
    __syncthreads();
    float tot = red[0] + red[1] + red[2] + red[3];
    float scale = rsqrtf(tot * inv_n + 1e-5f);
    for (int c = tid; c < ncols; c += 256)
        out[(size_t)t * out_stride + c] = row[c] * scale * w[c];
}

// ---------------------------------------------------------------------------
// decay = sigmoid(gpre + bias[col]) written HEAD-MAJOR: a_h[h][t][192]
// ---------------------------------------------------------------------------
__global__ __launch_bounds__(256) void sigmoid_relayout(
    const float* __restrict__ g, const float* __restrict__ bias,
    float* __restrict__ a_h)
{
    int i = blockIdx.x * 256 + threadIdx.x;   // < TT*HDK
    int t = i / HDK, col = i - t * HDK;
    int h = col / DK, d = col - h * DK;
    float z = g[i] + bias[col];
    a_h[((size_t)h * TT + t) * DK + d] = 1.f / (1.f + expf(-z));
}

// ---------------------------------------------------------------------------
// beta[t,h] = sigmoid(x . wb[:,h]); stores both [t][8] and head-major [h][t]
// ---------------------------------------------------------------------------
__global__ __launch_bounds__(256) void beta_kernel(
    const float* __restrict__ x, const float* __restrict__ wb,
    float* __restrict__ beta, float* __restrict__ beta_h)
{
    const int lane = threadIdx.x & 63, wv = threadIdx.x >> 6;
    const int p = blockIdx.x * 4 + wv;        // p = t*8 + h
    const int t = p >> 3, h = p & 7;
    const float* xr = x + (size_t)t * DIM;
    float s = 0.f;
    for (int e = lane; e < DIM; e += 64) s += xr[e] * wb[e * HH + h];
#pragma unroll
    for (int m = 1; m < 64; m <<= 1) s += __shfl_xor(s, m);
    if (lane == 0) {
        float r = 1.f / (1.f + expf(-s));
        beta[p] = r;
        beta_h[(size_t)h * TT + t] = r;
    }
}

// ---------------------------------------------------------------------------
// l2norm(q)*DK^-0.5 and build+l2norm k; outputs HEAD-MAJOR [h][t][192].
// ---------------------------------------------------------------------------
__global__ __launch_bounds__(256) void prep_qk(
    const float* __restrict__ qraw, const float* __restrict__ kvb,
    const float* __restrict__ kv_all, float* __restrict__ q_h,
    float* __restrict__ k_h)
{
    const int lane = threadIdx.x & 63, wv = threadIdx.x >> 6;
    const int p = blockIdx.x * 4 + wv;
    const int t = p >> 3, h = p & 7;

    const float* qrow = qraw + (size_t)t * HDK + h * DK;
    float q0 = qrow[lane], q1 = qrow[lane + 64], q2 = qrow[lane + 128];
    float ss = q0 * q0 + q1 * q1 + q2 * q2;
#pragma unroll
    for (int m = 1; m < 64; m <<= 1) ss += __shfl_xor(ss, m);
    float sc = rsqrtf(ss + 1e-6f) * 0.07216878364870323f;  // * DK^-0.5
    float* qo = q_h + ((size_t)h * TT + t) * DK;
    qo[lane] = q0 * sc; qo[lane + 64] = q1 * sc; qo[lane + 128] = q2 * sc;

    const float* knope = kvb + (size_t)t * HKV + h * (DNOPE + DV);
    float k0 = knope[lane], k1 = knope[lane + 64];
    float k2 = kv_all[(size_t)t * (KVLR + DROPE) + KVLR + lane];
    float ks = k0 * k0 + k1 * k1 + k2 * k2;
#pragma unroll
    for (int m = 1; m < 64; m <<= 1) ks += __shfl_xor(ks, m);
    float kc = rsqrtf(ks + 1e-6f);
    float* ko = k_h + ((size_t)h * TT + t) * DK;
    ko[lane] = k0 * kc; ko[lane + 64] = k1 * kc; ko[lane + 128] = k2 * kc;
}

// ---------------------------------------------------------------------------
// Transpose v: kvb[t][h*256+128+c] -> v_h[h][c][t]
// ---------------------------------------------------------------------------
__global__ __launch_bounds__(256) void vtrans(
    const float* __restrict__ kvb, float* __restrict__ v_h)
{
    __shared__ float ld[128][129];
    const int h = blockIdx.x >> 3, tb = (blockIdx.x & 7) * 128;
    const int tid = threadIdx.x;
    for (int it = 0; it < 64; it++) {
        int tl = it * 2 + (tid >> 7);
        int c  = tid & 127;
        ld[tl][c] = kvb[(size_t)(tb + tl) * HKV + h * (DNOPE + DV) + DNOPE + c];
    }
    __syncthreads();
    for (int it = 0; it < 64; it++) {
        int c  = it * 2 + (tid >> 7);
        int tl = tid & 127;
        v_h[((size_t)h * DV + c) * TT + tb + tl] = ld[tl][c];
    }
}

// ---------------------------------------------------------------------------
// Input-only scalars (premultiplied by beta_t), head-major [h][t]:
//   d2_h = b_t sum_d k_t a_t k_{t-1};  r2_h = b_t sum_d k_t a_t a_{t-1} k_{t-2}
// ---------------------------------------------------------------------------
__global__ __launch_bounds__(256) void prep_scalars(
    const float* __restrict__ k_h, const float* __restrict__ a_h,
    const float* __restrict__ beta, float* __restrict__ d2_h,
    float* __restrict__ r2_h)
{
    const int lane = threadIdx.x & 63, wv = threadIdx.x >> 6;
    const int p = blockIdx.x * 4 + wv;        // p = t*8 + h
    const int t = p >> 3, h = p & 7;
    const size_t rb = ((size_t)h * TT + t) * DK;
    const float b = beta[p];

    float pd = 0.f, pr = 0.f;
#pragma unroll
    for (int j = 0; j < 3; j++) {
        const int d = lane + j * 64;
        float k0 = k_h[rb + d], a0 = a_h[rb + d];
        float k1 = (t >= 1) ? k_h[rb - DK + d] : 0.f;
        float a1 = (t >= 1) ? a_h[rb - DK + d] : 1.f;
        float k2 = (t >= 2) ? k_h[rb - 2 * DK + d] : 0.f;
        float ka = k0 * a0;
        pd += ka * k1;
        pr += ka * a1 * k2;
    }
#pragma unroll
    for (int m = 1; m < 64; m <<= 1) { pd += __shfl_xor(pd, m); pr += __shfl_xor(pr, m); }
    if (lane == 0) {
        d2_h[(size_t)h * TT + t] = b * pd;
        r2_h[(size_t)h * TT + t] = b * pr;
    }
}

// ---------------------------------------------------------------------------
// 32-lane sum reduction: 4 DPP stages + 1 ds_swizzle xor16 (validated R2).
// ---------------------------------------------------------------------------
__device__ __forceinline__ float red32(float x) {
    x += __int_as_float(__builtin_amdgcn_update_dpp(0, __float_as_int(x), 0xB1, 0xF, 0xF, false));
    x += __int_as_float(__builtin_amdgcn_update_dpp(0, __float_as_int(x), 0x4E, 0xF, 0xF, false));
    x += __int_as_float(__builtin_amdgcn_update_dpp(0, __float_as_int(x), 0x141, 0xF, 0xF, false));
    x += __int_as_float(__builtin_amdgcn_update_dpp(0, __float_as_int(x), 0x140, 0xF, 0xF, false));
    x += __int_as_float(__builtin_amdgcn_ds_swizzle(__float_as_int(x), 0x401F));
    return x;
}

// async global->LDS (width 16 / 4). LDS dest = uniform base + lane*size.
__device__ __forceinline__ void gl_lds16(const float* g, float* l) {
    __builtin_amdgcn_global_load_lds(
        (const __attribute__((address_space(1))) void*)g,
        (__attribute__((address_space(3))) void*)l, 16, 0, 0);
}
__device__ __forceinline__ void gl_lds4(const float* g, float* l) {
    __builtin_amdgcn_global_load_lds(
        (const __attribute__((address_space(1))) void*)g,
        (__attribute__((address_space(3))) void*)l, 4, 0, 0);
}

// ---------------------------------------------------------------------------
// KDA scan v4 (unchanged from R4): LDS double-buffered tiles, 32 lanes/col.
// ---------------------------------------------------------------------------
__global__ __launch_bounds__(256) void kda_scan4(
    const float* __restrict__ q_h, const float* __restrict__ k_h,
    const float* __restrict__ a_h, const float* __restrict__ v_h,
    const float* __restrict__ beta_h, const float* __restrict__ d2_h,
    const float* __restrict__ r2_h, float* __restrict__ o)
{
    __shared__ __align__(16) float Kt[2][TB][192];
    __shared__ __align__(16) float At[2][TB][192];
    __shared__ __align__(16) float Qt[2][TB][192];
    __shared__ __align__(16) float Vt[2][8][TB];
    __shared__ __align__(16) float St[2][3][TB];   // b, d2, r2

    const int tid = threadIdx.x;
    const int w = tid >> 6, lane = tid & 63;
    const int sub = lane >> 5, l = lane & 31;
    const int h = blockIdx.x >> 4, cg = blockIdx.x & 15;
    const int cb = w * 2 + sub;                  // column within block 0..7
    const int d4 = l * 4, dlo = 128 + l * 2;     // this lane's dims

    const float* kg = k_h + (size_t)h * TT * DK;
    const float* ag = a_h + (size_t)h * TT * DK;
    const float* qg = q_h + (size_t)h * TT * DK;
    const float* vg = v_h + ((size_t)h * DV + cg * 8) * TT;
    const float* bg = beta_h + (size_t)h * TT;
    const float* dg = d2_h + (size_t)h * TT;
    const float* rg = r2_h + (size_t)h * TT;
    float* op = o + (size_t)h * DV + cg * 8 + cb;

    auto stage = [&](int buf, int n) {
        const size_t toff = (size_t)n * TB * DK;
        if (w == 0) {
            const float* g = kg + toff; float* lb = &Kt[buf][0][0];
#pragma unroll
            for (int i = 0; i < 12; i++) gl_lds16(g + i * 256 + lane * 4, lb + i * 256);
        } else if (w == 1) {
            const float* g = ag + toff; float* lb = &At[buf][0][0];
#pragma unroll
            for (int i = 0; i < 12; i++) gl_lds16(g + i * 256 + lane * 4, lb + i * 256);
        } else if (w == 2) {
            const float* g = qg + toff; float* lb = &Qt[buf][0][0];
#pragma unroll
            for (int i = 0; i < 12; i++) gl_lds16(g + i * 256 + lane * 4, lb + i * 256);
        } else {
            if (lane < 32) {   // V: 8 cols x 16 t = 512 B; lane -> base + lane*16
                const float* g = vg + (size_t)(lane >> 2) * TT + n * TB + (lane & 3) * 4;
                gl_lds16(g, &Vt[buf][0][0]);
            }
            if (lane < 48) {   // St: 3 x 16 floats; lane -> base + lane*4
                const int which = lane >> 4, tt = lane & 15;
                const float* g = (which == 0 ? bg : which == 1 ? dg : rg) + n * TB + tt;
                gl_lds4(g, &St[buf][0][0]);
            }
        }
    };

    float sd[6], kp1[6], kp2[6], qpv[6], apv[6];
#pragma unroll
    for (int j = 0; j < 6; j++) { sd[j] = 0.f; kp1[j] = 0.f; kp2[j] = 0.f; qpv[j] = 0.f; apv[j] = 1.f; }
    float u1 = 0.f, u2 = 0.f;

    stage(0, 0);
    stage(1, 1);

    for (int n = 0; n < TT / TB; n++) {
        const int buf = n & 1;
        __syncthreads();   // own-wave vmcnt drained -> buf's tile is resident
#pragma unroll 4
        for (int tt = 0; tt < TB; tt++) {
            const int t = n * TB + tt;
            const float* Kr = &Kt[buf][tt][0];
            const float* Ar = &At[buf][tt][0];
            const float* Qr = &Qt[buf][tt][0];
            float kc[6], ac[6], qc[6];
            { float4 f = *(const float4*)(Kr + d4); kc[0]=f.x; kc[1]=f.y; kc[2]=f.z; kc[3]=f.w;
              float2 g2 = *(const float2*)(Kr + dlo); kc[4]=g2.x; kc[5]=g2.y; }
            { float4 f = *(const float4*)(Ar + d4); ac[0]=f.x; ac[1]=f.y; ac[2]=f.z; ac[3]=f.w;
              float2 g2 = *(const float2*)(Ar + dlo); ac[4]=g2.x; ac[5]=g2.y; }
            { float4 f = *(const float4*)(Qr + d4); qc[0]=f.x; qc[1]=f.y; qc[2]=f.z; qc[3]=f.w;
              float2 g2 = *(const float2*)(Qr + dlo); qc[4]=g2.x; qc[5]=g2.y; }
            const float vc  = Vt[buf][cb][tt];
            const float bS  = St[buf][0][tt];
            const float d2S = St[buf][1][tt];
            const float r2S = St[buf][2][tt];

            // r1 = red32( sum_j k a a_prev * sd )
            float p0 = 0.f, p1 = 0.f;
#pragma unroll
            for (int j = 0; j < 6; j++) {
                float kaa = kc[j] * ac[j] * apv[j];
                if (j & 1) p1 = fmaf(kaa, sd[j], p1); else p0 = fmaf(kaa, sd[j], p0);
            }
            float r1 = red32(p0 + p1);

            float ut = bS * vc - bS * r1 - u2 * r2S - u1 * d2S;

            // sd -> S~_{t-1}
#pragma unroll
            for (int j = 0; j < 6; j++)
                sd[j] = apv[j] * fmaf(u2, kp2[j], sd[j]);

            // o_{t-1}
            float o0 = 0.f, o1 = 0.f;
#pragma unroll
            for (int j = 0; j < 6; j++) {
                float tmp = fmaf(u1, kp1[j], sd[j]);
                if (j & 1) o1 = fmaf(qpv[j], tmp, o1); else o0 = fmaf(qpv[j], tmp, o0);
            }
            float ov = red32(o0 + o1);
            if (isnan(ov)) ov = 0.f;
            else if (isinf(ov)) ov = ov > 0.f ? 1e4f : -1e4f;
            if (l == 0 && t > 0) op[(size_t)(t - 1) * (HH * DV)] = ov;

            // rotate registers
#pragma unroll
            for (int j = 0; j < 6; j++) {
                kp2[j] = kp1[j]; kp1[j] = kc[j]; qpv[j] = qc[j]; apv[j] = ac[j];
            }
            u2 = u1; u1 = ut;
        }
        __syncthreads();   // all waves done reading buf
        if (n + 2 < TT / TB) stage(buf, n + 2);
    }

    // epilogue: o_{TT-1}
    {
#pragma unroll
        for (int j = 0; j < 6; j++)
            sd[j] = apv[j] * fmaf(u2, kp2[j], sd[j]);
        float o0 = 0.f, o1 = 0.f;
#pragma unroll
        for (int j = 0; j < 6; j++) {
            float tmp = fmaf(u1, kp1[j], sd[j]);
            if (j & 1) o1 = fmaf(qpv[j], tmp, o1); else o0 = fmaf(qpv[j], tmp, o0);
        }
        float ov = red32(o0 + o1);
        if (isnan(ov)) ov = 0.f;
        else if (isinf(ov)) ov = ov > 0.f ? 1e4f : -1e4f;
        if (l == 0) op[(size_t)(TT - 1) * (HH * DV)] = ov;
    }
}

// ---------------------------------------------------------------------------
extern "C" void kernel_launch(void* const* d_in, const int* in_sizes, int n_in,
                              void* d_out, int out_size, void* d_ws, size_t ws_size,
                              hipStream_t stream)
{
    const float* x         = (const float*)d_in[0];
    // d_in[1] = cos, d_in[2] = sin : unused by the reference
    const float* wq_a      = (const float*)d_in[3];
    const float* q_norm_w  = (const float*)d_in[4];
    const float* wq_b      = (const float*)d_in[5];
    const float* wkv_a     = (const float*)d_in[6];
    const float* kv_norm_w = (const float*)d_in[7];
    const float* wkv_b     = (const float*)d_in[8];
    const float* wg_w      = (const float*)d_in[9];
    const float* wg_b      = (const float*)d_in[10];
    const float* wb        = (const float*)d_in[11];
    const float* wo        = (const float*)d_in[12];
    float* out = (float*)d_out;

    float* ws = (float*)d_ws;
    float* xq     = ws;                        // T x 768 (rms in-place)
    float* kv_all = xq     + TT * QLR;         // T x 576
    float* kvn    = kv_all + TT * (KVLR + DROPE); // T x 512
    float* agraw  = kvn    + TT * KVLR;        // T x 1536 (dead after sigmoid)
    float* ob     = agraw;                     // alias: T x 1024 (scan output)
    float* qnraw  = agraw  + TT * HDK;         // T x 1536 (dead after prep_qk)
    float* v_h    = qnraw;                     // alias: 8 x 128 x 1024
    float* kvb    = qnraw  + TT * HDK;         // T x 2048
    float* a_h    = kvb    + TT * HKV;         // 8 x 1024 x 192
    float* q_h    = a_h    + TT * HDK;         // 8 x 1024 x 192
    float* k_h    = q_h    + TT * HDK;         // 8 x 1024 x 192
    float* betab  = k_h    + TT * HDK;         // T x 8
    float* beta_h = betab  + TT * HH;          // 8 x 1024
    float* d2_h   = beta_h + TT * HH;          // 8 x 1024
    float* r2_h   = d2_h   + TT * HH;          // 8 x 1024

    dim3 blk(256);

    // x projections (128x128 f32 tiles; N=576 predicated)
    gemm128<<<dim3((QLR + 127) / 128, TT / 128), blk, 0, stream>>>(x, wq_a, xq, TT, QLR, DIM);
    gemm128<<<dim3((KVLR + DROPE + 127) / 128, TT / 128), blk, 0, stream>>>(x, wkv_a, kv_all, TT, KVLR + DROPE, DIM);
    gemm128<<<dim3((HDK + 127) / 128, TT / 128), blk, 0, stream>>>(x, wg_w, agraw, TT, HDK, DIM);

    // norms
    rmsnorm_rows<<<TT, blk, 0, stream>>>(xq, QLR, q_norm_w, xq, QLR, QLR, 1.f / QLR);
    rmsnorm_rows<<<TT, blk, 0, stream>>>(kv_all, KVLR + DROPE, kv_norm_w, kvn, KVLR, KVLR, 1.f / KVLR);

    // low-rank expansions
    gemm128<<<dim3((HDK + 127) / 128, TT / 128), blk, 0, stream>>>(xq, wq_b, qnraw, TT, HDK, QLR);
    gemm128<<<dim3((HKV + 127) / 128, TT / 128), blk, 0, stream>>>(kvn, wkv_b, kvb, TT, HKV, KVLR);

    // gates (head-major relayout)
    sigmoid_relayout<<<(TT * HDK + 255) / 256, blk, 0, stream>>>(agraw, wg_b, a_h);
    beta_kernel<<<TT * HH / 4, blk, 0, stream>>>(x, wb, betab, beta_h);

    // l2norm q, build+l2norm k (head-major)
    prep_qk<<<TT * HH / 4, blk, 0, stream>>>(qnraw, kvb, kv_all, q_h, k_h);

    // v transpose (after prep_qk: v_h aliases qnraw)
    vtrans<<<64, blk, 0, stream>>>(kvb, v_h);

    // input-only scalar precompute
    prep_scalars<<<TT * HH / 4, blk, 0, stream>>>(k_h, a_h, betab, d2_h, r2_h);

    // LDS-staged gated delta-rule scan (ob aliases agraw)
    kda_scan4<<<128, blk, 0, stream>>>(q_h, k_h, a_h, v_h, beta_h, d2_h, r2_h, ob);

    // output projection
    gemm128<<<dim3((DIM + 127) / 128, TT / 128), blk, 0, stream>>>(ob, wo, out, TT, DIM, DIM);
}

// Round 6
// 687.367 us; speedup vs baseline: 1.6302x; 1.6302x over previous
//
#include <hip/hip_runtime.h>
#include <hip/hip_bf16.h>
#include <math.h>

// Problem constants
#define TT 1024
#define DIM 1024
#define HH 8
#define QLR 768
#define KVLR 512
#define DNOPE 128
#define DROPE 64
#define DV 128
#define DK 192            // DNOPE + DROPE
#define HDK (HH*DK)       // 1536
#define HKV (HH*(DNOPE+DV)) // 2048
#define TB 16             // scan tile (timesteps per LDS buffer)

// ---------------------------------------------------------------------------
// Multi-region f32 GEMM: up to 3 independent C = A(MxK) @ B(KxN) problems in
// one launch (block-range routing; all routing is wave-uniform).
// Tile: BM=128 x BN=64, 256 threads, 8x4 acc/thread. M%128==0, N%64==0,
// K%16==0 required (true at every call site).
// LDS: As[k][m] (transposed at store: conflict-free col-stores, fragment
// reads hit disjoint bank quads), Bs[k][n] natural (2-way = free).
// Register prefetch of tile k+1 issued between barriers.
// ---------------------------------------------------------------------------
__global__ __launch_bounds__(256, 2) void gemm_multi(
    const float* __restrict__ A0, const float* __restrict__ B0, float* __restrict__ C0,
    int K0, int N0, int T0,
    const float* __restrict__ A1, const float* __restrict__ B1, float* __restrict__ C1,
    int K1, int N1, int T1,
    const float* __restrict__ A2, const float* __restrict__ B2, float* __restrict__ C2,
    int K2, int N2, int T2)
{
    __shared__ float As[16][128];
    __shared__ float Bs[16][64];

    int bx = blockIdx.x;
    const float* A; const float* B; float* C; int K, N;
    if (bx < T0)            { A = A0; B = B0; C = C0; K = K0; N = N0; }
    else if (bx < T0 + T1)  { bx -= T0; A = A1; B = B1; C = C1; K = K1; N = N1; }
    else                    { bx -= T0 + T1; A = A2; B = B2; C = C2; K = K2; N = N2; }

    const int tid = threadIdx.x;
    const int bm = blockIdx.y * 128, bn = bx * 64;
    const int tm = tid >> 4, tn = tid & 15;          // compute grid 16x16
    const int ar = tid >> 1, ak8 = (tid & 1) * 8;    // A loader: 2 float4 along k
    const int bk = tid >> 4, bc4 = (tid & 15) * 4;   // B loader: 1 float4 along n

    float acc[8][4];
#pragma unroll
    for (int i = 0; i < 8; i++)
#pragma unroll
        for (int j = 0; j < 4; j++) acc[i][j] = 0.f;

    const float* Ar = A + (size_t)(bm + ar) * K + ak8;
    const float* Br = B + bn + bc4;

    // prologue: tile 0 into registers
    float4 av0 = *(const float4*)(Ar);
    float4 av1 = *(const float4*)(Ar + 4);
    float4 bv  = *(const float4*)(Br + (size_t)bk * N);

    for (int k0 = 0;; k0 += 16) {
        __syncthreads();            // previous tile's readers done
        // A transposed store: col ar, rows ak8..ak8+7 (banks spread by ar)
        As[ak8 + 0][ar] = av0.x; As[ak8 + 1][ar] = av0.y;
        As[ak8 + 2][ar] = av0.z; As[ak8 + 3][ar] = av0.w;
        As[ak8 + 4][ar] = av1.x; As[ak8 + 5][ar] = av1.y;
        As[ak8 + 6][ar] = av1.z; As[ak8 + 7][ar] = av1.w;
        *(float4*)&Bs[bk][bc4] = bv;
        __syncthreads();

        const bool more = (k0 + 16) < K;
        if (more) {                 // prefetch tile k0+16 (waited at next store)
            av0 = *(const float4*)(Ar + k0 + 16);
            av1 = *(const float4*)(Ar + k0 + 20);
            bv  = *(const float4*)(Br + (size_t)(k0 + 16 + bk) * N);
        }

#pragma unroll
        for (int kk = 0; kk < 16; kk++) {
            float4 a0 = *(const float4*)&As[kk][tm * 8];
            float4 a1 = *(const float4*)&As[kk][tm * 8 + 4];
            float4 b0 = *(const float4*)&Bs[kk][tn * 4];
            float aa[8] = {a0.x, a0.y, a0.z, a0.w, a1.x, a1.y, a1.z, a1.w};
            float bb[4] = {b0.x, b0.y, b0.z, b0.w};
#pragma unroll
            for (int i = 0; i < 8; i++)
#pragma unroll
                for (int j = 0; j < 4; j++)
                    acc[i][j] = fmaf(aa[i], bb[j], acc[i][j]);
        }
        if (!more) break;
    }

#pragma unroll
    for (int i = 0; i < 8; i++) {
        float4 v = make_float4(acc[i][0], acc[i][1], acc[i][2], acc[i][3]);
        *(float4*)&C[(size_t)(bm + tm * 8 + i) * N + bn + tn * 4] = v;
    }
}

// ---------------------------------------------------------------------------
// RMSNorm rows (in-place safe: barrier between read and write phases)
// ---------------------------------------------------------------------------
__global__ __launch_bounds__(256) void rmsnorm_rows(
    const float* __restrict__ in, int in_stride, const float* __restrict__ w,
    float* __restrict__ out, int out_stride, int ncols, float inv_n)
{
    const int t = blockIdx.x;
    const int tid = threadIdx.x;
    const float* row = in + (size_t)t * in_stride;
    float ss = 0.f;
    for (int c = tid; c < ncols; c += 256) { float v = row[c]; ss += v * v; }
#pragma unroll
    for (int m = 1; m < 64; m <<= 1) ss += __shfl_xor(ss, m);
    __shared__ float red[4];
    if ((tid & 63) == 0) red[tid >> 6] = ss;
    __syncthreads();
    float tot = red[0] + red[1] + red[2] + red[3];
    float scale = rsqrtf(tot * inv_n + 1e-5f);
    for (int c = tid; c < ncols; c += 256)
        out[(size_t)t * out_stride + c] = row[c] * scale * w[c];
}

// ---------------------------------------------------------------------------
// decay = sigmoid(gpre + bias[col]) written HEAD-MAJOR: a_h[h][t][192]
// ---------------------------------------------------------------------------
__global__ __launch_bounds__(256) void sigmoid_relayout(
    const float* __restrict__ g, const float* __restrict__ bias,
    float* __restrict__ a_h)
{
    int i = blockIdx.x * 256 + threadIdx.x;   // < TT*HDK
    int t = i / HDK, col = i - t * HDK;
    int h = col / DK, d = col - h * DK;
    float z = g[i] + bias[col];
    a_h[((size_t)h * TT + t) * DK + d] = 1.f / (1.f + expf(-z));
}

// ---------------------------------------------------------------------------
// beta[t,h] = sigmoid(x . wb[:,h]); stores both [t][8] and head-major [h][t]
// ---------------------------------------------------------------------------
__global__ __launch_bounds__(256) void beta_kernel(
    const float* __restrict__ x, const float* __restrict__ wb,
    float* __restrict__ beta, float* __restrict__ beta_h)
{
    const int lane = threadIdx.x & 63, wv = threadIdx.x >> 6;
    const int p = blockIdx.x * 4 + wv;        // p = t*8 + h
    const int t = p >> 3, h = p & 7;
    const float* xr = x + (size_t)t * DIM;
    float s = 0.f;
    for (int e = lane; e < DIM; e += 64) s += xr[e] * wb[e * HH + h];
#pragma unroll
    for (int m = 1; m < 64; m <<= 1) s += __shfl_xor(s, m);
    if (lane == 0) {
        float r = 1.f / (1.f + expf(-s));
        beta[p] = r;
        beta_h[(size_t)h * TT + t] = r;
    }
}

// ---------------------------------------------------------------------------
// l2norm(q)*DK^-0.5 and build+l2norm k; outputs HEAD-MAJOR [h][t][192].
// ---------------------------------------------------------------------------
__global__ __launch_bounds__(256) void prep_qk(
    const float* __restrict__ qraw, const float* __restrict__ kvb,
    const float* __restrict__ kv_all, float* __restrict__ q_h,
    float* __restrict__ k_h)
{
    const int lane = threadIdx.x & 63, wv = threadIdx.x >> 6;
    const int p = blockIdx.x * 4 + wv;
    const int t = p >> 3, h = p & 7;

    const float* qrow = qraw + (size_t)t * HDK + h * DK;
    float q0 = qrow[lane], q1 = qrow[lane + 64], q2 = qrow[lane + 128];
    float ss = q0 * q0 + q1 * q1 + q2 * q2;
#pragma unroll
    for (int m = 1; m < 64; m <<= 1) ss += __shfl_xor(ss, m);
    float sc = rsqrtf(ss + 1e-6f) * 0.07216878364870323f;  // * DK^-0.5
    float* qo = q_h + ((size_t)h * TT + t) * DK;
    qo[lane] = q0 * sc; qo[lane + 64] = q1 * sc; qo[lane + 128] = q2 * sc;

    const float* knope = kvb + (size_t)t * HKV + h * (DNOPE + DV);
    float k0 = knope[lane], k1 = knope[lane + 64];
    float k2 = kv_all[(size_t)t * (KVLR + DROPE) + KVLR + lane];
    float ks = k0 * k0 + k1 * k1 + k2 * k2;
#pragma unroll
    for (int m = 1; m < 64; m <<= 1) ks += __shfl_xor(ks, m);
    float kc = rsqrtf(ks + 1e-6f);
    float* ko = k_h + ((size_t)h * TT + t) * DK;
    ko[lane] = k0 * kc; ko[lane + 64] = k1 * kc; ko[lane + 128] = k2 * kc;
}

// ---------------------------------------------------------------------------
// Transpose v: kvb[t][h*256+128+c] -> v_h[h][c][t]
// ---------------------------------------------------------------------------
__global__ __launch_bounds__(256) void vtrans(
    const float* __restrict__ kvb, float* __restrict__ v_h)
{
    __shared__ float ld[128][129];
    const int h = blockIdx.x >> 3, tb = (blockIdx.x & 7) * 128;
    const int tid = threadIdx.x;
    for (int it = 0; it < 64; it++) {
        int tl = it * 2 + (tid >> 7);
        int c  = tid & 127;
        ld[tl][c] = kvb[(size_t)(tb + tl) * HKV + h * (DNOPE + DV) + DNOPE + c];
    }
    __syncthreads();
    for (int it = 0; it < 64; it++) {
        int c  = it * 2 + (tid >> 7);
        int tl = tid & 127;
        v_h[((size_t)h * DV + c) * TT + tb + tl] = ld[tl][c];
    }
}

// ---------------------------------------------------------------------------
// Input-only scalars (premultiplied by beta_t), head-major [h][t]:
//   d2_h = b_t sum_d k_t a_t k_{t-1};  r2_h = b_t sum_d k_t a_t a_{t-1} k_{t-2}
// ---------------------------------------------------------------------------
__global__ __launch_bounds__(256) void prep_scalars(
    const float* __restrict__ k_h, const float* __restrict__ a_h,
    const float* __restrict__ beta, float* __restrict__ d2_h,
    float* __restrict__ r2_h)
{
    const int lane = threadIdx.x & 63, wv = threadIdx.x >> 6;
    const int p = blockIdx.x * 4 + wv;        // p = t*8 + h
    const int t = p >> 3, h = p & 7;
    const size_t rb = ((size_t)h * TT + t) * DK;
    const float b = beta[p];

    float pd = 0.f, pr = 0.f;
#pragma unroll
    for (int j = 0; j < 3; j++) {
        const int d = lane + j * 64;
        float k0 = k_h[rb + d], a0 = a_h[rb + d];
        float k1 = (t >= 1) ? k_h[rb - DK + d] : 0.f;
        float a1 = (t >= 1) ? a_h[rb - DK + d] : 1.f;
        float k2 = (t >= 2) ? k_h[rb - 2 * DK + d] : 0.f;
        float ka = k0 * a0;
        pd += ka * k1;
        pr += ka * a1 * k2;
    }
#pragma unroll
    for (int m = 1; m < 64; m <<= 1) { pd += __shfl_xor(pd, m); pr += __shfl_xor(pr, m); }
    if (lane == 0) {
        d2_h[(size_t)h * TT + t] = b * pd;
        r2_h[(size_t)h * TT + t] = b * pr;
    }
}

// ---------------------------------------------------------------------------
// 32-lane sum reduction: 4 DPP stages + 1 ds_swizzle xor16 (validated R2).
// ---------------------------------------------------------------------------
__device__ __forceinline__ float red32(float x) {
    x += __int_as_float(__builtin_amdgcn_update_dpp(0, __float_as_int(x), 0xB1, 0xF, 0xF, false));
    x += __int_as_float(__builtin_amdgcn_update_dpp(0, __float_as_int(x), 0x4E, 0xF, 0xF, false));
    x += __int_as_float(__builtin_amdgcn_update_dpp(0, __float_as_int(x), 0x141, 0xF, 0xF, false));
    x += __int_as_float(__builtin_amdgcn_update_dpp(0, __float_as_int(x), 0x140, 0xF, 0xF, false));
    x += __int_as_float(__builtin_amdgcn_ds_swizzle(__float_as_int(x), 0x401F));
    return x;
}

// async global->LDS (width 16 / 4). LDS dest = uniform base + lane*size.
__device__ __forceinline__ void gl_lds16(const float* g, float* l) {
    __builtin_amdgcn_global_load_lds(
        (const __attribute__((address_space(1))) void*)g,
        (__attribute__((address_space(3))) void*)l, 16, 0, 0);
}
__device__ __forceinline__ void gl_lds4(const float* g, float* l) {
    __builtin_amdgcn_global_load_lds(
        (const __attribute__((address_space(1))) void*)g,
        (__attribute__((address_space(3))) void*)l, 4, 0, 0);
}

// ---------------------------------------------------------------------------
// KDA scan v4 (unchanged from R4): LDS double-buffered tiles, 32 lanes/col.
// ---------------------------------------------------------------------------
__global__ __launch_bounds__(256) void kda_scan4(
    const float* __restrict__ q_h, const float* __restrict__ k_h,
    const float* __restrict__ a_h, const float* __restrict__ v_h,
    const float* __restrict__ beta_h, const float* __restrict__ d2_h,
    const float* __restrict__ r2_h, float* __restrict__ o)
{
    __shared__ __align__(16) float Kt[2][TB][192];
    __shared__ __align__(16) float At[2][TB][192];
    __shared__ __align__(16) float Qt[2][TB][192];
    __shared__ __align__(16) float Vt[2][8][TB];
    __shared__ __align__(16) float St[2][3][TB];   // b, d2, r2

    const int tid = threadIdx.x;
    const int w = tid >> 6, lane = tid & 63;
    const int sub = lane >> 5, l = lane & 31;
    const int h = blockIdx.x >> 4, cg = blockIdx.x & 15;
    const int cb = w * 2 + sub;                  // column within block 0..7
    const int d4 = l * 4, dlo = 128 + l * 2;     // this lane's dims

    const float* kg = k_h + (size_t)h * TT * DK;
    const float* ag = a_h + (size_t)h * TT * DK;
    const float* qg = q_h + (size_t)h * TT * DK;
    const float* vg = v_h + ((size_t)h * DV + cg * 8) * TT;
    const float* bg = beta_h + (size_t)h * TT;
    const float* dg = d2_h + (size_t)h * TT;
    const float* rg = r2_h + (size_t)h * TT;
    float* op = o + (size_t)h * DV + cg * 8 + cb;

    auto stage = [&](int buf, int n) {
        const size_t toff = (size_t)n * TB * DK;
        if (w == 0) {
            const float* g = kg + toff; float* lb = &Kt[buf][0][0];
#pragma unroll
            for (int i = 0; i < 12; i++) gl_lds16(g + i * 256 + lane * 4, lb + i * 256);
        } else if (w == 1) {
            const float* g = ag + toff; float* lb = &At[buf][0][0];
#pragma unroll
            for (int i = 0; i < 12; i++) gl_lds16(g + i * 256 + lane * 4, lb + i * 256);
        } else if (w == 2) {
            const float* g = qg + toff; float* lb = &Qt[buf][0][0];
#pragma unroll
            for (int i = 0; i < 12; i++) gl_lds16(g + i * 256 + lane * 4, lb + i * 256);
        } else {
            if (lane < 32) {   // V: 8 cols x 16 t = 512 B; lane -> base + lane*16
                const float* g = vg + (size_t)(lane >> 2) * TT + n * TB + (lane & 3) * 4;
                gl_lds16(g, &Vt[buf][0][0]);
            }
            if (lane < 48) {   // St: 3 x 16 floats; lane -> base + lane*4
                const int which = lane >> 4, tt = lane & 15;
                const float* g = (which == 0 ? bg : which == 1 ? dg : rg) + n * TB + tt;
                gl_lds4(g, &St[buf][0][0]);
            }
        }
    };

    float sd[6], kp1[6], kp2[6], qpv[6], apv[6];
#pragma unroll
    for (int j = 0; j < 6; j++) { sd[j] = 0.f; kp1[j] = 0.f; kp2[j] = 0.f; qpv[j] = 0.f; apv[j] = 1.f; }
    float u1 = 0.f, u2 = 0.f;

    stage(0, 0);
    stage(1, 1);

    for (int n = 0; n < TT / TB; n++) {
        const int buf = n & 1;
        __syncthreads();   // own-wave vmcnt drained -> buf's tile is resident
#pragma unroll 4
        for (int tt = 0; tt < TB; tt++) {
            const int t = n * TB + tt;
            const float* Kr = &Kt[buf][tt][0];
            const float* Ar = &At[buf][tt][0];
            const float* Qr = &Qt[buf][tt][0];
            float kc[6], ac[6], qc[6];
            { float4 f = *(const float4*)(Kr + d4); kc[0]=f.x; kc[1]=f.y; kc[2]=f.z; kc[3]=f.w;
              float2 g2 = *(const float2*)(Kr + dlo); kc[4]=g2.x; kc[5]=g2.y; }
            { float4 f = *(const float4*)(Ar + d4); ac[0]=f.x; ac[1]=f.y; ac[2]=f.z; ac[3]=f.w;
              float2 g2 = *(const float2*)(Ar + dlo); ac[4]=g2.x; ac[5]=g2.y; }
            { float4 f = *(const float4*)(Qr + d4); qc[0]=f.x; qc[1]=f.y; qc[2]=f.z; qc[3]=f.w;
              float2 g2 = *(const float2*)(Qr + dlo); qc[4]=g2.x; qc[5]=g2.y; }
            const float vc  = Vt[buf][cb][tt];
            const float bS  = St[buf][0][tt];
            const float d2S = St[buf][1][tt];
            const float r2S = St[buf][2][tt];

            // r1 = red32( sum_j k a a_prev * sd )
            float p0 = 0.f, p1 = 0.f;
#pragma unroll
            for (int j = 0; j < 6; j++) {
                float kaa = kc[j] * ac[j] * apv[j];
                if (j & 1) p1 = fmaf(kaa, sd[j], p1); else p0 = fmaf(kaa, sd[j], p0);
            }
            float r1 = red32(p0 + p1);

            float ut = bS * vc - bS * r1 - u2 * r2S - u1 * d2S;

            // sd -> S~_{t-1}
#pragma unroll
            for (int j = 0; j < 6; j++)
                sd[j] = apv[j] * fmaf(u2, kp2[j], sd[j]);

            // o_{t-1}
            float o0 = 0.f, o1 = 0.f;
#pragma unroll
            for (int j = 0; j < 6; j++) {
                float tmp = fmaf(u1, kp1[j], sd[j]);
                if (j & 1) o1 = fmaf(qpv[j], tmp, o1); else o0 = fmaf(qpv[j], tmp, o0);
            }
            float ov = red32(o0 + o1);
            if (isnan(ov)) ov = 0.f;
            else if (isinf(ov)) ov = ov > 0.f ? 1e4f : -1e4f;
            if (l == 0 && t > 0) op[(size_t)(t - 1) * (HH * DV)] = ov;

            // rotate registers
#pragma unroll
            for (int j = 0; j < 6; j++) {
                kp2[j] = kp1[j]; kp1[j] = kc[j]; qpv[j] = qc[j]; apv[j] = ac[j];
            }
            u2 = u1; u1 = ut;
        }
        __syncthreads();   // all waves done reading buf
        if (n + 2 < TT / TB) stage(buf, n + 2);
    }

    // epilogue: o_{TT-1}
    {
#pragma unroll
        for (int j = 0; j < 6; j++)
            sd[j] = apv[j] * fmaf(u2, kp2[j], sd[j]);
        float o0 = 0.f, o1 = 0.f;
#pragma unroll
        for (int j = 0; j < 6; j++) {
            float tmp = fmaf(u1, kp1[j], sd[j]);
            if (j & 1) o1 = fmaf(qpv[j], tmp, o1); else o0 = fmaf(qpv[j], tmp, o0);
        }
        float ov = red32(o0 + o1);
        if (isnan(ov)) ov = 0.f;
        else if (isinf(ov)) ov = ov > 0.f ? 1e4f : -1e4f;
        if (l == 0) op[(size_t)(TT - 1) * (HH * DV)] = ov;
    }
}

// ---------------------------------------------------------------------------
extern "C" void kernel_launch(void* const* d_in, const int* in_sizes, int n_in,
                              void* d_out, int out_size, void* d_ws, size_t ws_size,
                              hipStream_t stream)
{
    const float* x         = (const float*)d_in[0];
    // d_in[1] = cos, d_in[2] = sin : unused by the reference
    const float* wq_a      = (const float*)d_in[3];
    const float* q_norm_w  = (const float*)d_in[4];
    const float* wq_b      = (const float*)d_in[5];
    const float* wkv_a     = (const float*)d_in[6];
    const float* kv_norm_w = (const float*)d_in[7];
    const float* wkv_b     = (const float*)d_in[8];
    const float* wg_w      = (const float*)d_in[9];
    const float* wg_b      = (const float*)d_in[10];
    const float* wb        = (const float*)d_in[11];
    const float* wo        = (const float*)d_in[12];
    float* out = (float*)d_out;

    float* ws = (float*)d_ws;
    float* xq     = ws;                        // T x 768 (rms in-place)
    float* kv_all = xq     + TT * QLR;         // T x 576
    float* kvn    = kv_all + TT * (KVLR + DROPE); // T x 512
    float* agraw  = kvn    + TT * KVLR;        // T x 1536 (dead after sigmoid)
    float* ob     = agraw;                     // alias: T x 1024 (scan output)
    float* qnraw  = agraw  + TT * HDK;         // T x 1536 (dead after prep_qk)
    float* v_h    = qnraw;                     // alias: 8 x 128 x 1024
    float* kvb    = qnraw  + TT * HDK;         // T x 2048
    float* a_h    = kvb    + TT * HKV;         // 8 x 1024 x 192
    float* q_h    = a_h    + TT * HDK;         // 8 x 1024 x 192
    float* k_h    = q_h    + TT * HDK;         // 8 x 1024 x 192
    float* betab  = k_h    + TT * HDK;         // T x 8
    float* beta_h = betab  + TT * HH;          // 8 x 1024
    float* d2_h   = beta_h + TT * HH;          // 8 x 1024
    float* r2_h   = d2_h   + TT * HH;          // 8 x 1024

    dim3 blk(256);

    // x projections fused: {wq_a (12 tiles), wkv_a (9), wg_w (24)} = 45 x 8 blocks
    gemm_multi<<<dim3(12 + 9 + 24, TT / 128), blk, 0, stream>>>(
        x, wq_a, xq,    DIM, QLR, 12,
        x, wkv_a, kv_all, DIM, KVLR + DROPE, 9,
        x, wg_w, agraw, DIM, HDK, 24);

    // norms
    rmsnorm_rows<<<TT, blk, 0, stream>>>(xq, QLR, q_norm_w, xq, QLR, QLR, 1.f / QLR);
    rmsnorm_rows<<<TT, blk, 0, stream>>>(kv_all, KVLR + DROPE, kv_norm_w, kvn, KVLR, KVLR, 1.f / KVLR);

    // low-rank expansions fused: {wq_b (24 tiles), wkv_b (32)} = 56 x 8 blocks
    gemm_multi<<<dim3(24 + 32, TT / 128), blk, 0, stream>>>(
        xq, wq_b, qnraw, QLR, HDK, 24,
        kvn, wkv_b, kvb, KVLR, HKV, 32,
        x, wq_a, xq, DIM, QLR, 0);   // unused region

    // gates (head-major relayout)
    sigmoid_relayout<<<(TT * HDK + 255) / 256, blk, 0, stream>>>(agraw, wg_b, a_h);
    beta_kernel<<<TT * HH / 4, blk, 0, stream>>>(x, wb, betab, beta_h);

    // l2norm q, build+l2norm k (head-major)
    prep_qk<<<TT * HH / 4, blk, 0, stream>>>(qnraw, kvb, kv_all, q_h, k_h);

    // v transpose (after prep_qk: v_h aliases qnraw)
    vtrans<<<64, blk, 0, stream>>>(kvb, v_h);

    // input-only scalar precompute
    prep_scalars<<<TT * HH / 4, blk, 0, stream>>>(k_h, a_h, betab, d2_h, r2_h);

    // LDS-staged gated delta-rule scan (ob aliases agraw)
    kda_scan4<<<128, blk, 0, stream>>>(q_h, k_h, a_h, v_h, beta_h, d2_h, r2_h, ob);

    // output projection: 16 x 8 blocks
    gemm_multi<<<dim3(16, TT / 128), blk, 0, stream>>>(
        ob, wo, out, DIM, DIM, 16,
        ob, wo, out, DIM, DIM, 0,
        ob, wo, out, DIM, DIM, 0);
}

// Round 7
// 564.129 us; speedup vs baseline: 1.9863x; 1.2185x over previous
//
#include <hip/hip_runtime.h>
#include <hip/hip_bf16.h>
#include <math.h>

// Problem constants
#define TT 1024
#define DIM 1024
#define HH 8
#define QLR 768
#define KVLR 512
#define DNOPE 128
#define DROPE 64
#define DV 128
#define DK 192            // DNOPE + DROPE
#define HDK (HH*DK)       // 1536
#define HKV (HH*(DNOPE+DV)) // 2048

// Phase-A blob layout (floats) per (chunk n, head h):
#define OY   0            // Y   [16][192]  = T * (b k e^G)
#define OQ   3072         // Qa  [16][192]  = q e^G
#define OC   6144         // KcT [192][16]  = (k e^{-G} * lam)^T
#define OPL  9216         // PL  [16][16]   incl-lower  Qa.Kap^T
#define OU   9472         // u'  [16][128]  = T (b v)
#define OLAM 11520        // lam [192]      = e^{G_15}
#define PABLK 11712

// ---------------------------------------------------------------------------
// Multi-region f32 GEMM (unchanged from R6): up to 3 independent problems,
// 128x64 tile, 8x4 acc/thread. M%128==0, N%64==0, K%16==0.
// ---------------------------------------------------------------------------
__global__ __launch_bounds__(256, 2) void gemm_multi(
    const float* __restrict__ A0, const float* __restrict__ B0, float* __restrict__ C0,
    int K0, int N0, int T0,
    const float* __restrict__ A1, const float* __restrict__ B1, float* __restrict__ C1,
    int K1, int N1, int T1,
    const float* __restrict__ A2, const float* __restrict__ B2, float* __restrict__ C2,
    int K2, int N2, int T2)
{
    __shared__ float As[16][128];
    __shared__ float Bs[16][64];

    int bx = blockIdx.x;
    const float* A; const float* B; float* C; int K, N;
    if (bx < T0)            { A = A0; B = B0; C = C0; K = K0; N = N0; }
    else if (bx < T0 + T1)  { bx -= T0; A = A1; B = B1; C = C1; K = K1; N = N1; }
    else                    { bx -= T0 + T1; A = A2; B = B2; C = C2; K = K2; N = N2; }

    const int tid = threadIdx.x;
    const int bm = blockIdx.y * 128, bn = bx * 64;
    const int tm = tid >> 4, tn = tid & 15;
    const int ar = tid >> 1, ak8 = (tid & 1) * 8;
    const int bk = tid >> 4, bc4 = (tid & 15) * 4;

    float acc[8][4];
#pragma unroll
    for (int i = 0; i < 8; i++)
#pragma unroll
        for (int j = 0; j < 4; j++) acc[i][j] = 0.f;

    const float* Ar = A + (size_t)(bm + ar) * K + ak8;
    const float* Br = B + bn + bc4;

    float4 av0 = *(const float4*)(Ar);
    float4 av1 = *(const float4*)(Ar + 4);
    float4 bv  = *(const float4*)(Br + (size_t)bk * N);

    for (int k0 = 0;; k0 += 16) {
        __syncthreads();
        As[ak8 + 0][ar] = av0.x; As[ak8 + 1][ar] = av0.y;
        As[ak8 + 2][ar] = av0.z; As[ak8 + 3][ar] = av0.w;
        As[ak8 + 4][ar] = av1.x; As[ak8 + 5][ar] = av1.y;
        As[ak8 + 6][ar] = av1.z; As[ak8 + 7][ar] = av1.w;
        *(float4*)&Bs[bk][bc4] = bv;
        __syncthreads();

        const bool more = (k0 + 16) < K;
        if (more) {
            av0 = *(const float4*)(Ar + k0 + 16);
            av1 = *(const float4*)(Ar + k0 + 20);
            bv  = *(const float4*)(Br + (size_t)(k0 + 16 + bk) * N);
        }

#pragma unroll
        for (int kk = 0; kk < 16; kk++) {
            float4 a0 = *(const float4*)&As[kk][tm * 8];
            float4 a1 = *(const float4*)&As[kk][tm * 8 + 4];
            float4 b0 = *(const float4*)&Bs[kk][tn * 4];
            float aa[8] = {a0.x, a0.y, a0.z, a0.w, a1.x, a1.y, a1.z, a1.w};
            float bb[4] = {b0.x, b0.y, b0.z, b0.w};
#pragma unroll
            for (int i = 0; i < 8; i++)
#pragma unroll
                for (int j = 0; j < 4; j++)
                    acc[i][j] = fmaf(aa[i], bb[j], acc[i][j]);
        }
        if (!more) break;
    }

#pragma unroll
    for (int i = 0; i < 8; i++) {
        float4 v = make_float4(acc[i][0], acc[i][1], acc[i][2], acc[i][3]);
        *(float4*)&C[(size_t)(bm + tm * 8 + i) * N + bn + tn * 4] = v;
    }
}

// ---------------------------------------------------------------------------
__global__ __launch_bounds__(256) void rmsnorm_rows(
    const float* __restrict__ in, int in_stride, const float* __restrict__ w,
    float* __restrict__ out, int out_stride, int ncols, float inv_n)
{
    const int t = blockIdx.x;
    const int tid = threadIdx.x;
    const float* row = in + (size_t)t * in_stride;
    float ss = 0.f;
    for (int c = tid; c < ncols; c += 256) { float v = row[c]; ss += v * v; }
#pragma unroll
    for (int m = 1; m < 64; m <<= 1) ss += __shfl_xor(ss, m);
    __shared__ float red[4];
    if ((tid & 63) == 0) red[tid >> 6] = ss;
    __syncthreads();
    float tot = red[0] + red[1] + red[2] + red[3];
    float scale = rsqrtf(tot * inv_n + 1e-5f);
    for (int c = tid; c < ncols; c += 256)
        out[(size_t)t * out_stride + c] = row[c] * scale * w[c];
}

// ---------------------------------------------------------------------------
// la = log_sigmoid(gpre + bias), HEAD-MAJOR: la_h[h][t][192]
// ---------------------------------------------------------------------------
__global__ __launch_bounds__(256) void logsig_relayout(
    const float* __restrict__ g, const float* __restrict__ bias,
    float* __restrict__ la_h)
{
    int i = blockIdx.x * 256 + threadIdx.x;   // < TT*HDK
    int t = i / HDK, col = i - t * HDK;
    int h = col / DK, d = col - h * DK;
    float z = g[i] + bias[col];
    // log_sigmoid(z) = min(z,0) - log1p(exp(-|z|))
    float la = fminf(z, 0.f) - log1pf(__expf(-fabsf(z)));
    la_h[((size_t)h * TT + t) * DK + d] = la;
}

// ---------------------------------------------------------------------------
__global__ __launch_bounds__(256) void beta_kernel(
    const float* __restrict__ x, const float* __restrict__ wb,
    float* __restrict__ beta)
{
    const int lane = threadIdx.x & 63, wv = threadIdx.x >> 6;
    const int p = blockIdx.x * 4 + wv;        // p = t*8 + h
    const int t = p >> 3, h = p & 7;
    const float* xr = x + (size_t)t * DIM;
    float s = 0.f;
    for (int e = lane; e < DIM; e += 64) s += xr[e] * wb[e * HH + h];
#pragma unroll
    for (int m = 1; m < 64; m <<= 1) s += __shfl_xor(s, m);
    if (lane == 0) beta[p] = 1.f / (1.f + expf(-s));
}

// ---------------------------------------------------------------------------
// l2norm(q)*DK^-0.5 and build+l2norm k; outputs HEAD-MAJOR [h][t][192].
// ---------------------------------------------------------------------------
__global__ __launch_bounds__(256) void prep_qk(
    const float* __restrict__ qraw, const float* __restrict__ kvb,
    const float* __restrict__ kv_all, float* __restrict__ q_h,
    float* __restrict__ k_h)
{
    const int lane = threadIdx.x & 63, wv = threadIdx.x >> 6;
    const int p = blockIdx.x * 4 + wv;
    const int t = p >> 3, h = p & 7;

    const float* qrow = qraw + (size_t)t * HDK + h * DK;
    float q0 = qrow[lane], q1 = qrow[lane + 64], q2 = qrow[lane + 128];
    float ss = q0 * q0 + q1 * q1 + q2 * q2;
#pragma unroll
    for (int m = 1; m < 64; m <<= 1) ss += __shfl_xor(ss, m);
    float sc = rsqrtf(ss + 1e-6f) * 0.07216878364870323f;  // * DK^-0.5
    float* qo = q_h + ((size_t)h * TT + t) * DK;
    qo[lane] = q0 * sc; qo[lane + 64] = q1 * sc; qo[lane + 128] = q2 * sc;

    const float* knope = kvb + (size_t)t * HKV + h * (DNOPE + DV);
    float k0 = knope[lane], k1 = knope[lane + 64];
    float k2 = kv_all[(size_t)t * (KVLR + DROPE) + KVLR + lane];
    float ks = k0 * k0 + k1 * k1 + k2 * k2;
#pragma unroll
    for (int m = 1; m < 64; m <<= 1) ks += __shfl_xor(ks, m);
    float kc = rsqrtf(ks + 1e-6f);
    float* ko = k_h + ((size_t)h * TT + t) * DK;
    ko[lane] = k0 * kc; ko[lane + 64] = k1 * kc; ko[lane + 128] = k2 * kc;
}

// ---------------------------------------------------------------------------
__device__ __forceinline__ float dpp_xor1(float x) {
    return __int_as_float(__builtin_amdgcn_update_dpp(
        0, __float_as_int(x), 0xB1, 0xF, 0xF, false));
}

__device__ __forceinline__ void gl_lds16(const float* g, float* l) {
    __builtin_amdgcn_global_load_lds(
        (const __attribute__((address_space(1))) void*)g,
        (__attribute__((address_space(3))) void*)l, 16, 0, 0);
}
__device__ __forceinline__ void gl_lds4(const float* g, float* l) {
    __builtin_amdgcn_global_load_lds(
        (const __attribute__((address_space(1))) void*)g,
        (__attribute__((address_space(3))) void*)l, 4, 0, 0);
}

// ---------------------------------------------------------------------------
// Phase A: per-(chunk,head) S-independent quantities.
// Within chunk (i local, G = inclusive cumsum of log a):
//   M[i][j] = b_i sum_d k_i k_j e^{G_i-G_j}  (j<i)
//   PL[i][j]= sum_d q_i k_j e^{G_i-G_j}      (j<=i)
//   Y = (I+M)^{-1} Wb, u' = (I+M)^{-1}(b v), Qa = q e^G,
//   lam = e^{G_15}, KcT[d][j] = k_j e^{-G_j} lam[d]
// Block per (n,h): 512 blocks x 256 threads.
// ---------------------------------------------------------------------------
__global__ __launch_bounds__(256) void chunk_prep(
    const float* __restrict__ k_h, const float* __restrict__ la_h,
    const float* __restrict__ q_h, const float* __restrict__ kvb,
    const float* __restrict__ betab, float* __restrict__ pa)
{
    __shared__ float Ls[16][196];  // la -> G (in place)
    __shared__ float Ks[16][196];  // k  -> Kap
    __shared__ float Qs[16][196];  // q  -> Qa
    __shared__ float Ws[16][196];  // Wb
    __shared__ float Xs[16][196];  // relayout scratch
    __shared__ float Ms[16][16];
    __shared__ float bs[16];

    const int tid = threadIdx.x;
    const int n = blockIdx.x >> 3, h = blockIdx.x & 7;
    const size_t g0 = ((size_t)h * TT + n * 16) * DK;
    float* blob = pa + (size_t)blockIdx.x * PABLK;

#pragma unroll
    for (int s = 0; s < 3; s++) {
        int off = (tid * 3 + s) * 4;
        int r = off / 192, c = off - r * 192;
        *(float4*)&Ks[r][c] = *(const float4*)(k_h + g0 + off);
        *(float4*)&Ls[r][c] = *(const float4*)(la_h + g0 + off);
        *(float4*)&Qs[r][c] = *(const float4*)(q_h + g0 + off);
    }
    if (tid < 16) bs[tid] = betab[(size_t)(n * 16 + tid) * HH + h];
    __syncthreads();

    if (tid < 192) {
        float g = 0.f;
#pragma unroll
        for (int i = 0; i < 16; i++) { g += Ls[i][tid]; Ls[i][tid] = g; }
    }
    __syncthreads();

#pragma unroll
    for (int s = 0; s < 12; s++) {
        int idx = s * 256 + tid;
        int i = idx / 192, d = idx - i * 192;
        float G = Ls[i][d];
        float eg = __expf(G), en = __expf(-G);
        float kk = Ks[i][d];
        Ws[i][d] = bs[i] * kk * eg;
        Qs[i][d] *= eg;
        Ks[i][d] = kk * en;
    }
    __syncthreads();

    // Qa out (coalesced)
#pragma unroll
    for (int s = 0; s < 3; s++) {
        int off = (tid * 3 + s) * 4;
        int r = off / 192, c = off - r * 192;
        *(float4*)(blob + OQ + off) = *(const float4*)&Qs[r][c];
    }
    // KcT + lam out
    if (tid < 192) {
        float lam = __expf(Ls[15][tid]);
        blob[OLAM + tid] = lam;
#pragma unroll
        for (int j4 = 0; j4 < 4; j4++) {
            float4 v;
            v.x = Ks[j4 * 4 + 0][tid] * lam; v.y = Ks[j4 * 4 + 1][tid] * lam;
            v.z = Ks[j4 * 4 + 2][tid] * lam; v.w = Ks[j4 * 4 + 3][tid] * lam;
            *(float4*)(blob + OC + tid * 16 + j4 * 4) = v;
        }
    }
    // M & PL gemms (thread per (i,j))
    {
        const int i = tid >> 4, j = tid & 15;
        float m = 0.f, p = 0.f;
#pragma unroll
        for (int d4 = 0; d4 < 48; d4++) {
            float4 w  = *(const float4*)&Ws[i][d4 * 4];
            float4 ka = *(const float4*)&Ks[j][d4 * 4];
            float4 qa = *(const float4*)&Qs[i][d4 * 4];
            m += w.x * ka.x + w.y * ka.y + w.z * ka.z + w.w * ka.w;
            p += qa.x * ka.x + qa.y * ka.y + qa.z * ka.z + qa.w * ka.w;
        }
        Ms[i][j] = (j < i) ? m : 0.f;
        blob[OPL + tid] = (j <= i) ? p : 0.f;
    }
    __syncthreads();

    // forward substitution (unit lower-triangular I+M)
    float y[16], uu[16];
    const bool doY = (tid < 192);
    const bool doU = (tid >= 128);
    const int dcol = tid, ccol = tid - 128;
    if (doY) {
#pragma unroll
        for (int i = 0; i < 16; i++) y[i] = Ws[i][dcol];
#pragma unroll
        for (int i = 1; i < 16; i++)
#pragma unroll
            for (int j = 0; j < i; j++)
                y[i] = fmaf(-Ms[i][j], y[j], y[i]);
    }
    if (doU) {
#pragma unroll
        for (int i = 0; i < 16; i++)
            uu[i] = bs[i] * kvb[(size_t)(n * 16 + i) * HKV + h * (DNOPE + DV) + DNOPE + ccol];
#pragma unroll
        for (int i = 1; i < 16; i++)
#pragma unroll
            for (int j = 0; j < i; j++)
                uu[i] = fmaf(-Ms[i][j], uu[j], uu[i]);
    }
    // Y out via relayout
    if (doY) {
#pragma unroll
        for (int i = 0; i < 16; i++) Xs[i][dcol] = y[i];
    }
    __syncthreads();
#pragma unroll
    for (int s = 0; s < 3; s++) {
        int off = (tid * 3 + s) * 4;
        int r = off / 192, c = off - r * 192;
        *(float4*)(blob + OY + off) = *(const float4*)&Xs[r][c];
    }
    __syncthreads();
    if (doU) {
#pragma unroll
        for (int i = 0; i < 16; i++) Xs[i][ccol] = uu[i];
    }
    __syncthreads();
#pragma unroll
    for (int s = 0; s < 2; s++) {
        int off = (tid * 2 + s) * 4;
        int r = off / 128, c = off - r * 128;
        *(float4*)(blob + OU + off) = *(const float4*)&Xs[r][c];
    }
}

// ---------------------------------------------------------------------------
// Phase B: sequential over 64 chunks; block owns (head, 8 v-columns) state
// slice S[192][8] in LDS — no inter-block coupling. Per chunk:
//   z=Y.S, zq=Qa.S ; u = u' - z ; o = zq + PL u ; S = lam*S + KcT u
// Double-buffered global_load_lds staging; DPP-xor1 reductions only.
// grid 128 = 8 h x 16 colgroups; 256 threads.
// ---------------------------------------------------------------------------
__global__ __launch_bounds__(256) void kda_chunk(
    const float* __restrict__ pa, float* __restrict__ ob)
{
    __shared__ float Yb[2][3136];   // [16][196] padded rows
    __shared__ float Qb[2][3136];
    __shared__ float Cb[2][3072];   // KcT [192][16] packed
    __shared__ float Pb[2][256];
    __shared__ float ubs[2][128];   // u' slice [16][8]
    __shared__ float lbs[2][192];
    __shared__ float Ss[1568];      // state [8][196]
    __shared__ float us[144];       // u [16][9]

    const int tid = threadIdx.x;
    const int w = tid >> 6, lane = tid & 63;
    const int h = blockIdx.x >> 4, cg = blockIdx.x & 15;
    const int c0 = cg * 8;

    auto stage = [&](int buf, int n) {
        const float* blob = pa + (size_t)(n * 8 + h) * PABLK;
        if (w == 0) {
            if (lane < 48)
#pragma unroll
                for (int r = 0; r < 16; r++)
                    gl_lds16(blob + OY + r * 192 + lane * 4, &Yb[buf][r * 196]);
        } else if (w == 1) {
            if (lane < 48)
#pragma unroll
                for (int r = 0; r < 16; r++)
                    gl_lds16(blob + OQ + r * 192 + lane * 4, &Qb[buf][r * 196]);
        } else if (w == 2) {
#pragma unroll
            for (int s = 0; s < 12; s++)
                gl_lds16(blob + OC + s * 256 + lane * 4, &Cb[buf][s * 256]);
        } else {
            gl_lds16(blob + OPL + lane * 4, &Pb[buf][0]);
            gl_lds4(blob + OU + (lane >> 3) * 128 + c0 + (lane & 7), &ubs[buf][0]);
            gl_lds4(blob + OU + (8 + (lane >> 3)) * 128 + c0 + (lane & 7), &ubs[buf][64]);
            if (lane < 48)
                gl_lds16(blob + OLAM + lane * 4, &lbs[buf][0]);
        }
    };

    for (int idx = tid; idx < 1568; idx += 256) Ss[idx] = 0.f;
    stage(0, 0);
    stage(1, 1);

    const int ti = tid >> 4, cc = (tid >> 1) & 7, half = tid & 1;
    const int dg = tid >> 3, c2 = tid & 7;

    for (int n = 0; n < TT / 16; n++) {
        const int buf = n & 1;
        __syncthreads();   // A: buf staged (vmcnt drained), prev update done

        // z = Y.S, zq = Qa.S over this lane's 96-d half (skewed reads)
        const float* Yr = &Yb[buf][ti * 196 + half * 96];
        const float* Qr = &Qb[buf][ti * 196 + half * 96];
        const float* Sr = &Ss[cc * 196 + half * 96];
        int sp = (ti * 3) % 24;
        float zy0 = 0.f, zy1 = 0.f, zq0 = 0.f, zq1 = 0.f;
#pragma unroll 4
        for (int s = 0; s < 24; s++) {
            float4 yv = *(const float4*)(Yr + sp * 4);
            float4 qv = *(const float4*)(Qr + sp * 4);
            float4 sv = *(const float4*)(Sr + sp * 4);
            zy0 = fmaf(yv.x, sv.x, zy0); zy1 = fmaf(yv.y, sv.y, zy1);
            zy0 = fmaf(yv.z, sv.z, zy0); zy1 = fmaf(yv.w, sv.w, zy1);
            zq0 = fmaf(qv.x, sv.x, zq0); zq1 = fmaf(qv.y, sv.y, zq1);
            zq0 = fmaf(qv.z, sv.z, zq0); zq1 = fmaf(qv.w, sv.w, zq1);
            sp++; if (sp == 24) sp = 0;
        }
        float zy = zy0 + zy1; zy += dpp_xor1(zy);
        float zq = zq0 + zq1; zq += dpp_xor1(zq);
        float u_ic = ubs[buf][ti * 8 + cc] - zy;
        if (half == 0) us[ti * 9 + cc] = u_ic;
        __syncthreads();   // B: us ready

        // o = zq + PL u  (j-parity split across half, combined via xor1)
        float acc = 0.f;
        for (int j = half; j <= ti; j += 2)
            acc = fmaf(Pb[buf][ti * 16 + j], us[j * 9 + cc], acc);
        acc += dpp_xor1(acc);
        float ov = zq + acc;
        if (isnan(ov)) ov = 0.f;
        else if (isinf(ov)) ov = ov > 0.f ? 1e4f : -1e4f;
        if (half == 0)
            ob[(size_t)(n * 16 + ti) * (HH * DV) + h * DV + c0 + cc] = ov;

        // state update: S[d][c2] = lam[d] S + sum_j KcT[d][j] u[j][c2]
        float uu2[16];
#pragma unroll
        for (int j = 0; j < 16; j++) uu2[j] = us[j * 9 + c2];
#pragma unroll
        for (int s = 0; s < 6; s++) {
            int d = dg * 6 + s;
            float sv = Ss[c2 * 196 + d];
            float a2 = lbs[buf][d] * sv;
            const float4* C4 = (const float4*)&Cb[buf][d * 16];
            float4 k0 = C4[0], k1 = C4[1], k2 = C4[2], k3 = C4[3];
            a2 = fmaf(k0.x, uu2[0],  a2); a2 = fmaf(k0.y, uu2[1],  a2);
            a2 = fmaf(k0.z, uu2[2],  a2); a2 = fmaf(k0.w, uu2[3],  a2);
            a2 = fmaf(k1.x, uu2[4],  a2); a2 = fmaf(k1.y, uu2[5],  a2);
            a2 = fmaf(k1.z, uu2[6],  a2); a2 = fmaf(k1.w, uu2[7],  a2);
            a2 = fmaf(k2.x, uu2[8],  a2); a2 = fmaf(k2.y, uu2[9],  a2);
            a2 = fmaf(k2.z, uu2[10], a2); a2 = fmaf(k2.w, uu2[11], a2);
            a2 = fmaf(k3.x, uu2[12], a2); a2 = fmaf(k3.y, uu2[13], a2);
            a2 = fmaf(k3.z, uu2[14], a2); a2 = fmaf(k3.w, uu2[15], a2);
            Ss[c2 * 196 + d] = a2;
        }
        __syncthreads();   // C: buf fully consumed, Ss updated
        if (n + 2 < TT / 16) stage(buf, n + 2);
    }
}

// ---------------------------------------------------------------------------
extern "C" void kernel_launch(void* const* d_in, const int* in_sizes, int n_in,
                              void* d_out, int out_size, void* d_ws, size_t ws_size,
                              hipStream_t stream)
{
    const float* x         = (const float*)d_in[0];
    // d_in[1] = cos, d_in[2] = sin : unused by the reference
    const float* wq_a      = (const float*)d_in[3];
    const float* q_norm_w  = (const float*)d_in[4];
    const float* wq_b      = (const float*)d_in[5];
    const float* wkv_a     = (const float*)d_in[6];
    const float* kv_norm_w = (const float*)d_in[7];
    const float* wkv_b     = (const float*)d_in[8];
    const float* wg_w      = (const float*)d_in[9];
    const float* wg_b      = (const float*)d_in[10];
    const float* wb        = (const float*)d_in[11];
    const float* wo        = (const float*)d_in[12];
    float* out = (float*)d_out;

    float* ws = (float*)d_ws;
    float* xq     = ws;                        // T x 768 (rms in-place)
    float* kv_all = xq     + TT * QLR;         // T x 576
    float* kvn    = kv_all + TT * (KVLR + DROPE); // T x 512
    float* agraw  = kvn    + TT * KVLR;        // T x 1536 (dead after logsig)
    float* ob     = agraw;                     // alias: T x 1024 (scan output)
    float* qnraw  = agraw  + TT * HDK;         // T x 1536 (dead after prep_qk)
    float* kvb    = qnraw  + TT * HDK;         // T x 2048
    float* la_h   = kvb    + TT * HKV;         // 8 x 1024 x 192
    float* q_h    = la_h   + TT * HDK;         // 8 x 1024 x 192
    float* k_h    = q_h    + TT * HDK;         // 8 x 1024 x 192
    float* betab  = k_h    + TT * HDK;         // T x 8
    float* pa     = betab  + TT * HH;          // 512 x PABLK (24 MB)

    dim3 blk(256);

    // x projections fused: {wq_a (12), wkv_a (9), wg_w (24)} = 45 x 8 blocks
    gemm_multi<<<dim3(12 + 9 + 24, TT / 128), blk, 0, stream>>>(
        x, wq_a, xq,    DIM, QLR, 12,
        x, wkv_a, kv_all, DIM, KVLR + DROPE, 9,
        x, wg_w, agraw, DIM, HDK, 24);

    // norms
    rmsnorm_rows<<<TT, blk, 0, stream>>>(xq, QLR, q_norm_w, xq, QLR, QLR, 1.f / QLR);
    rmsnorm_rows<<<TT, blk, 0, stream>>>(kv_all, KVLR + DROPE, kv_norm_w, kvn, KVLR, KVLR, 1.f / KVLR);

    // low-rank expansions fused: {wq_b (24), wkv_b (32)} = 56 x 8 blocks
    gemm_multi<<<dim3(24 + 32, TT / 128), blk, 0, stream>>>(
        xq, wq_b, qnraw, QLR, HDK, 24,
        kvn, wkv_b, kvb, KVLR, HKV, 32,
        x, wq_a, xq, DIM, QLR, 0);   // unused region

    // gates
    logsig_relayout<<<(TT * HDK + 255) / 256, blk, 0, stream>>>(agraw, wg_b, la_h);
    beta_kernel<<<TT * HH / 4, blk, 0, stream>>>(x, wb, betab);

    // l2norm q, build+l2norm k (head-major)
    prep_qk<<<TT * HH / 4, blk, 0, stream>>>(qnraw, kvb, kv_all, q_h, k_h);

    // chunked delta rule: phase A (parallel) + phase B (sequential chunks)
    chunk_prep<<<512, blk, 0, stream>>>(k_h, la_h, q_h, kvb, betab, pa);
    kda_chunk<<<128, blk, 0, stream>>>(pa, ob);

    // output projection: 16 x 8 blocks
    gemm_multi<<<dim3(16, TT / 128), blk, 0, stream>>>(
        ob, wo, out, DIM, DIM, 16,
        ob, wo, out, DIM, DIM, 0,
        ob, wo, out, DIM, DIM, 0);
}

// Round 8
// 530.425 us; speedup vs baseline: 2.1126x; 1.0635x over previous
//
#include <hip/hip_runtime.h>
#include <hip/hip_bf16.h>
#include <math.h>

// Problem constants
#define TT 1024
#define DIM 1024
#define HH 8
#define QLR 768
#define KVLR 512
#define DNOPE 128
#define DROPE 64
#define DV 128
#define DK 192            // DNOPE + DROPE
#define HDK (HH*DK)       // 1536
#define HKV (HH*(DNOPE+DV)) // 2048

// Phase-A blob layout (floats) per (chunk n, head h):
#define OY   0            // Y   [16][192]  = T * (b k e^G)
#define OQ   3072         // Qa  [16][192]  = q e^G
#define OC   6144         // KcT [192][20]  = (k e^{-G} * lam)^T, rows padded to 20
#define OPL  9984         // PL  [16][16]   incl-lower  Qa.Kap^T
#define OU   10240        // u'  [16][128]  = T (b v)
#define OLAM 12288        // lam [192]      = e^{G_15}
#define PABLK 12480

// ---------------------------------------------------------------------------
// Multi-region f32 GEMM (unchanged from R6): up to 3 independent problems,
// 128x64 tile, 8x4 acc/thread. M%128==0, N%64==0, K%16==0.
// ---------------------------------------------------------------------------
__global__ __launch_bounds__(256, 2) void gemm_multi(
    const float* __restrict__ A0, const float* __restrict__ B0, float* __restrict__ C0,
    int K0, int N0, int T0,
    const float* __restrict__ A1, const float* __restrict__ B1, float* __restrict__ C1,
    int K1, int N1, int T1,
    const float* __restrict__ A2, const float* __restrict__ B2, float* __restrict__ C2,
    int K2, int N2, int T2)
{
    __shared__ float As[16][128];
    __shared__ float Bs[16][64];

    int bx = blockIdx.x;
    const float* A; const float* B; float* C; int K, N;
    if (bx < T0)            { A = A0; B = B0; C = C0; K = K0; N = N0; }
    else if (bx < T0 + T1)  { bx -= T0; A = A1; B = B1; C = C1; K = K1; N = N1; }
    else                    { bx -= T0 + T1; A = A2; B = B2; C = C2; K = K2; N = N2; }

    const int tid = threadIdx.x;
    const int bm = blockIdx.y * 128, bn = bx * 64;
    const int tm = tid >> 4, tn = tid & 15;
    const int ar = tid >> 1, ak8 = (tid & 1) * 8;
    const int bk = tid >> 4, bc4 = (tid & 15) * 4;

    float acc[8][4];
#pragma unroll
    for (int i = 0; i < 8; i++)
#pragma unroll
        for (int j = 0; j < 4; j++) acc[i][j] = 0.f;

    const float* Ar = A + (size_t)(bm + ar) * K + ak8;
    const float* Br = B + bn + bc4;

    float4 av0 = *(const float4*)(Ar);
    float4 av1 = *(const float4*)(Ar + 4);
    float4 bv  = *(const float4*)(Br + (size_t)bk * N);

    for (int k0 = 0;; k0 += 16) {
        __syncthreads();
        As[ak8 + 0][ar] = av0.x; As[ak8 + 1][ar] = av0.y;
        As[ak8 + 2][ar] = av0.z; As[ak8 + 3][ar] = av0.w;
        As[ak8 + 4][ar] = av1.x; As[ak8 + 5][ar] = av1.y;
        As[ak8 + 6][ar] = av1.z; As[ak8 + 7][ar] = av1.w;
        *(float4*)&Bs[bk][bc4] = bv;
        __syncthreads();

        const bool more = (k0 + 16) < K;
        if (more) {
            av0 = *(const float4*)(Ar + k0 + 16);
            av1 = *(const float4*)(Ar + k0 + 20);
            bv  = *(const float4*)(Br + (size_t)(k0 + 16 + bk) * N);
        }

#pragma unroll
        for (int kk = 0; kk < 16; kk++) {
            float4 a0 = *(const float4*)&As[kk][tm * 8];
            float4 a1 = *(const float4*)&As[kk][tm * 8 + 4];
            float4 b0 = *(const float4*)&Bs[kk][tn * 4];
            float aa[8] = {a0.x, a0.y, a0.z, a0.w, a1.x, a1.y, a1.z, a1.w};
            float bb[4] = {b0.x, b0.y, b0.z, b0.w};
#pragma unroll
            for (int i = 0; i < 8; i++)
#pragma unroll
                for (int j = 0; j < 4; j++)
                    acc[i][j] = fmaf(aa[i], bb[j], acc[i][j]);
        }
        if (!more) break;
    }

#pragma unroll
    for (int i = 0; i < 8; i++) {
        float4 v = make_float4(acc[i][0], acc[i][1], acc[i][2], acc[i][3]);
        *(float4*)&C[(size_t)(bm + tm * 8 + i) * N + bn + tn * 4] = v;
    }
}

// ---------------------------------------------------------------------------
__global__ __launch_bounds__(256) void rmsnorm_rows(
    const float* __restrict__ in, int in_stride, const float* __restrict__ w,
    float* __restrict__ out, int out_stride, int ncols, float inv_n)
{
    const int t = blockIdx.x;
    const int tid = threadIdx.x;
    const float* row = in + (size_t)t * in_stride;
    float ss = 0.f;
    for (int c = tid; c < ncols; c += 256) { float v = row[c]; ss += v * v; }
#pragma unroll
    for (int m = 1; m < 64; m <<= 1) ss += __shfl_xor(ss, m);
    __shared__ float red[4];
    if ((tid & 63) == 0) red[tid >> 6] = ss;
    __syncthreads();
    float tot = red[0] + red[1] + red[2] + red[3];
    float scale = rsqrtf(tot * inv_n + 1e-5f);
    for (int c = tid; c < ncols; c += 256)
        out[(size_t)t * out_stride + c] = row[c] * scale * w[c];
}

// ---------------------------------------------------------------------------
// la = log_sigmoid(gpre + bias), HEAD-MAJOR: la_h[h][t][192]
// ---------------------------------------------------------------------------
__global__ __launch_bounds__(256) void logsig_relayout(
    const float* __restrict__ g, const float* __restrict__ bias,
    float* __restrict__ la_h)
{
    int i = blockIdx.x * 256 + threadIdx.x;   // < TT*HDK
    int t = i / HDK, col = i - t * HDK;
    int h = col / DK, d = col - h * DK;
    float z = g[i] + bias[col];
    // log_sigmoid(z) = min(z,0) - log1p(exp(-|z|))
    float la = fminf(z, 0.f) - log1pf(__expf(-fabsf(z)));
    la_h[((size_t)h * TT + t) * DK + d] = la;
}

// ---------------------------------------------------------------------------
__global__ __launch_bounds__(256) void beta_kernel(
    const float* __restrict__ x, const float* __restrict__ wb,
    float* __restrict__ beta)
{
    const int lane = threadIdx.x & 63, wv = threadIdx.x >> 6;
    const int p = blockIdx.x * 4 + wv;        // p = t*8 + h
    const int t = p >> 3, h = p & 7;
    const float* xr = x + (size_t)t * DIM;
    float s = 0.f;
    for (int e = lane; e < DIM; e += 64) s += xr[e] * wb[e * HH + h];
#pragma unroll
    for (int m = 1; m < 64; m <<= 1) s += __shfl_xor(s, m);
    if (lane == 0) beta[p] = 1.f / (1.f + expf(-s));
}

// ---------------------------------------------------------------------------
// l2norm(q)*DK^-0.5 and build+l2norm k; outputs HEAD-MAJOR [h][t][192].
// ---------------------------------------------------------------------------
__global__ __launch_bounds__(256) void prep_qk(
    const float* __restrict__ qraw, const float* __restrict__ kvb,
    const float* __restrict__ kv_all, float* __restrict__ q_h,
    float* __restrict__ k_h)
{
    const int lane = threadIdx.x & 63, wv = threadIdx.x >> 6;
    const int p = blockIdx.x * 4 + wv;
    const int t = p >> 3, h = p & 7;

    const float* qrow = qraw + (size_t)t * HDK + h * DK;
    float q0 = qrow[lane], q1 = qrow[lane + 64], q2 = qrow[lane + 128];
    float ss = q0 * q0 + q1 * q1 + q2 * q2;
#pragma unroll
    for (int m = 1; m < 64; m <<= 1) ss += __shfl_xor(ss, m);
    float sc = rsqrtf(ss + 1e-6f) * 0.07216878364870323f;  // * DK^-0.5
    float* qo = q_h + ((size_t)h * TT + t) * DK;
    qo[lane] = q0 * sc; qo[lane + 64] = q1 * sc; qo[lane + 128] = q2 * sc;

    const float* knope = kvb + (size_t)t * HKV + h * (DNOPE + DV);
    float k0 = knope[lane], k1 = knope[lane + 64];
    float k2 = kv_all[(size_t)t * (KVLR + DROPE) + KVLR + lane];
    float ks = k0 * k0 + k1 * k1 + k2 * k2;
#pragma unroll
    for (int m = 1; m < 64; m <<= 1) ks += __shfl_xor(ks, m);
    float kc = rsqrtf(ks + 1e-6f);
    float* ko = k_h + ((size_t)h * TT + t) * DK;
    ko[lane] = k0 * kc; ko[lane + 64] = k1 * kc; ko[lane + 128] = k2 * kc;
}

// ---------------------------------------------------------------------------
__device__ __forceinline__ float dpp_xor1(float x) {
    return __int_as_float(__builtin_amdgcn_update_dpp(
        0, __float_as_int(x), 0xB1, 0xF, 0xF, false));
}

__device__ __forceinline__ void gl_lds16(const float* g, float* l) {
    __builtin_amdgcn_global_load_lds(
        (const __attribute__((address_space(1))) void*)g,
        (__attribute__((address_space(3))) void*)l, 16, 0, 0);
}
__device__ __forceinline__ void gl_lds4(const float* g, float* l) {
    __builtin_amdgcn_global_load_lds(
        (const __attribute__((address_space(1))) void*)g,
        (__attribute__((address_space(3))) void*)l, 4, 0, 0);
}

// ---------------------------------------------------------------------------
// Phase A: per-(chunk,head) S-independent quantities (as R7, but KcT rows
// padded to 20 floats so Phase B's LDS reads are conflict-free).
// ---------------------------------------------------------------------------
__global__ __launch_bounds__(256) void chunk_prep(
    const float* __restrict__ k_h, const float* __restrict__ la_h,
    const float* __restrict__ q_h, const float* __restrict__ kvb,
    const float* __restrict__ betab, float* __restrict__ pa)
{
    __shared__ float Ls[16][196];  // la -> G (in place)
    __shared__ float Ks[16][196];  // k  -> Kap
    __shared__ float Qs[16][196];  // q  -> Qa
    __shared__ float Ws[16][196];  // Wb
    __shared__ float Xs[16][196];  // relayout scratch
    __shared__ float Ms[16][16];
    __shared__ float bs[16];

    const int tid = threadIdx.x;
    const int n = blockIdx.x >> 3, h = blockIdx.x & 7;
    const size_t g0 = ((size_t)h * TT + n * 16) * DK;
    float* blob = pa + (size_t)blockIdx.x * PABLK;

#pragma unroll
    for (int s = 0; s < 3; s++) {
        int off = (tid * 3 + s) * 4;
        int r = off / 192, c = off - r * 192;
        *(float4*)&Ks[r][c] = *(const float4*)(k_h + g0 + off);
        *(float4*)&Ls[r][c] = *(const float4*)(la_h + g0 + off);
        *(float4*)&Qs[r][c] = *(const float4*)(q_h + g0 + off);
    }
    if (tid < 16) bs[tid] = betab[(size_t)(n * 16 + tid) * HH + h];
    __syncthreads();

    if (tid < 192) {
        float g = 0.f;
#pragma unroll
        for (int i = 0; i < 16; i++) { g += Ls[i][tid]; Ls[i][tid] = g; }
    }
    __syncthreads();

#pragma unroll
    for (int s = 0; s < 12; s++) {
        int idx = s * 256 + tid;
        int i = idx / 192, d = idx - i * 192;
        float G = Ls[i][d];
        float eg = __expf(G), en = __expf(-G);
        float kk = Ks[i][d];
        Ws[i][d] = bs[i] * kk * eg;
        Qs[i][d] *= eg;
        Ks[i][d] = kk * en;
    }
    __syncthreads();

    // Qa out (coalesced)
#pragma unroll
    for (int s = 0; s < 3; s++) {
        int off = (tid * 3 + s) * 4;
        int r = off / 192, c = off - r * 192;
        *(float4*)(blob + OQ + off) = *(const float4*)&Qs[r][c];
    }
    // KcT (padded rows of 20) + lam out
    if (tid < 192) {
        float lam = __expf(Ls[15][tid]);
        blob[OLAM + tid] = lam;
#pragma unroll
        for (int j4 = 0; j4 < 4; j4++) {
            float4 v;
            v.x = Ks[j4 * 4 + 0][tid] * lam; v.y = Ks[j4 * 4 + 1][tid] * lam;
            v.z = Ks[j4 * 4 + 2][tid] * lam; v.w = Ks[j4 * 4 + 3][tid] * lam;
            *(float4*)(blob + OC + tid * 20 + j4 * 4) = v;
        }
        blob[OC + tid * 20 + 16] = 0.f; blob[OC + tid * 20 + 17] = 0.f;
        blob[OC + tid * 20 + 18] = 0.f; blob[OC + tid * 20 + 19] = 0.f;
    }
    // M & PL gemms (thread per (i,j))
    {
        const int i = tid >> 4, j = tid & 15;
        float m = 0.f, p = 0.f;
#pragma unroll
        for (int d4 = 0; d4 < 48; d4++) {
            float4 w  = *(const float4*)&Ws[i][d4 * 4];
            float4 ka = *(const float4*)&Ks[j][d4 * 4];
            float4 qa = *(const float4*)&Qs[i][d4 * 4];
            m += w.x * ka.x + w.y * ka.y + w.z * ka.z + w.w * ka.w;
            p += qa.x * ka.x + qa.y * ka.y + qa.z * ka.z + qa.w * ka.w;
        }
        Ms[i][j] = (j < i) ? m : 0.f;
        blob[OPL + tid] = (j <= i) ? p : 0.f;
    }
    __syncthreads();

    // forward substitution (unit lower-triangular I+M)
    float y[16], uu[16];
    const bool doY = (tid < 192);
    const bool doU = (tid >= 128);
    const int dcol = tid, ccol = tid - 128;
    if (doY) {
#pragma unroll
        for (int i = 0; i < 16; i++) y[i] = Ws[i][dcol];
#pragma unroll
        for (int i = 1; i < 16; i++)
#pragma unroll
            for (int j = 0; j < i; j++)
                y[i] = fmaf(-Ms[i][j], y[j], y[i]);
    }
    if (doU) {
#pragma unroll
        for (int i = 0; i < 16; i++)
            uu[i] = bs[i] * kvb[(size_t)(n * 16 + i) * HKV + h * (DNOPE + DV) + DNOPE + ccol];
#pragma unroll
        for (int i = 1; i < 16; i++)
#pragma unroll
            for (int j = 0; j < i; j++)
                uu[i] = fmaf(-Ms[i][j], uu[j], uu[i]);
    }
    // Y out via relayout
    if (doY) {
#pragma unroll
        for (int i = 0; i < 16; i++) Xs[i][dcol] = y[i];
    }
    __syncthreads();
#pragma unroll
    for (int s = 0; s < 3; s++) {
        int off = (tid * 3 + s) * 4;
        int r = off / 192, c = off - r * 192;
        *(float4*)(blob + OY + off) = *(const float4*)&Xs[r][c];
    }
    __syncthreads();
    if (doU) {
#pragma unroll
        for (int i = 0; i < 16; i++) Xs[i][ccol] = uu[i];
    }
    __syncthreads();
#pragma unroll
    for (int s = 0; s < 2; s++) {
        int off = (tid * 2 + s) * 4;
        int r = off / 128, c = off - r * 128;
        *(float4*)(blob + OU + off) = *(const float4*)&Xs[r][c];
    }
}

// ---------------------------------------------------------------------------
// Phase B: sequential over 64 chunks; block owns (head, 8 v-columns) state
// slice S[192][8] in LDS. Per chunk:
//   z=Y.S, zq=Qa.S ; u = u' - z ; o = zq + PL u ; S = lam*S + KcT u
// UNSKEWED z/zq reads: Y/Q addrs = f(ti,half) -> 8-lane broadcast across cc;
// S addrs = f(cc,half) -> 4-lane broadcast across ti; 196-float row stride
// (== 4 mod 32) spreads cc over distinct bank-quads. KcT rows padded to 20
// floats (stride 20 cycles 8 bank-quads) -> conflict-free update reads.
// ---------------------------------------------------------------------------
__global__ __launch_bounds__(256) void kda_chunk(
    const float* __restrict__ pa, float* __restrict__ ob)
{
    __shared__ float Yb[2][3136];   // [16][196] padded rows
    __shared__ float Qb[2][3136];
    __shared__ float Cb[2][3840];   // KcT [192][20] padded rows
    __shared__ float Pb[2][256];
    __shared__ float ubs[2][128];   // u' slice [16][8]
    __shared__ float lbs[2][192];
    __shared__ float Ss[1568];      // state [8][196]
    __shared__ float us[144];       // u [16][9]

    const int tid = threadIdx.x;
    const int w = tid >> 6, lane = tid & 63;
    const int h = blockIdx.x >> 4, cg = blockIdx.x & 15;
    const int c0 = cg * 8;

    auto stage = [&](int buf, int n) {
        const float* blob = pa + (size_t)(n * 8 + h) * PABLK;
        if (w == 0) {
            if (lane < 48)
#pragma unroll
                for (int r = 0; r < 16; r++)
                    gl_lds16(blob + OY + r * 192 + lane * 4, &Yb[buf][r * 196]);
        } else if (w == 1) {
            if (lane < 48)
#pragma unroll
                for (int r = 0; r < 16; r++)
                    gl_lds16(blob + OQ + r * 192 + lane * 4, &Qb[buf][r * 196]);
        } else if (w == 2) {
#pragma unroll
            for (int s = 0; s < 15; s++)
                gl_lds16(blob + OC + s * 256 + lane * 4, &Cb[buf][s * 256]);
        } else {
            gl_lds16(blob + OPL + lane * 4, &Pb[buf][0]);
            gl_lds4(blob + OU + (lane >> 3) * 128 + c0 + (lane & 7), &ubs[buf][0]);
            gl_lds4(blob + OU + (8 + (lane >> 3)) * 128 + c0 + (lane & 7), &ubs[buf][64]);
            if (lane < 48)
                gl_lds16(blob + OLAM + lane * 4, &lbs[buf][0]);
        }
    };

    for (int idx = tid; idx < 1568; idx += 256) Ss[idx] = 0.f;
    stage(0, 0);
    stage(1, 1);

    const int ti = tid >> 4, cc = (tid >> 1) & 7, half = tid & 1;
    const int dg = tid >> 3, c2 = tid & 7;

    for (int n = 0; n < TT / 16; n++) {
        const int buf = n & 1;
        __syncthreads();   // A: buf staged (vmcnt drained), prev update done

        // z = Y.S, zq = Qa.S over this lane's 96-d half (unskewed, broadcast)
        const float* Yr = &Yb[buf][ti * 196 + half * 96];
        const float* Qr = &Qb[buf][ti * 196 + half * 96];
        const float* Sr = &Ss[cc * 196 + half * 96];
        float zy0 = 0.f, zy1 = 0.f, zq0 = 0.f, zq1 = 0.f;
#pragma unroll 8
        for (int s = 0; s < 24; s++) {
            float4 yv = *(const float4*)(Yr + s * 4);
            float4 qv = *(const float4*)(Qr + s * 4);
            float4 sv = *(const float4*)(Sr + s * 4);
            zy0 = fmaf(yv.x, sv.x, zy0); zy1 = fmaf(yv.y, sv.y, zy1);
            zy0 = fmaf(yv.z, sv.z, zy0); zy1 = fmaf(yv.w, sv.w, zy1);
            zq0 = fmaf(qv.x, sv.x, zq0); zq1 = fmaf(qv.y, sv.y, zq1);
            zq0 = fmaf(qv.z, sv.z, zq0); zq1 = fmaf(qv.w, sv.w, zq1);
        }
        float zy = zy0 + zy1; zy += dpp_xor1(zy);
        float zq = zq0 + zq1; zq += dpp_xor1(zq);
        float u_ic = ubs[buf][ti * 8 + cc] - zy;
        if (half == 0) us[ti * 9 + cc] = u_ic;
        __syncthreads();   // B: us ready

        // o = zq + PL u  (j-parity split across half, combined via xor1)
        float acc = 0.f;
        for (int j = half; j <= ti; j += 2)
            acc = fmaf(Pb[buf][ti * 16 + j], us[j * 9 + cc], acc);
        acc += dpp_xor1(acc);
        float ov = zq + acc;
        if (isnan(ov)) ov = 0.f;
        else if (isinf(ov)) ov = ov > 0.f ? 1e4f : -1e4f;
        if (half == 0)
            ob[(size_t)(n * 16 + ti) * (HH * DV) + h * DV + c0 + cc] = ov;

        // state update: S[d][c2] = lam[d] S + sum_j KcT[d][j] u[j][c2]
        float uu2[16];
#pragma unroll
        for (int j = 0; j < 16; j++) uu2[j] = us[j * 9 + c2];
#pragma unroll
        for (int s = 0; s < 6; s++) {
            int d = dg * 6 + s;
            float sv = Ss[c2 * 196 + d];
            float a2 = lbs[buf][d] * sv;
            const float4* C4 = (const float4*)&Cb[buf][d * 20];
            float4 k0 = C4[0], k1 = C4[1], k2 = C4[2], k3 = C4[3];
            a2 = fmaf(k0.x, uu2[0],  a2); a2 = fmaf(k0.y, uu2[1],  a2);
            a2 = fmaf(k0.z, uu2[2],  a2); a2 = fmaf(k0.w, uu2[3],  a2);
            a2 = fmaf(k1.x, uu2[4],  a2); a2 = fmaf(k1.y, uu2[5],  a2);
            a2 = fmaf(k1.z, uu2[6],  a2); a2 = fmaf(k1.w, uu2[7],  a2);
            a2 = fmaf(k2.x, uu2[8],  a2); a2 = fmaf(k2.y, uu2[9],  a2);
            a2 = fmaf(k2.z, uu2[10], a2); a2 = fmaf(k2.w, uu2[11], a2);
            a2 = fmaf(k3.x, uu2[12], a2); a2 = fmaf(k3.y, uu2[13], a2);
            a2 = fmaf(k3.z, uu2[14], a2); a2 = fmaf(k3.w, uu2[15], a2);
            Ss[c2 * 196 + d] = a2;
        }
        __syncthreads();   // C: buf fully consumed, Ss updated
        if (n + 2 < TT / 16) stage(buf, n + 2);
    }
}

// ---------------------------------------------------------------------------
extern "C" void kernel_launch(void* const* d_in, const int* in_sizes, int n_in,
                              void* d_out, int out_size, void* d_ws, size_t ws_size,
                              hipStream_t stream)
{
    const float* x         = (const float*)d_in[0];
    // d_in[1] = cos, d_in[2] = sin : unused by the reference
    const float* wq_a      = (const float*)d_in[3];
    const float* q_norm_w  = (const float*)d_in[4];
    const float* wq_b      = (const float*)d_in[5];
    const float* wkv_a     = (const float*)d_in[6];
    const float* kv_norm_w = (const float*)d_in[7];
    const float* wkv_b     = (const float*)d_in[8];
    const float* wg_w      = (const float*)d_in[9];
    const float* wg_b      = (const float*)d_in[10];
    const float* wb        = (const float*)d_in[11];
    const float* wo        = (const float*)d_in[12];
    float* out = (float*)d_out;

    float* ws = (float*)d_ws;
    float* xq     = ws;                        // T x 768 (rms in-place)
    float* kv_all = xq     + TT * QLR;         // T x 576
    float* kvn    = kv_all + TT * (KVLR + DROPE); // T x 512
    float* agraw  = kvn    + TT * KVLR;        // T x 1536 (dead after logsig)
    float* ob     = agraw;                     // alias: T x 1024 (scan output)
    float* qnraw  = agraw  + TT * HDK;         // T x 1536 (dead after prep_qk)
    float* kvb    = qnraw  + TT * HDK;         // T x 2048
    float* la_h   = kvb    + TT * HKV;         // 8 x 1024 x 192
    float* q_h    = la_h   + TT * HDK;         // 8 x 1024 x 192
    float* k_h    = q_h    + TT * HDK;         // 8 x 1024 x 192
    float* betab  = k_h    + TT * HDK;         // T x 8
    float* pa     = betab  + TT * HH;          // 512 x PABLK (25.6 MB)

    dim3 blk(256);

    // x projections fused: {wq_a (12), wkv_a (9), wg_w (24)} = 45 x 8 blocks
    gemm_multi<<<dim3(12 + 9 + 24, TT / 128), blk, 0, stream>>>(
        x, wq_a, xq,    DIM, QLR, 12,
        x, wkv_a, kv_all, DIM, KVLR + DROPE, 9,
        x, wg_w, agraw, DIM, HDK, 24);

    // norms
    rmsnorm_rows<<<TT, blk, 0, stream>>>(xq, QLR, q_norm_w, xq, QLR, QLR, 1.f / QLR);
    rmsnorm_rows<<<TT, blk, 0, stream>>>(kv_all, KVLR + DROPE, kv_norm_w, kvn, KVLR, KVLR, 1.f / KVLR);

    // low-rank expansions fused: {wq_b (24), wkv_b (32)} = 56 x 8 blocks
    gemm_multi<<<dim3(24 + 32, TT / 128), blk, 0, stream>>>(
        xq, wq_b, qnraw, QLR, HDK, 24,
        kvn, wkv_b, kvb, KVLR, HKV, 32,
        x, wq_a, xq, DIM, QLR, 0);   // unused region

    // gates
    logsig_relayout<<<(TT * HDK + 255) / 256, blk, 0, stream>>>(agraw, wg_b, la_h);
    beta_kernel<<<TT * HH / 4, blk, 0, stream>>>(x, wb, betab);

    // l2norm q, build+l2norm k (head-major)
    prep_qk<<<TT * HH / 4, blk, 0, stream>>>(qnraw, kvb, kv_all, q_h, k_h);

    // chunked delta rule: phase A (parallel) + phase B (sequential chunks)
    chunk_prep<<<512, blk, 0, stream>>>(k_h, la_h, q_h, kvb, betab, pa);
    kda_chunk<<<128, blk, 0, stream>>>(pa, ob);

    // output projection: 16 x 8 blocks
    gemm_multi<<<dim3(16, TT / 128), blk, 0, stream>>>(
        ob, wo, out, DIM, DIM, 16,
        ob, wo, out, DIM, DIM, 0,
        ob, wo, out, DIM, DIM, 0);
}

// Round 9
// 484.865 us; speedup vs baseline: 2.3111x; 1.0940x over previous
//
#include <hip/hip_runtime.h>
#include <hip/hip_bf16.h>
#include <math.h>

// Problem constants
#define TT 1024
#define DIM 1024
#define HH 8
#define QLR 768
#define KVLR 512
#define DNOPE 128
#define DROPE 64
#define DV 128
#define DK 192            // DNOPE + DROPE
#define HDK (HH*DK)       // 1536
#define HKV (HH*(DNOPE+DV)) // 2048

// Phase-A blob layout (floats) per (chunk n, head h):
#define OY   0            // Y   [16][192]  = T * (b k e^G)
#define OQ   3072         // Qa  [16][192]  = q e^G
#define OC   6144         // KcT [192][20]  = (k e^{-G} * lam)^T, rows padded to 20
#define OPL  9984         // PL  [16][16]   incl-lower  Qa.Kap^T
#define OU   10240        // u'  [16][128]  = T (b v)
#define OLAM 12288        // lam [192]      = e^{G_15}
#define PABLK 12480

// ---------------------------------------------------------------------------
// Multi-region f32 GEMM (unchanged): up to 3 independent problems,
// 128x64 tile, 8x4 acc/thread. M%128==0, N%64==0, K%16==0.
// ---------------------------------------------------------------------------
__global__ __launch_bounds__(256, 2) void gemm_multi(
    const float* __restrict__ A0, const float* __restrict__ B0, float* __restrict__ C0,
    int K0, int N0, int T0,
    const float* __restrict__ A1, const float* __restrict__ B1, float* __restrict__ C1,
    int K1, int N1, int T1,
    const float* __restrict__ A2, const float* __restrict__ B2, float* __restrict__ C2,
    int K2, int N2, int T2)
{
    __shared__ float As[16][128];
    __shared__ float Bs[16][64];

    int bx = blockIdx.x;
    const float* A; const float* B; float* C; int K, N;
    if (bx < T0)            { A = A0; B = B0; C = C0; K = K0; N = N0; }
    else if (bx < T0 + T1)  { bx -= T0; A = A1; B = B1; C = C1; K = K1; N = N1; }
    else                    { bx -= T0 + T1; A = A2; B = B2; C = C2; K = K2; N = N2; }

    const int tid = threadIdx.x;
    const int bm = blockIdx.y * 128, bn = bx * 64;
    const int tm = tid >> 4, tn = tid & 15;
    const int ar = tid >> 1, ak8 = (tid & 1) * 8;
    const int bk = tid >> 4, bc4 = (tid & 15) * 4;

    float acc[8][4];
#pragma unroll
    for (int i = 0; i < 8; i++)
#pragma unroll
        for (int j = 0; j < 4; j++) acc[i][j] = 0.f;

    const float* Ar = A + (size_t)(bm + ar) * K + ak8;
    const float* Br = B + bn + bc4;

    float4 av0 = *(const float4*)(Ar);
    float4 av1 = *(const float4*)(Ar + 4);
    float4 bv  = *(const float4*)(Br + (size_t)bk * N);

    for (int k0 = 0;; k0 += 16) {
        __syncthreads();
        As[ak8 + 0][ar] = av0.x; As[ak8 + 1][ar] = av0.y;
        As[ak8 + 2][ar] = av0.z; As[ak8 + 3][ar] = av0.w;
        As[ak8 + 4][ar] = av1.x; As[ak8 + 5][ar] = av1.y;
        As[ak8 + 6][ar] = av1.z; As[ak8 + 7][ar] = av1.w;
        *(float4*)&Bs[bk][bc4] = bv;
        __syncthreads();

        const bool more = (k0 + 16) < K;
        if (more) {
            av0 = *(const float4*)(Ar + k0 + 16);
            av1 = *(const float4*)(Ar + k0 + 20);
            bv  = *(const float4*)(Br + (size_t)(k0 + 16 + bk) * N);
        }

#pragma unroll
        for (int kk = 0; kk < 16; kk++) {
            float4 a0 = *(const float4*)&As[kk][tm * 8];
            float4 a1 = *(const float4*)&As[kk][tm * 8 + 4];
            float4 b0 = *(const float4*)&Bs[kk][tn * 4];
            float aa[8] = {a0.x, a0.y, a0.z, a0.w, a1.x, a1.y, a1.z, a1.w};
            float bb[4] = {b0.x, b0.y, b0.z, b0.w};
#pragma unroll
            for (int i = 0; i < 8; i++)
#pragma unroll
                for (int j = 0; j < 4; j++)
                    acc[i][j] = fmaf(aa[i], bb[j], acc[i][j]);
        }
        if (!more) break;
    }

#pragma unroll
    for (int i = 0; i < 8; i++) {
        float4 v = make_float4(acc[i][0], acc[i][1], acc[i][2], acc[i][3]);
        *(float4*)&C[(size_t)(bm + tm * 8 + i) * N + bn + tn * 4] = v;
    }
}

// ---------------------------------------------------------------------------
__global__ __launch_bounds__(256) void rmsnorm_rows(
    const float* __restrict__ in, int in_stride, const float* __restrict__ w,
    float* __restrict__ out, int out_stride, int ncols, float inv_n)
{
    const int t = blockIdx.x;
    const int tid = threadIdx.x;
    const float* row = in + (size_t)t * in_stride;
    float ss = 0.f;
    for (int c = tid; c < ncols; c += 256) { float v = row[c]; ss += v * v; }
#pragma unroll
    for (int m = 1; m < 64; m <<= 1) ss += __shfl_xor(ss, m);
    __shared__ float red[4];
    if ((tid & 63) == 0) red[tid >> 6] = ss;
    __syncthreads();
    float tot = red[0] + red[1] + red[2] + red[3];
    float scale = rsqrtf(tot * inv_n + 1e-5f);
    for (int c = tid; c < ncols; c += 256)
        out[(size_t)t * out_stride + c] = row[c] * scale * w[c];
}

// ---------------------------------------------------------------------------
// la = log_sigmoid(gpre + bias), HEAD-MAJOR: la_h[h][t][192]
// ---------------------------------------------------------------------------
__global__ __launch_bounds__(256) void logsig_relayout(
    const float* __restrict__ g, const float* __restrict__ bias,
    float* __restrict__ la_h)
{
    int i = blockIdx.x * 256 + threadIdx.x;   // < TT*HDK
    int t = i / HDK, col = i - t * HDK;
    int h = col / DK, d = col - h * DK;
    float z = g[i] + bias[col];
    // log_sigmoid(z) = min(z,0) - log1p(exp(-|z|))
    float la = fminf(z, 0.f) - log1pf(__expf(-fabsf(z)));
    la_h[((size_t)h * TT + t) * DK + d] = la;
}

// ---------------------------------------------------------------------------
__global__ __launch_bounds__(256) void beta_kernel(
    const float* __restrict__ x, const float* __restrict__ wb,
    float* __restrict__ beta)
{
    const int lane = threadIdx.x & 63, wv = threadIdx.x >> 6;
    const int p = blockIdx.x * 4 + wv;        // p = t*8 + h
    const int t = p >> 3, h = p & 7;
    const float* xr = x + (size_t)t * DIM;
    float s = 0.f;
    for (int e = lane; e < DIM; e += 64) s += xr[e] * wb[e * HH + h];
#pragma unroll
    for (int m = 1; m < 64; m <<= 1) s += __shfl_xor(s, m);
    if (lane == 0) beta[p] = 1.f / (1.f + expf(-s));
}

// ---------------------------------------------------------------------------
// l2norm(q)*DK^-0.5 and build+l2norm k; outputs HEAD-MAJOR [h][t][192].
// ---------------------------------------------------------------------------
__global__ __launch_bounds__(256) void prep_qk(
    const float* __restrict__ qraw, const float* __restrict__ kvb,
    const float* __restrict__ kv_all, float* __restrict__ q_h,
    float* __restrict__ k_h)
{
    const int lane = threadIdx.x & 63, wv = threadIdx.x >> 6;
    const int p = blockIdx.x * 4 + wv;
    const int t = p >> 3, h = p & 7;

    const float* qrow = qraw + (size_t)t * HDK + h * DK;
    float q0 = qrow[lane], q1 = qrow[lane + 64], q2 = qrow[lane + 128];
    float ss = q0 * q0 + q1 * q1 + q2 * q2;
#pragma unroll
    for (int m = 1; m < 64; m <<= 1) ss += __shfl_xor(ss, m);
    float sc = rsqrtf(ss + 1e-6f) * 0.07216878364870323f;  // * DK^-0.5
    float* qo = q_h + ((size_t)h * TT + t) * DK;
    qo[lane] = q0 * sc; qo[lane + 64] = q1 * sc; qo[lane + 128] = q2 * sc;

    const float* knope = kvb + (size_t)t * HKV + h * (DNOPE + DV);
    float k0 = knope[lane], k1 = knope[lane + 64];
    float k2 = kv_all[(size_t)t * (KVLR + DROPE) + KVLR + lane];
    float ks = k0 * k0 + k1 * k1 + k2 * k2;
#pragma unroll
    for (int m = 1; m < 64; m <<= 1) ks += __shfl_xor(ks, m);
    float kc = rsqrtf(ks + 1e-6f);
    float* ko = k_h + ((size_t)h * TT + t) * DK;
    ko[lane] = k0 * kc; ko[lane + 64] = k1 * kc; ko[lane + 128] = k2 * kc;
}

// ---------------------------------------------------------------------------
__device__ __forceinline__ float dpp_xor1(float x) {
    return __int_as_float(__builtin_amdgcn_update_dpp(
        0, __float_as_int(x), 0xB1, 0xF, 0xF, false));
}
__device__ __forceinline__ float dpp_xor2(float x) {
    return __int_as_float(__builtin_amdgcn_update_dpp(
        0, __float_as_int(x), 0x4E, 0xF, 0xF, false));
}
// 16-lane sum (lanes grouped by lane&15): xor1, xor2, half-mirror, mirror.
// Verified on-device in R2 (kda_scan3 passed).
__device__ __forceinline__ float red16(float x) {
    x += dpp_xor1(x);
    x += dpp_xor2(x);
    x += __int_as_float(__builtin_amdgcn_update_dpp(0, __float_as_int(x), 0x141, 0xF, 0xF, false));
    x += __int_as_float(__builtin_amdgcn_update_dpp(0, __float_as_int(x), 0x140, 0xF, 0xF, false));
    return x;
}

__device__ __forceinline__ void gl_lds16(const float* g, float* l) {
    __builtin_amdgcn_global_load_lds(
        (const __attribute__((address_space(1))) void*)g,
        (__attribute__((address_space(3))) void*)l, 16, 0, 0);
}
__device__ __forceinline__ void gl_lds4(const float* g, float* l) {
    __builtin_amdgcn_global_load_lds(
        (const __attribute__((address_space(1))) void*)g,
        (__attribute__((address_space(3))) void*)l, 4, 0, 0);
}

// ---------------------------------------------------------------------------
// Phase A: per-(chunk,head) S-independent quantities (unchanged from R8).
// ---------------------------------------------------------------------------
__global__ __launch_bounds__(256) void chunk_prep(
    const float* __restrict__ k_h, const float* __restrict__ la_h,
    const float* __restrict__ q_h, const float* __restrict__ kvb,
    const float* __restrict__ betab, float* __restrict__ pa)
{
    __shared__ float Ls[16][196];  // la -> G (in place)
    __shared__ float Ks[16][196];  // k  -> Kap
    __shared__ float Qs[16][196];  // q  -> Qa
    __shared__ float Ws[16][196];  // Wb
    __shared__ float Xs[16][196];  // relayout scratch
    __shared__ float Ms[16][16];
    __shared__ float bs[16];

    const int tid = threadIdx.x;
    const int n = blockIdx.x >> 3, h = blockIdx.x & 7;
    const size_t g0 = ((size_t)h * TT + n * 16) * DK;
    float* blob = pa + (size_t)blockIdx.x * PABLK;

#pragma unroll
    for (int s = 0; s < 3; s++) {
        int off = (tid * 3 + s) * 4;
        int r = off / 192, c = off - r * 192;
        *(float4*)&Ks[r][c] = *(const float4*)(k_h + g0 + off);
        *(float4*)&Ls[r][c] = *(const float4*)(la_h + g0 + off);
        *(float4*)&Qs[r][c] = *(const float4*)(q_h + g0 + off);
    }
    if (tid < 16) bs[tid] = betab[(size_t)(n * 16 + tid) * HH + h];
    __syncthreads();

    if (tid < 192) {
        float g = 0.f;
#pragma unroll
        for (int i = 0; i < 16; i++) { g += Ls[i][tid]; Ls[i][tid] = g; }
    }
    __syncthreads();

#pragma unroll
    for (int s = 0; s < 12; s++) {
        int idx = s * 256 + tid;
        int i = idx / 192, d = idx - i * 192;
        float G = Ls[i][d];
        float eg = __expf(G), en = __expf(-G);
        float kk = Ks[i][d];
        Ws[i][d] = bs[i] * kk * eg;
        Qs[i][d] *= eg;
        Ks[i][d] = kk * en;
    }
    __syncthreads();

    // Qa out (coalesced)
#pragma unroll
    for (int s = 0; s < 3; s++) {
        int off = (tid * 3 + s) * 4;
        int r = off / 192, c = off - r * 192;
        *(float4*)(blob + OQ + off) = *(const float4*)&Qs[r][c];
    }
    // KcT (padded rows of 20) + lam out
    if (tid < 192) {
        float lam = __expf(Ls[15][tid]);
        blob[OLAM + tid] = lam;
#pragma unroll
        for (int j4 = 0; j4 < 4; j4++) {
            float4 v;
            v.x = Ks[j4 * 4 + 0][tid] * lam; v.y = Ks[j4 * 4 + 1][tid] * lam;
            v.z = Ks[j4 * 4 + 2][tid] * lam; v.w = Ks[j4 * 4 + 3][tid] * lam;
            *(float4*)(blob + OC + tid * 20 + j4 * 4) = v;
        }
        blob[OC + tid * 20 + 16] = 0.f; blob[OC + tid * 20 + 17] = 0.f;
        blob[OC + tid * 20 + 18] = 0.f; blob[OC + tid * 20 + 19] = 0.f;
    }
    // M & PL gemms (thread per (i,j))
    {
        const int i = tid >> 4, j = tid & 15;
        float m = 0.f, p = 0.f;
#pragma unroll
        for (int d4 = 0; d4 < 48; d4++) {
            float4 w  = *(const float4*)&Ws[i][d4 * 4];
            float4 ka = *(const float4*)&Ks[j][d4 * 4];
            float4 qa = *(const float4*)&Qs[i][d4 * 4];
            m += w.x * ka.x + w.y * ka.y + w.z * ka.z + w.w * ka.w;
            p += qa.x * ka.x + qa.y * ka.y + qa.z * ka.z + qa.w * ka.w;
        }
        Ms[i][j] = (j < i) ? m : 0.f;
        blob[OPL + tid] = (j <= i) ? p : 0.f;
    }
    __syncthreads();

    // forward substitution (unit lower-triangular I+M)
    float y[16], uu[16];
    const bool doY = (tid < 192);
    const bool doU = (tid >= 128);
    const int dcol = tid, ccol = tid - 128;
    if (doY) {
#pragma unroll
        for (int i = 0; i < 16; i++) y[i] = Ws[i][dcol];
#pragma unroll
        for (int i = 1; i < 16; i++)
#pragma unroll
            for (int j = 0; j < i; j++)
                y[i] = fmaf(-Ms[i][j], y[j], y[i]);
    }
    if (doU) {
#pragma unroll
        for (int i = 0; i < 16; i++)
            uu[i] = bs[i] * kvb[(size_t)(n * 16 + i) * HKV + h * (DNOPE + DV) + DNOPE + ccol];
#pragma unroll
        for (int i = 1; i < 16; i++)
#pragma unroll
            for (int j = 0; j < i; j++)
                uu[i] = fmaf(-Ms[i][j], uu[j], uu[i]);
    }
    // Y out via relayout
    if (doY) {
#pragma unroll
        for (int i = 0; i < 16; i++) Xs[i][dcol] = y[i];
    }
    __syncthreads();
#pragma unroll
    for (int s = 0; s < 3; s++) {
        int off = (tid * 3 + s) * 4;
        int r = off / 192, c = off - r * 192;
        *(float4*)(blob + OY + off) = *(const float4*)&Xs[r][c];
    }
    __syncthreads();
    if (doU) {
#pragma unroll
        for (int i = 0; i < 16; i++) Xs[i][ccol] = uu[i];
    }
    __syncthreads();
#pragma unroll
    for (int s = 0; s < 2; s++) {
        int off = (tid * 2 + s) * 4;
        int r = off / 128, c = off - r * 128;
        *(float4*)(blob + OU + off) = *(const float4*)&Xs[r][c];
    }
}

// ---------------------------------------------------------------------------
// Phase B v2: 256 blocks (8 h x 32 colgroups of 4 v-cols), register-blocked.
// Thread map (z/zq): tid = tig*32 + ccg*16 + dg; tig:8 (2 ti each),
// ccg:2 (2 cc each), dg:16 (12 dims each). Each thread: 6 S + 6 Y + 6 Q
// float4 loads -> 8 partial dots (2ti x 2cc x {zy,zq}); red16 over dg
// (pure DPP). Update map: c2 = tid&3, dseg = tid>>2 (3 dims each); u read
// as float4 from us[4][20] (col-major).
// ---------------------------------------------------------------------------
__global__ __launch_bounds__(256) void kda_chunk(
    const float* __restrict__ pa, float* __restrict__ ob)
{
    __shared__ float Yb[2][3136];   // [16][196] padded rows
    __shared__ float Qb[2][3136];
    __shared__ float Cb[2][3840];   // KcT [192][20] padded rows
    __shared__ float Pb[2][256];
    __shared__ float ubs[2][64];    // u' slice [16][4]
    __shared__ float lbs[2][192];
    __shared__ float Ss[784];       // state [4 cc][196]
    __shared__ float us[80];        // u [4 cc][20] (ti index within row)

    const int tid = threadIdx.x;
    const int w = tid >> 6, lane = tid & 63;
    const int h = blockIdx.x >> 5, cg = blockIdx.x & 31;
    const int c0 = cg * 4;

    const int dg  = tid & 15;        // 12-dim segment (lane&15 -> red16 ok)
    const int ccg = (tid >> 4) & 1;
    const int tig = tid >> 5;

    auto stage = [&](int buf, int n) {
        const float* blob = pa + (size_t)(n * 8 + h) * PABLK;
        if (w == 0) {
            if (lane < 48)
#pragma unroll
                for (int r = 0; r < 16; r++)
                    gl_lds16(blob + OY + r * 192 + lane * 4, &Yb[buf][r * 196]);
        } else if (w == 1) {
            if (lane < 48)
#pragma unroll
                for (int r = 0; r < 16; r++)
                    gl_lds16(blob + OQ + r * 192 + lane * 4, &Qb[buf][r * 196]);
        } else if (w == 2) {
#pragma unroll
            for (int s = 0; s < 15; s++)
                gl_lds16(blob + OC + s * 256 + lane * 4, &Cb[buf][s * 256]);
        } else {
            gl_lds16(blob + OPL + lane * 4, &Pb[buf][0]);
            gl_lds4(blob + OU + (lane >> 2) * 128 + c0 + (lane & 3), &ubs[buf][0]);
            if (lane < 48)
                gl_lds16(blob + OLAM + lane * 4, &lbs[buf][0]);
        }
    };

    for (int idx = tid; idx < 784; idx += 256) Ss[idx] = 0.f;
    stage(0, 0);
    stage(1, 1);

    const int c2 = tid & 3, dseg = tid >> 2;   // update-phase map

    for (int n = 0; n < TT / 16; n++) {
        const int buf = n & 1;
        __syncthreads();   // A: buf staged (vmcnt drained), prev update done

        // ---- z/zq: register-blocked 2ti x 2cc over 12 dims ----
        const int dbase = dg * 12;
        float4 sv[2][3];
#pragma unroll
        for (int j = 0; j < 2; j++)
#pragma unroll
            for (int s = 0; s < 3; s++)
                sv[j][s] = *(const float4*)&Ss[(ccg * 2 + j) * 196 + dbase + s * 4];

        float py[2][2] = {{0.f, 0.f}, {0.f, 0.f}};
        float pq[2][2] = {{0.f, 0.f}, {0.f, 0.f}};
#pragma unroll
        for (int i = 0; i < 2; i++) {
            const float* Yr = &Yb[buf][(tig * 2 + i) * 196 + dbase];
            const float* Qr = &Qb[buf][(tig * 2 + i) * 196 + dbase];
#pragma unroll
            for (int s = 0; s < 3; s++) {
                float4 yv = *(const float4*)(Yr + s * 4);
                float4 qv = *(const float4*)(Qr + s * 4);
#pragma unroll
                for (int j = 0; j < 2; j++) {
                    float4 s4 = sv[j][s];
                    py[i][j] = fmaf(yv.x, s4.x, py[i][j]);
                    py[i][j] = fmaf(yv.y, s4.y, py[i][j]);
                    py[i][j] = fmaf(yv.z, s4.z, py[i][j]);
                    py[i][j] = fmaf(yv.w, s4.w, py[i][j]);
                    pq[i][j] = fmaf(qv.x, s4.x, pq[i][j]);
                    pq[i][j] = fmaf(qv.y, s4.y, pq[i][j]);
                    pq[i][j] = fmaf(qv.z, s4.z, pq[i][j]);
                    pq[i][j] = fmaf(qv.w, s4.w, pq[i][j]);
                }
            }
        }
        float zy[2][2], zq[2][2];
#pragma unroll
        for (int i = 0; i < 2; i++)
#pragma unroll
            for (int j = 0; j < 2; j++) {
                zy[i][j] = red16(py[i][j]);
                zq[i][j] = red16(pq[i][j]);
            }

        // ---- u = u' - zy ; lanes dg%4==0 write their combo (m = dg>>2) ----
        float uv[2][2];
#pragma unroll
        for (int i = 0; i < 2; i++)
#pragma unroll
            for (int j = 0; j < 2; j++)
                uv[i][j] = ubs[buf][(tig * 2 + i) * 4 + (ccg * 2 + j)] - zy[i][j];
        {
            const int m = dg >> 2;
            if ((dg & 3) == 0) {
                const int ii = m >> 1, jj = m & 1;
                float val = (m == 0) ? uv[0][0] : (m == 1) ? uv[0][1]
                          : (m == 2) ? uv[1][0] : uv[1][1];
                us[(ccg * 2 + jj) * 20 + (tig * 2 + ii)] = val;
            }
        }
        __syncthreads();   // B: us ready

        // ---- o = zq + PL u  (combo m = dg>>2, j-quarter = dg&3) ----
        {
            const int m = dg >> 2, qtr = dg & 3;
            const int ii = m >> 1, jj = m & 1;
            const int ti = tig * 2 + ii, cc = ccg * 2 + jj;
            float acc = 0.f;
            for (int j = qtr; j <= ti; j += 4)
                acc = fmaf(Pb[buf][ti * 16 + j], us[cc * 20 + j], acc);
            acc += dpp_xor1(acc);
            acc += dpp_xor2(acc);
            if (qtr == 0) {
                float zqv = (m == 0) ? zq[0][0] : (m == 1) ? zq[0][1]
                          : (m == 2) ? zq[1][0] : zq[1][1];
                float ov = zqv + acc;
                if (isnan(ov)) ov = 0.f;
                else if (isinf(ov)) ov = ov > 0.f ? 1e4f : -1e4f;
                ob[(size_t)(n * 16 + ti) * (HH * DV) + h * DV + c0 + cc] = ov;
            }
        }

        // ---- state update: S[d][c2] = lam[d] S + sum_j KcT[d][j] u[j][c2] ----
        const float4* up = (const float4*)&us[c2 * 20];
        float4 u0 = up[0], u1 = up[1], u2v = up[2], u3 = up[3];
#pragma unroll
        for (int s = 0; s < 3; s++) {
            int d = dseg * 3 + s;
            float svv = Ss[c2 * 196 + d];
            float a2 = lbs[buf][d] * svv;
            const float4* C4 = (const float4*)&Cb[buf][d * 20];
            float4 k0 = C4[0], k1 = C4[1], k2 = C4[2], k3 = C4[3];
            a2 = fmaf(k0.x, u0.x,  a2); a2 = fmaf(k0.y, u0.y,  a2);
            a2 = fmaf(k0.z, u0.z,  a2); a2 = fmaf(k0.w, u0.w,  a2);
            a2 = fmaf(k1.x, u1.x,  a2); a2 = fmaf(k1.y, u1.y,  a2);
            a2 = fmaf(k1.z, u1.z,  a2); a2 = fmaf(k1.w, u1.w,  a2);
            a2 = fmaf(k2.x, u2v.x, a2); a2 = fmaf(k2.y, u2v.y, a2);
            a2 = fmaf(k2.z, u2v.z, a2); a2 = fmaf(k2.w, u2v.w, a2);
            a2 = fmaf(k3.x, u3.x,  a2); a2 = fmaf(k3.y, u3.y,  a2);
            a2 = fmaf(k3.z, u3.z,  a2); a2 = fmaf(k3.w, u3.w,  a2);
            Ss[c2 * 196 + d] = a2;
        }
        __syncthreads();   // C: buf fully consumed, Ss updated
        if (n + 2 < TT / 16) stage(buf, n + 2);
    }
}

// ---------------------------------------------------------------------------
extern "C" void kernel_launch(void* const* d_in, const int* in_sizes, int n_in,
                              void* d_out, int out_size, void* d_ws, size_t ws_size,
                              hipStream_t stream)
{
    const float* x         = (const float*)d_in[0];
    // d_in[1] = cos, d_in[2] = sin : unused by the reference
    const float* wq_a      = (const float*)d_in[3];
    const float* q_norm_w  = (const float*)d_in[4];
    const float* wq_b      = (const float*)d_in[5];
    const float* wkv_a     = (const float*)d_in[6];
    const float* kv_norm_w = (const float*)d_in[7];
    const float* wkv_b     = (const float*)d_in[8];
    const float* wg_w      = (const float*)d_in[9];
    const float* wg_b      = (const float*)d_in[10];
    const float* wb        = (const float*)d_in[11];
    const float* wo        = (const float*)d_in[12];
    float* out = (float*)d_out;

    float* ws = (float*)d_ws;
    float* xq     = ws;                        // T x 768 (rms in-place)
    float* kv_all = xq     + TT * QLR;         // T x 576
    float* kvn    = kv_all + TT * (KVLR + DROPE); // T x 512
    float* agraw  = kvn    + TT * KVLR;        // T x 1536 (dead after logsig)
    float* ob     = agraw;                     // alias: T x 1024 (scan output)
    float* qnraw  = agraw  + TT * HDK;         // T x 1536 (dead after prep_qk)
    float* kvb    = qnraw  + TT * HDK;         // T x 2048
    float* la_h   = kvb    + TT * HKV;         // 8 x 1024 x 192
    float* q_h    = la_h   + TT * HDK;         // 8 x 1024 x 192
    float* k_h    = q_h    + TT * HDK;         // 8 x 1024 x 192
    float* betab  = k_h    + TT * HDK;         // T x 8
    float* pa     = betab  + TT * HH;          // 512 x PABLK (25.6 MB)

    dim3 blk(256);

    // x projections fused: {wq_a (12), wkv_a (9), wg_w (24)} = 45 x 8 blocks
    gemm_multi<<<dim3(12 + 9 + 24, TT / 128), blk, 0, stream>>>(
        x, wq_a, xq,    DIM, QLR, 12,
        x, wkv_a, kv_all, DIM, KVLR + DROPE, 9,
        x, wg_w, agraw, DIM, HDK, 24);

    // norms
    rmsnorm_rows<<<TT, blk, 0, stream>>>(xq, QLR, q_norm_w, xq, QLR, QLR, 1.f / QLR);
    rmsnorm_rows<<<TT, blk, 0, stream>>>(kv_all, KVLR + DROPE, kv_norm_w, kvn, KVLR, KVLR, 1.f / KVLR);

    // low-rank expansions fused: {wq_b (24), wkv_b (32)} = 56 x 8 blocks
    gemm_multi<<<dim3(24 + 32, TT / 128), blk, 0, stream>>>(
        xq, wq_b, qnraw, QLR, HDK, 24,
        kvn, wkv_b, kvb, KVLR, HKV, 32,
        x, wq_a, xq, DIM, QLR, 0);   // unused region

    // gates
    logsig_relayout<<<(TT * HDK + 255) / 256, blk, 0, stream>>>(agraw, wg_b, la_h);
    beta_kernel<<<TT * HH / 4, blk, 0, stream>>>(x, wb, betab);

    // l2norm q, build+l2norm k (head-major)
    prep_qk<<<TT * HH / 4, blk, 0, stream>>>(qnraw, kvb, kv_all, q_h, k_h);

    // chunked delta rule: phase A (parallel) + phase B (sequential chunks)
    chunk_prep<<<512, blk, 0, stream>>>(k_h, la_h, q_h, kvb, betab, pa);
    kda_chunk<<<256, blk, 0, stream>>>(pa, ob);

    // output projection: 16 x 8 blocks
    gemm_multi<<<dim3(16, TT / 128), blk, 0, stream>>>(
        ob, wo, out, DIM, DIM, 16,
        ob, wo, out, DIM, DIM, 0,
        ob, wo, out, DIM, DIM, 0);
}

// Round 10
// 355.587 us; speedup vs baseline: 3.1513x; 1.3636x over previous
//
#include <hip/hip_runtime.h>
#include <hip/hip_bf16.h>
#include <math.h>

// Problem constants
#define TT 1024
#define DIM 1024
#define HH 8
#define QLR 768
#define KVLR 512
#define DNOPE 128
#define DROPE 64
#define DV 128
#define DK 192            // DNOPE + DROPE
#define HDK (HH*DK)       // 1536
#define HKV (HH*(DNOPE+DV)) // 2048

// Phase-A blob layout (floats) per (chunk n, head h):
#define OY   0
#define OQ   3072
#define OC   6144         // KcT [192][20] padded
#define OPL  9984
#define OU   10240
#define OLAM 12288
#define PABLK 12480

typedef __attribute__((ext_vector_type(8))) short short8;
typedef __attribute__((ext_vector_type(4))) float f32x4;

// ---------------------------------------------------------------------------
// bf16 split helpers (manual bit ops: no header-type dependence)
// ---------------------------------------------------------------------------
__device__ __forceinline__ unsigned short f2bf_rn(float f) {
    unsigned u = __float_as_uint(f);
    unsigned lsb = (u >> 16) & 1u;
    u += 0x7fffu + lsb;
    return (unsigned short)(u >> 16);
}
__device__ __forceinline__ float bf2f(unsigned short h) {
    return __uint_as_float(((unsigned)h) << 16);
}

// ---------------------------------------------------------------------------
// Weight transpose+split: W[K][N] f32 -> Wt_h[N][K], Wt_l[N][K] bf16.
// 3 regions per launch, 64x64 tiles, LDS transpose with +1 pad.
// ---------------------------------------------------------------------------
__global__ __launch_bounds__(256) void wconv(
    const float* __restrict__ W0, unsigned short* __restrict__ H0,
    unsigned short* __restrict__ L0, int K0, int N0, int T0,
    const float* __restrict__ W1, unsigned short* __restrict__ H1,
    unsigned short* __restrict__ L1, int K1, int N1, int T1,
    const float* __restrict__ W2, unsigned short* __restrict__ H2,
    unsigned short* __restrict__ L2, int K2, int N2, int T2)
{
    __shared__ float Ls[64][65];
    int bx = blockIdx.x;
    const float* W; unsigned short* H; unsigned short* L; int K, N;
    if (bx < T0)           { W = W0; H = H0; L = L0; K = K0; N = N0; }
    else if (bx < T0 + T1) { bx -= T0; W = W1; H = H1; L = L1; K = K1; N = N1; }
    else                   { bx -= T0 + T1; W = W2; H = H2; L = L2; K = K2; N = N2; }

    const int NT = N >> 6;
    const int kt = bx / NT, nt = bx - kt * NT;
    const int k0 = kt * 64, n0 = nt * 64;
    const int tid = threadIdx.x;
    const int r = tid >> 2, c = (tid & 3) * 16;

#pragma unroll
    for (int i = 0; i < 4; i++)
        *(float4*)&Ls[r][c + i * 4] =
            *(const float4*)&W[(size_t)(k0 + r) * N + n0 + c + i * 4];
    __syncthreads();

    const int nr = tid >> 2, kc = (tid & 3) * 16;
    unsigned short hb[16], lb[16];
#pragma unroll
    for (int j = 0; j < 16; j++) {
        float v = Ls[kc + j][nr];
        unsigned short h = f2bf_rn(v);
        hb[j] = h;
        lb[j] = f2bf_rn(v - bf2f(h));
    }
    size_t ob = (size_t)(n0 + nr) * K + k0 + kc;
    *(float4*)&H[ob]     = ((float4*)hb)[0];
    *(float4*)&H[ob + 8] = ((float4*)hb)[1];
    *(float4*)&L[ob]     = ((float4*)lb)[0];
    *(float4*)&L[ob + 8] = ((float4*)lb)[1];
}

// ---------------------------------------------------------------------------
// Activation split: A f32 -> H, L bf16 (same layout). 8 elems/thread.
// ---------------------------------------------------------------------------
__global__ __launch_bounds__(256) void aconv(
    const float* __restrict__ A, unsigned short* __restrict__ H,
    unsigned short* __restrict__ L)
{
    int i = (blockIdx.x * 256 + threadIdx.x) * 8;
    float4 v0 = *(const float4*)&A[i];
    float4 v1 = *(const float4*)&A[i + 4];
    float vv[8] = {v0.x, v0.y, v0.z, v0.w, v1.x, v1.y, v1.z, v1.w};
    unsigned short hb[8], lb[8];
#pragma unroll
    for (int j = 0; j < 8; j++) {
        unsigned short h = f2bf_rn(vv[j]);
        hb[j] = h;
        lb[j] = f2bf_rn(vv[j] - bf2f(h));
    }
    *(float4*)&H[i] = *(float4*)hb;
    *(float4*)&L[i] = *(float4*)lb;
}

// ---------------------------------------------------------------------------
// bf16x3 MFMA GEMM: C(f32)[M][N] = (Ah+Al)[M][K] @ (Bh+Bl)^T  where B given
// as Bt[N][K] bf16 hi/lo. 3 regions; block 128 thr = 2 waves, C-tile 64x64,
// wave tile 32x64 = 2x4 MFMA 16x16x32 units, 3 MFMAs per unit (hh, hl, lh).
// LDS rows padded to 40 ushorts (stride 20 words -> 2-way max, free).
// Register-prefetched single-buffer K-loop. M%64==0, N%64==0, K%32==0.
// ---------------------------------------------------------------------------
__global__ __launch_bounds__(128) void gemm_bt(
    const unsigned short* __restrict__ Ah0, const unsigned short* __restrict__ Al0,
    const unsigned short* __restrict__ Bh0, const unsigned short* __restrict__ Bl0,
    float* __restrict__ C0, int K0, int N0, int T0,
    const unsigned short* __restrict__ Ah1, const unsigned short* __restrict__ Al1,
    const unsigned short* __restrict__ Bh1, const unsigned short* __restrict__ Bl1,
    float* __restrict__ C1, int K1, int N1, int T1,
    const unsigned short* __restrict__ Ah2, const unsigned short* __restrict__ Al2,
    const unsigned short* __restrict__ Bh2, const unsigned short* __restrict__ Bl2,
    float* __restrict__ C2, int K2, int N2, int T2)
{
    __shared__ unsigned short Ahs[64 * 40], Als[64 * 40];
    __shared__ unsigned short Bhs[64 * 40], Bls[64 * 40];

    int bx = blockIdx.x;
    const unsigned short *Ah, *Al, *Bh, *Bl; float* C; int K, N;
    if (bx < T0) {
        Ah = Ah0; Al = Al0; Bh = Bh0; Bl = Bl0; C = C0; K = K0; N = N0;
    } else if (bx < T0 + T1) {
        bx -= T0; Ah = Ah1; Al = Al1; Bh = Bh1; Bl = Bl1; C = C1; K = K1; N = N1;
    } else {
        bx -= T0 + T1; Ah = Ah2; Al = Al2; Bh = Bh2; Bl = Bl2; C = C2; K = K2; N = N2;
    }

    const int tid = threadIdx.x;
    const int w = tid >> 6, l = tid & 63;
    const int q = l >> 4, m16 = l & 15;
    const int bm = blockIdx.y * 64, bn = bx * 64;

    // staging: thread covers 2 chunks of 8 ushorts per matrix
    const int c0i = tid * 2, c1i = tid * 2 + 1;
    const int r0 = c0i >> 2, o0 = (c0i & 3) * 8;
    const int r1 = c1i >> 2, o1 = (c1i & 3) * 8;
    const unsigned short* pAh0 = Ah + (size_t)(bm + r0) * K + o0;
    const unsigned short* pAh1 = Ah + (size_t)(bm + r1) * K + o1;
    const unsigned short* pAl0 = Al + (size_t)(bm + r0) * K + o0;
    const unsigned short* pAl1 = Al + (size_t)(bm + r1) * K + o1;
    const unsigned short* pBh0 = Bh + (size_t)(bn + r0) * K + o0;
    const unsigned short* pBh1 = Bh + (size_t)(bn + r1) * K + o1;
    const unsigned short* pBl0 = Bl + (size_t)(bn + r0) * K + o0;
    const unsigned short* pBl1 = Bl + (size_t)(bn + r1) * K + o1;

    f32x4 acc[2][4];
#pragma unroll
    for (int i = 0; i < 2; i++)
#pragma unroll
        for (int j = 0; j < 4; j++)
            acc[i][j] = (f32x4){0.f, 0.f, 0.f, 0.f};

    float4 vAh0 = *(const float4*)pAh0, vAh1 = *(const float4*)pAh1;
    float4 vAl0 = *(const float4*)pAl0, vAl1 = *(const float4*)pAl1;
    float4 vBh0 = *(const float4*)pBh0, vBh1 = *(const float4*)pBh1;
    float4 vBl0 = *(const float4*)pBl0, vBl1 = *(const float4*)pBl1;

    for (int k0 = 0;; k0 += 32) {
        __syncthreads();
        *(float4*)&Ahs[r0 * 40 + o0] = vAh0; *(float4*)&Ahs[r1 * 40 + o1] = vAh1;
        *(float4*)&Als[r0 * 40 + o0] = vAl0; *(float4*)&Als[r1 * 40 + o1] = vAl1;
        *(float4*)&Bhs[r0 * 40 + o0] = vBh0; *(float4*)&Bhs[r1 * 40 + o1] = vBh1;
        *(float4*)&Bls[r0 * 40 + o0] = vBl0; *(float4*)&Bls[r1 * 40 + o1] = vBl1;
        __syncthreads();

        const bool more = (k0 + 32) < K;
        if (more) {
            const int kn = k0 + 32;
            vAh0 = *(const float4*)(pAh0 + kn); vAh1 = *(const float4*)(pAh1 + kn);
            vAl0 = *(const float4*)(pAl0 + kn); vAl1 = *(const float4*)(pAl1 + kn);
            vBh0 = *(const float4*)(pBh0 + kn); vBh1 = *(const float4*)(pBh1 + kn);
            vBl0 = *(const float4*)(pBl0 + kn); vBl1 = *(const float4*)(pBl1 + kn);
        }

        // fragments: A rows (m), B rows (n); k = q*8 + j
        short8 fah[2], fal[2], fbh[4], fbl[4];
#pragma unroll
        for (int mt = 0; mt < 2; mt++) {
            const int row = w * 32 + mt * 16 + m16;
            fah[mt] = *(const short8*)&Ahs[row * 40 + q * 8];
            fal[mt] = *(const short8*)&Als[row * 40 + q * 8];
        }
#pragma unroll
        for (int nt = 0; nt < 4; nt++) {
            const int row = nt * 16 + m16;
            fbh[nt] = *(const short8*)&Bhs[row * 40 + q * 8];
            fbl[nt] = *(const short8*)&Bls[row * 40 + q * 8];
        }
#pragma unroll
        for (int mt = 0; mt < 2; mt++)
#pragma unroll
            for (int nt = 0; nt < 4; nt++) {
                acc[mt][nt] = __builtin_amdgcn_mfma_f32_16x16x32_bf16(
                    fah[mt], fbh[nt], acc[mt][nt], 0, 0, 0);
                acc[mt][nt] = __builtin_amdgcn_mfma_f32_16x16x32_bf16(
                    fah[mt], fbl[nt], acc[mt][nt], 0, 0, 0);
                acc[mt][nt] = __builtin_amdgcn_mfma_f32_16x16x32_bf16(
                    fal[mt], fbh[nt], acc[mt][nt], 0, 0, 0);
            }
        if (!more) break;
    }

    // epilogue: D row = q*4 + r, col = m16
#pragma unroll
    for (int mt = 0; mt < 2; mt++)
#pragma unroll
        for (int nt = 0; nt < 4; nt++) {
            const int mrow = bm + w * 32 + mt * 16 + q * 4;
            const int ncol = bn + nt * 16 + m16;
#pragma unroll
            for (int r = 0; r < 4; r++)
                C[(size_t)(mrow + r) * N + ncol] = acc[mt][nt][r];
        }
}

// ---------------------------------------------------------------------------
// RMSNorm rows -> bf16 hi/lo outputs
// ---------------------------------------------------------------------------
__global__ __launch_bounds__(256) void rmsnorm_bf(
    const float* __restrict__ in, int in_stride, const float* __restrict__ w,
    unsigned short* __restrict__ oh, unsigned short* __restrict__ ol,
    int ncols, float inv_n)
{
    const int t = blockIdx.x;
    const int tid = threadIdx.x;
    const float* row = in + (size_t)t * in_stride;
    float ss = 0.f;
    for (int c = tid; c < ncols; c += 256) { float v = row[c]; ss += v * v; }
#pragma unroll
    for (int m = 1; m < 64; m <<= 1) ss += __shfl_xor(ss, m);
    __shared__ float red[4];
    if ((tid & 63) == 0) red[tid >> 6] = ss;
    __syncthreads();
    float tot = red[0] + red[1] + red[2] + red[3];
    float scale = rsqrtf(tot * inv_n + 1e-5f);
    for (int c = tid; c < ncols; c += 256) {
        float v = row[c] * scale * w[c];
        unsigned short h = f2bf_rn(v);
        oh[(size_t)t * ncols + c] = h;
        ol[(size_t)t * ncols + c] = f2bf_rn(v - bf2f(h));
    }
}

// ---------------------------------------------------------------------------
// la = log_sigmoid(gpre + bias), HEAD-MAJOR: la_h[h][t][192]
// ---------------------------------------------------------------------------
__global__ __launch_bounds__(256) void logsig_relayout(
    const float* __restrict__ g, const float* __restrict__ bias,
    float* __restrict__ la_h)
{
    int i = blockIdx.x * 256 + threadIdx.x;   // < TT*HDK
    int t = i / HDK, col = i - t * HDK;
    int h = col / DK, d = col - h * DK;
    float z = g[i] + bias[col];
    float la = fminf(z, 0.f) - log1pf(__expf(-fabsf(z)));
    la_h[((size_t)h * TT + t) * DK + d] = la;
}

// ---------------------------------------------------------------------------
__global__ __launch_bounds__(256) void beta_kernel(
    const float* __restrict__ x, const float* __restrict__ wb,
    float* __restrict__ beta)
{
    const int lane = threadIdx.x & 63, wv = threadIdx.x >> 6;
    const int p = blockIdx.x * 4 + wv;        // p = t*8 + h
    const int t = p >> 3, h = p & 7;
    const float* xr = x + (size_t)t * DIM;
    float s = 0.f;
    for (int e = lane; e < DIM; e += 64) s += xr[e] * wb[e * HH + h];
#pragma unroll
    for (int m = 1; m < 64; m <<= 1) s += __shfl_xor(s, m);
    if (lane == 0) beta[p] = 1.f / (1.f + expf(-s));
}

// ---------------------------------------------------------------------------
// l2norm(q)*DK^-0.5 and build+l2norm k; outputs HEAD-MAJOR [h][t][192].
// ---------------------------------------------------------------------------
__global__ __launch_bounds__(256) void prep_qk(
    const float* __restrict__ qraw, const float* __restrict__ kvb,
    const float* __restrict__ kv_all, float* __restrict__ q_h,
    float* __restrict__ k_h)
{
    const int lane = threadIdx.x & 63, wv = threadIdx.x >> 6;
    const int p = blockIdx.x * 4 + wv;
    const int t = p >> 3, h = p & 7;

    const float* qrow = qraw + (size_t)t * HDK + h * DK;
    float q0 = qrow[lane], q1 = qrow[lane + 64], q2 = qrow[lane + 128];
    float ss = q0 * q0 + q1 * q1 + q2 * q2;
#pragma unroll
    for (int m = 1; m < 64; m <<= 1) ss += __shfl_xor(ss, m);
    float sc = rsqrtf(ss + 1e-6f) * 0.07216878364870323f;  // * DK^-0.5
    float* qo = q_h + ((size_t)h * TT + t) * DK;
    qo[lane] = q0 * sc; qo[lane + 64] = q1 * sc; qo[lane + 128] = q2 * sc;

    const float* knope = kvb + (size_t)t * HKV + h * (DNOPE + DV);
    float k0 = knope[lane], k1 = knope[lane + 64];
    float k2 = kv_all[(size_t)t * (KVLR + DROPE) + KVLR + lane];
    float ks = k0 * k0 + k1 * k1 + k2 * k2;
#pragma unroll
    for (int m = 1; m < 64; m <<= 1) ks += __shfl_xor(ks, m);
    float kc = rsqrtf(ks + 1e-6f);
    float* ko = k_h + ((size_t)h * TT + t) * DK;
    ko[lane] = k0 * kc; ko[lane + 64] = k1 * kc; ko[lane + 128] = k2 * kc;
}

// ---------------------------------------------------------------------------
__device__ __forceinline__ float dpp_xor1(float x) {
    return __int_as_float(__builtin_amdgcn_update_dpp(
        0, __float_as_int(x), 0xB1, 0xF, 0xF, false));
}
__device__ __forceinline__ float dpp_xor2(float x) {
    return __int_as_float(__builtin_amdgcn_update_dpp(
        0, __float_as_int(x), 0x4E, 0xF, 0xF, false));
}
__device__ __forceinline__ float red16(float x) {
    x += dpp_xor1(x);
    x += dpp_xor2(x);
    x += __int_as_float(__builtin_amdgcn_update_dpp(0, __float_as_int(x), 0x141, 0xF, 0xF, false));
    x += __int_as_float(__builtin_amdgcn_update_dpp(0, __float_as_int(x), 0x140, 0xF, 0xF, false));
    return x;
}

__device__ __forceinline__ void gl_lds16(const float* g, float* l) {
    __builtin_amdgcn_global_load_lds(
        (const __attribute__((address_space(1))) void*)g,
        (__attribute__((address_space(3))) void*)l, 16, 0, 0);
}
__device__ __forceinline__ void gl_lds4(const float* g, float* l) {
    __builtin_amdgcn_global_load_lds(
        (const __attribute__((address_space(1))) void*)g,
        (__attribute__((address_space(3))) void*)l, 4, 0, 0);
}

// ---------------------------------------------------------------------------
// Phase A: per-(chunk,head) S-independent quantities (unchanged from R8/R9).
// ---------------------------------------------------------------------------
__global__ __launch_bounds__(256) void chunk_prep(
    const float* __restrict__ k_h, const float* __restrict__ la_h,
    const float* __restrict__ q_h, const float* __restrict__ kvb,
    const float* __restrict__ betab, float* __restrict__ pa)
{
    __shared__ float Ls[16][196];
    __shared__ float Ks[16][196];
    __shared__ float Qs[16][196];
    __shared__ float Ws[16][196];
    __shared__ float Xs[16][196];
    __shared__ float Ms[16][16];
    __shared__ float bs[16];

    const int tid = threadIdx.x;
    const int n = blockIdx.x >> 3, h = blockIdx.x & 7;
    const size_t g0 = ((size_t)h * TT + n * 16) * DK;
    float* blob = pa + (size_t)blockIdx.x * PABLK;

#pragma unroll
    for (int s = 0; s < 3; s++) {
        int off = (tid * 3 + s) * 4;
        int r = off / 192, c = off - r * 192;
        *(float4*)&Ks[r][c] = *(const float4*)(k_h + g0 + off);
        *(float4*)&Ls[r][c] = *(const float4*)(la_h + g0 + off);
        *(float4*)&Qs[r][c] = *(const float4*)(q_h + g0 + off);
    }
    if (tid < 16) bs[tid] = betab[(size_t)(n * 16 + tid) * HH + h];
    __syncthreads();

    if (tid < 192) {
        float g = 0.f;
#pragma unroll
        for (int i = 0; i < 16; i++) { g += Ls[i][tid]; Ls[i][tid] = g; }
    }
    __syncthreads();

#pragma unroll
    for (int s = 0; s < 12; s++) {
        int idx = s * 256 + tid;
        int i = idx / 192, d = idx - i * 192;
        float G = Ls[i][d];
        float eg = __expf(G), en = __expf(-G);
        float kk = Ks[i][d];
        Ws[i][d] = bs[i] * kk * eg;
        Qs[i][d] *= eg;
        Ks[i][d] = kk * en;
    }
    __syncthreads();

#pragma unroll
    for (int s = 0; s < 3; s++) {
        int off = (tid * 3 + s) * 4;
        int r = off / 192, c = off - r * 192;
        *(float4*)(blob + OQ + off) = *(const float4*)&Qs[r][c];
    }
    if (tid < 192) {
        float lam = __expf(Ls[15][tid]);
        blob[OLAM + tid] = lam;
#pragma unroll
        for (int j4 = 0; j4 < 4; j4++) {
            float4 v;
            v.x = Ks[j4 * 4 + 0][tid] * lam; v.y = Ks[j4 * 4 + 1][tid] * lam;
            v.z = Ks[j4 * 4 + 2][tid] * lam; v.w = Ks[j4 * 4 + 3][tid] * lam;
            *(float4*)(blob + OC + tid * 20 + j4 * 4) = v;
        }
        blob[OC + tid * 20 + 16] = 0.f; blob[OC + tid * 20 + 17] = 0.f;
        blob[OC + tid * 20 + 18] = 0.f; blob[OC + tid * 20 + 19] = 0.f;
    }
    {
        const int i = tid >> 4, j = tid & 15;
        float m = 0.f, p = 0.f;
#pragma unroll
        for (int d4 = 0; d4 < 48; d4++) {
            float4 w  = *(const float4*)&Ws[i][d4 * 4];
            float4 ka = *(const float4*)&Ks[j][d4 * 4];
            float4 qa = *(const float4*)&Qs[i][d4 * 4];
            m += w.x * ka.x + w.y * ka.y + w.z * ka.z + w.w * ka.w;
            p += qa.x * ka.x + qa.y * ka.y + qa.z * ka.z + qa.w * ka.w;
        }
        Ms[i][j] = (j < i) ? m : 0.f;
        blob[OPL + tid] = (j <= i) ? p : 0.f;
    }
    __syncthreads();

    float y[16], uu[16];
    const bool doY = (tid < 192);
    const bool doU = (tid >= 128);
    const int dcol = tid, ccol = tid - 128;
    if (doY) {
#pragma unroll
        for (int i = 0; i < 16; i++) y[i] = Ws[i][dcol];
#pragma unroll
        for (int i = 1; i < 16; i++)
#pragma unroll
            for (int j = 0; j < i; j++)
                y[i] = fmaf(-Ms[i][j], y[j], y[i]);
    }
    if (doU) {
#pragma unroll
        for (int i = 0; i < 16; i++)
            uu[i] = bs[i] * kvb[(size_t)(n * 16 + i) * HKV + h * (DNOPE + DV) + DNOPE + ccol];
#pragma unroll
        for (int i = 1; i < 16; i++)
#pragma unroll
            for (int j = 0; j < i; j++)
                uu[i] = fmaf(-Ms[i][j], uu[j], uu[i]);
    }
    if (doY) {
#pragma unroll
        for (int i = 0; i < 16; i++) Xs[i][dcol] = y[i];
    }
    __syncthreads();
#pragma unroll
    for (int s = 0; s < 3; s++) {
        int off = (tid * 3 + s) * 4;
        int r = off / 192, c = off - r * 192;
        *(float4*)(blob + OY + off) = *(const float4*)&Xs[r][c];
    }
    __syncthreads();
    if (doU) {
#pragma unroll
        for (int i = 0; i < 16; i++) Xs[i][ccol] = uu[i];
    }
    __syncthreads();
#pragma unroll
    for (int s = 0; s < 2; s++) {
        int off = (tid * 2 + s) * 4;
        int r = off / 128, c = off - r * 128;
        *(float4*)(blob + OU + off) = *(const float4*)&Xs[r][c];
    }
}

// ---------------------------------------------------------------------------
// Phase B (R9 structure): 256 blocks, register-blocked; epilogue now emits
// bf16 hi/lo of o directly (feeds the MFMA output projection).
// ---------------------------------------------------------------------------
__global__ __launch_bounds__(256) void kda_chunk(
    const float* __restrict__ pa, unsigned short* __restrict__ obh,
    unsigned short* __restrict__ obl)
{
    __shared__ float Yb[2][3136];
    __shared__ float Qb[2][3136];
    __shared__ float Cb[2][3840];
    __shared__ float Pb[2][256];
    __shared__ float ubs[2][64];
    __shared__ float lbs[2][192];
    __shared__ float Ss[784];
    __shared__ float us[80];

    const int tid = threadIdx.x;
    const int w = tid >> 6, lane = tid & 63;
    const int h = blockIdx.x >> 5, cg = blockIdx.x & 31;
    const int c0 = cg * 4;

    const int dg  = tid & 15;
    const int ccg = (tid >> 4) & 1;
    const int tig = tid >> 5;

    auto stage = [&](int buf, int n) {
        const float* blob = pa + (size_t)(n * 8 + h) * PABLK;
        if (w == 0) {
            if (lane < 48)
#pragma unroll
                for (int r = 0; r < 16; r++)
                    gl_lds16(blob + OY + r * 192 + lane * 4, &Yb[buf][r * 196]);
        } else if (w == 1) {
            if (lane < 48)
#pragma unroll
                for (int r = 0; r < 16; r++)
                    gl_lds16(blob + OQ + r * 192 + lane * 4, &Qb[buf][r * 196]);
        } else if (w == 2) {
#pragma unroll
            for (int s = 0; s < 15; s++)
                gl_lds16(blob + OC + s * 256 + lane * 4, &Cb[buf][s * 256]);
        } else {
            gl_lds16(blob + OPL + lane * 4, &Pb[buf][0]);
            gl_lds4(blob + OU + (lane >> 2) * 128 + c0 + (lane & 3), &ubs[buf][0]);
            if (lane < 48)
                gl_lds16(blob + OLAM + lane * 4, &lbs[buf][0]);
        }
    };

    for (int idx = tid; idx < 784; idx += 256) Ss[idx] = 0.f;
    stage(0, 0);
    stage(1, 1);

    const int c2 = tid & 3, dseg = tid >> 2;

    for (int n = 0; n < TT / 16; n++) {
        const int buf = n & 1;
        __syncthreads();

        const int dbase = dg * 12;
        float4 sv[2][3];
#pragma unroll
        for (int j = 0; j < 2; j++)
#pragma unroll
            for (int s = 0; s < 3; s++)
                sv[j][s] = *(const float4*)&Ss[(ccg * 2 + j) * 196 + dbase + s * 4];

        float py[2][2] = {{0.f, 0.f}, {0.f, 0.f}};
        float pq[2][2] = {{0.f, 0.f}, {0.f, 0.f}};
#pragma unroll
        for (int i = 0; i < 2; i++) {
            const float* Yr = &Yb[buf][(tig * 2 + i) * 196 + dbase];
            const float* Qr = &Qb[buf][(tig * 2 + i) * 196 + dbase];
#pragma unroll
            for (int s = 0; s < 3; s++) {
                float4 yv = *(const float4*)(Yr + s * 4);
                float4 qv = *(const float4*)(Qr + s * 4);
#pragma unroll
                for (int j = 0; j < 2; j++) {
                    float4 s4 = sv[j][s];
                    py[i][j] = fmaf(yv.x, s4.x, py[i][j]);
                    py[i][j] = fmaf(yv.y, s4.y, py[i][j]);
                    py[i][j] = fmaf(yv.z, s4.z, py[i][j]);
                    py[i][j] = fmaf(yv.w, s4.w, py[i][j]);
                    pq[i][j] = fmaf(qv.x, s4.x, pq[i][j]);
                    pq[i][j] = fmaf(qv.y, s4.y, pq[i][j]);
                    pq[i][j] = fmaf(qv.z, s4.z, pq[i][j]);
                    pq[i][j] = fmaf(qv.w, s4.w, pq[i][j]);
                }
            }
        }
        float zy[2][2], zq[2][2];
#pragma unroll
        for (int i = 0; i < 2; i++)
#pragma unroll
            for (int j = 0; j < 2; j++) {
                zy[i][j] = red16(py[i][j]);
                zq[i][j] = red16(pq[i][j]);
            }

        float uv[2][2];
#pragma unroll
        for (int i = 0; i < 2; i++)
#pragma unroll
            for (int j = 0; j < 2; j++)
                uv[i][j] = ubs[buf][(tig * 2 + i) * 4 + (ccg * 2 + j)] - zy[i][j];
        {
            const int m = dg >> 2;
            if ((dg & 3) == 0) {
                const int ii = m >> 1, jj = m & 1;
                float val = (m == 0) ? uv[0][0] : (m == 1) ? uv[0][1]
                          : (m == 2) ? uv[1][0] : uv[1][1];
                us[(ccg * 2 + jj) * 20 + (tig * 2 + ii)] = val;
            }
        }
        __syncthreads();

        {
            const int m = dg >> 2, qtr = dg & 3;
            const int ii = m >> 1, jj = m & 1;
            const int ti = tig * 2 + ii, cc = ccg * 2 + jj;
            float acc = 0.f;
            for (int j = qtr; j <= ti; j += 4)
                acc = fmaf(Pb[buf][ti * 16 + j], us[cc * 20 + j], acc);
            acc += dpp_xor1(acc);
            acc += dpp_xor2(acc);
            if (qtr == 0) {
                float zqv = (m == 0) ? zq[0][0] : (m == 1) ? zq[0][1]
                          : (m == 2) ? zq[1][0] : zq[1][1];
                float ov = zqv + acc;
                if (isnan(ov)) ov = 0.f;
                else if (isinf(ov)) ov = ov > 0.f ? 1e4f : -1e4f;
                size_t oi = (size_t)(n * 16 + ti) * (HH * DV) + h * DV + c0 + cc;
                unsigned short hb = f2bf_rn(ov);
                obh[oi] = hb;
                obl[oi] = f2bf_rn(ov - bf2f(hb));
            }
        }

        const float4* up = (const float4*)&us[c2 * 20];
        float4 u0 = up[0], u1 = up[1], u2v = up[2], u3 = up[3];
#pragma unroll
        for (int s = 0; s < 3; s++) {
            int d = dseg * 3 + s;
            float svv = Ss[c2 * 196 + d];
            float a2 = lbs[buf][d] * svv;
            const float4* C4 = (const float4*)&Cb[buf][d * 20];
            float4 k0 = C4[0], k1 = C4[1], k2 = C4[2], k3 = C4[3];
            a2 = fmaf(k0.x, u0.x,  a2); a2 = fmaf(k0.y, u0.y,  a2);
            a2 = fmaf(k0.z, u0.z,  a2); a2 = fmaf(k0.w, u0.w,  a2);
            a2 = fmaf(k1.x, u1.x,  a2); a2 = fmaf(k1.y, u1.y,  a2);
            a2 = fmaf(k1.z, u1.z,  a2); a2 = fmaf(k1.w, u1.w,  a2);
            a2 = fmaf(k2.x, u2v.x, a2); a2 = fmaf(k2.y, u2v.y, a2);
            a2 = fmaf(k2.z, u2v.z, a2); a2 = fmaf(k2.w, u2v.w, a2);
            a2 = fmaf(k3.x, u3.x,  a2); a2 = fmaf(k3.y, u3.y,  a2);
            a2 = fmaf(k3.z, u3.z,  a2); a2 = fmaf(k3.w, u3.w,  a2);
            Ss[c2 * 196 + d] = a2;
        }
        __syncthreads();
        if (n + 2 < TT / 16) stage(buf, n + 2);
    }
}

// ---------------------------------------------------------------------------
extern "C" void kernel_launch(void* const* d_in, const int* in_sizes, int n_in,
                              void* d_out, int out_size, void* d_ws, size_t ws_size,
                              hipStream_t stream)
{
    const float* x         = (const float*)d_in[0];
    // d_in[1] = cos, d_in[2] = sin : unused by the reference
    const float* wq_a      = (const float*)d_in[3];
    const float* q_norm_w  = (const float*)d_in[4];
    const float* wq_b      = (const float*)d_in[5];
    const float* wkv_a     = (const float*)d_in[6];
    const float* kv_norm_w = (const float*)d_in[7];
    const float* wkv_b     = (const float*)d_in[8];
    const float* wg_w      = (const float*)d_in[9];
    const float* wg_b      = (const float*)d_in[10];
    const float* wb        = (const float*)d_in[11];
    const float* wo        = (const float*)d_in[12];
    float* out = (float*)d_out;

    float* ws = (float*)d_ws;
    float* xq     = ws;                        // T x 768 (f32, gemm1 out)
    float* kv_all = xq     + TT * QLR;         // T x 576
    float* agraw  = kv_all + TT * (KVLR + DROPE); // T x 1536 (dead after logsig)
    float* qnraw  = agraw  + TT * HDK;         // T x 1536
    float* kvb    = qnraw  + TT * HDK;         // T x 2048
    float* la_h   = kvb    + TT * HKV;         // 8 x 1024 x 192
    float* q_h    = la_h   + TT * HDK;
    float* k_h    = q_h    + TT * HDK;
    float* betab  = k_h    + TT * HDK;         // T x 8
    float* pa     = betab  + TT * HH;          // 512 x PABLK (25.6 MB)
    float* tail   = pa     + 512 * PABLK;

    // bf16 buffers after pa: wo_t + activations (ushort elems)
    unsigned short* wo_h  = (unsigned short*)tail;          // 1024*1024
    unsigned short* wo_l  = wo_h  + 1048576;
    unsigned short* xh    = wo_l  + 1048576;                // 1024*1024
    unsigned short* xl    = xh    + 1048576;
    unsigned short* xqh   = xl    + 1048576;                // 1024*768
    unsigned short* xql   = xqh   + 786432;
    unsigned short* kvnh  = xql   + 786432;                 // 1024*512
    unsigned short* kvnl  = kvnh  + 524288;

    // stage-1/2 weights carved from pa (dead before chunk_prep writes pa)
    unsigned short* wqa_h  = (unsigned short*)pa;           // 768n x 1024k
    unsigned short* wqa_l  = wqa_h  + 786432;
    unsigned short* wkva_h = wqa_l  + 786432;               // 576n x 1024k
    unsigned short* wkva_l = wkva_h + 589824;
    unsigned short* wgw_h  = wkva_l + 589824;               // 1536n x 1024k
    unsigned short* wgw_l  = wgw_h  + 1572864;
    unsigned short* wqb_h  = wgw_l  + 1572864;              // 1536n x 768k
    unsigned short* wqb_l  = wqb_h  + 1179648;
    unsigned short* wkvb_h = wqb_l  + 1179648;              // 2048n x 512k
    unsigned short* wkvb_l = wkvb_h + 1048576;

    // ob bf16 aliases agraw (dead after logsig; written by kda_chunk later)
    unsigned short* obh = (unsigned short*)agraw;           // 1024*1024
    unsigned short* obl = obh + 1048576;

    dim3 blk(256);

    // weight transpose+split: two multi-region launches
    wconv<<<dim3(192 + 144 + 384), blk, 0, stream>>>(
        wq_a, wqa_h, wqa_l, DIM, QLR, 192,
        wkv_a, wkva_h, wkva_l, DIM, KVLR + DROPE, 144,
        wg_w, wgw_h, wgw_l, DIM, HDK, 384);
    wconv<<<dim3(288 + 256 + 256), blk, 0, stream>>>(
        wq_b, wqb_h, wqb_l, QLR, HDK, 288,
        wkv_b, wkvb_h, wkvb_l, KVLR, HKV, 256,
        wo, wo_h, wo_l, DIM, DIM, 256);

    // x split
    aconv<<<dim3(TT * DIM / (256 * 8)), blk, 0, stream>>>(x, xh, xl);

    // x projections (MFMA bf16x3): {wq_a(12), wkv_a(9), wg_w(24)} n-tiles
    gemm_bt<<<dim3(12 + 9 + 24, 16), dim3(128), 0, stream>>>(
        xh, xl, wqa_h, wqa_l, xq, DIM, QLR, 12,
        xh, xl, wkva_h, wkva_l, kv_all, DIM, KVLR + DROPE, 9,
        xh, xl, wgw_h, wgw_l, agraw, DIM, HDK, 24);

    // norms -> bf16 hi/lo
    rmsnorm_bf<<<TT, blk, 0, stream>>>(xq, QLR, q_norm_w, xqh, xql, QLR, 1.f / QLR);
    rmsnorm_bf<<<TT, blk, 0, stream>>>(kv_all, KVLR + DROPE, kv_norm_w, kvnh, kvnl, KVLR, 1.f / KVLR);

    // low-rank expansions: {wq_b(24), wkv_b(32)} n-tiles
    gemm_bt<<<dim3(24 + 32, 16), dim3(128), 0, stream>>>(
        xqh, xql, wqb_h, wqb_l, qnraw, QLR, HDK, 24,
        kvnh, kvnl, wkvb_h, wkvb_l, kvb, KVLR, HKV, 32,
        xh, xl, wqa_h, wqa_l, xq, DIM, QLR, 0);

    // gates
    logsig_relayout<<<(TT * HDK + 255) / 256, blk, 0, stream>>>(agraw, wg_b, la_h);
    beta_kernel<<<TT * HH / 4, blk, 0, stream>>>(x, wb, betab);

    // l2norm q, build+l2norm k (head-major)
    prep_qk<<<TT * HH / 4, blk, 0, stream>>>(qnraw, kvb, kv_all, q_h, k_h);

    // chunked delta rule
    chunk_prep<<<512, blk, 0, stream>>>(k_h, la_h, q_h, kvb, betab, pa);
    kda_chunk<<<256, blk, 0, stream>>>(pa, obh, obl);

    // output projection (MFMA)
    gemm_bt<<<dim3(16, 16), dim3(128), 0, stream>>>(
        obh, obl, wo_h, wo_l, out, DIM, DIM, 16,
        xh, xl, wqa_h, wqa_l, xq, DIM, QLR, 0,
        xh, xl, wqa_h, wqa_l, xq, DIM, QLR, 0);
}

// Round 11
// 326.099 us; speedup vs baseline: 3.4362x; 1.0904x over previous
//
#include <hip/hip_runtime.h>
#include <hip/hip_bf16.h>
#include <math.h>

// Problem constants
#define TT 1024
#define DIM 1024
#define HH 8
#define QLR 768
#define KVLR 512
#define DNOPE 128
#define DROPE 64
#define DV 128
#define DK 192            // DNOPE + DROPE
#define HDK (HH*DK)       // 1536
#define HKV (HH*(DNOPE+DV)) // 2048

// Phase-A blob layout (floats) per (chunk n, head h):
#define OY   0
#define OQ   3072
#define OC   6144         // KcT [192][20] padded
#define OPL  9984
#define OU   10240
#define OLAM 12288
#define PABLK 12480

typedef __attribute__((ext_vector_type(8))) short short8;
typedef __attribute__((ext_vector_type(4))) float f32x4;

// ---------------------------------------------------------------------------
// bf16 split helpers
// ---------------------------------------------------------------------------
__device__ __forceinline__ unsigned short f2bf_rn(float f) {
    unsigned u = __float_as_uint(f);
    unsigned lsb = (u >> 16) & 1u;
    u += 0x7fffu + lsb;
    return (unsigned short)(u >> 16);
}
__device__ __forceinline__ float bf2f(unsigned short h) {
    return __uint_as_float(((unsigned)h) << 16);
}

// ---------------------------------------------------------------------------
// Weight transpose+split: W[K][N] f32 -> Wt_h[N][K], Wt_l[N][K] bf16.
// ---------------------------------------------------------------------------
__global__ __launch_bounds__(256) void wconv(
    const float* __restrict__ W0, unsigned short* __restrict__ H0,
    unsigned short* __restrict__ L0, int K0, int N0, int T0,
    const float* __restrict__ W1, unsigned short* __restrict__ H1,
    unsigned short* __restrict__ L1, int K1, int N1, int T1,
    const float* __restrict__ W2, unsigned short* __restrict__ H2,
    unsigned short* __restrict__ L2, int K2, int N2, int T2)
{
    __shared__ float Ls[64][65];
    int bx = blockIdx.x;
    const float* W; unsigned short* H; unsigned short* L; int K, N;
    if (bx < T0)           { W = W0; H = H0; L = L0; K = K0; N = N0; }
    else if (bx < T0 + T1) { bx -= T0; W = W1; H = H1; L = L1; K = K1; N = N1; }
    else                   { bx -= T0 + T1; W = W2; H = H2; L = L2; K = K2; N = N2; }

    const int NT = N >> 6;
    const int kt = bx / NT, nt = bx - kt * NT;
    const int k0 = kt * 64, n0 = nt * 64;
    const int tid = threadIdx.x;
    const int r = tid >> 2, c = (tid & 3) * 16;

#pragma unroll
    for (int i = 0; i < 4; i++)
        *(float4*)&Ls[r][c + i * 4] =
            *(const float4*)&W[(size_t)(k0 + r) * N + n0 + c + i * 4];
    __syncthreads();

    const int nr = tid >> 2, kc = (tid & 3) * 16;
    unsigned short hb[16], lb[16];
#pragma unroll
    for (int j = 0; j < 16; j++) {
        float v = Ls[kc + j][nr];
        unsigned short h = f2bf_rn(v);
        hb[j] = h;
        lb[j] = f2bf_rn(v - bf2f(h));
    }
    size_t ob = (size_t)(n0 + nr) * K + k0 + kc;
    *(float4*)&H[ob]     = ((float4*)hb)[0];
    *(float4*)&H[ob + 8] = ((float4*)hb)[1];
    *(float4*)&L[ob]     = ((float4*)lb)[0];
    *(float4*)&L[ob + 8] = ((float4*)lb)[1];
}

// ---------------------------------------------------------------------------
// Activation split: A f32 -> H, L bf16.
// ---------------------------------------------------------------------------
__global__ __launch_bounds__(256) void aconv(
    const float* __restrict__ A, unsigned short* __restrict__ H,
    unsigned short* __restrict__ L)
{
    int i = (blockIdx.x * 256 + threadIdx.x) * 8;
    float4 v0 = *(const float4*)&A[i];
    float4 v1 = *(const float4*)&A[i + 4];
    float vv[8] = {v0.x, v0.y, v0.z, v0.w, v1.x, v1.y, v1.z, v1.w};
    unsigned short hb[8], lb[8];
#pragma unroll
    for (int j = 0; j < 8; j++) {
        unsigned short h = f2bf_rn(vv[j]);
        hb[j] = h;
        lb[j] = f2bf_rn(vv[j] - bf2f(h));
    }
    *(float4*)&H[i] = *(float4*)hb;
    *(float4*)&L[i] = *(float4*)lb;
}

// ---------------------------------------------------------------------------
// bf16x3 MFMA GEMM (unchanged from R10).
// ---------------------------------------------------------------------------
__global__ __launch_bounds__(128) void gemm_bt(
    const unsigned short* __restrict__ Ah0, const unsigned short* __restrict__ Al0,
    const unsigned short* __restrict__ Bh0, const unsigned short* __restrict__ Bl0,
    float* __restrict__ C0, int K0, int N0, int T0,
    const unsigned short* __restrict__ Ah1, const unsigned short* __restrict__ Al1,
    const unsigned short* __restrict__ Bh1, const unsigned short* __restrict__ Bl1,
    float* __restrict__ C1, int K1, int N1, int T1,
    const unsigned short* __restrict__ Ah2, const unsigned short* __restrict__ Al2,
    const unsigned short* __restrict__ Bh2, const unsigned short* __restrict__ Bl2,
    float* __restrict__ C2, int K2, int N2, int T2)
{
    __shared__ unsigned short Ahs[64 * 40], Als[64 * 40];
    __shared__ unsigned short Bhs[64 * 40], Bls[64 * 40];

    int bx = blockIdx.x;
    const unsigned short *Ah, *Al, *Bh, *Bl; float* C; int K, N;
    if (bx < T0) {
        Ah = Ah0; Al = Al0; Bh = Bh0; Bl = Bl0; C = C0; K = K0; N = N0;
    } else if (bx < T0 + T1) {
        bx -= T0; Ah = Ah1; Al = Al1; Bh = Bh1; Bl = Bl1; C = C1; K = K1; N = N1;
    } else {
        bx -= T0 + T1; Ah = Ah2; Al = Al2; Bh = Bh2; Bl = Bl2; C = C2; K = K2; N = N2;
    }

    const int tid = threadIdx.x;
    const int w = tid >> 6, l = tid & 63;
    const int q = l >> 4, m16 = l & 15;
    const int bm = blockIdx.y * 64, bn = bx * 64;

    const int c0i = tid * 2, c1i = tid * 2 + 1;
    const int r0 = c0i >> 2, o0 = (c0i & 3) * 8;
    const int r1 = c1i >> 2, o1 = (c1i & 3) * 8;
    const unsigned short* pAh0 = Ah + (size_t)(bm + r0) * K + o0;
    const unsigned short* pAh1 = Ah + (size_t)(bm + r1) * K + o1;
    const unsigned short* pAl0 = Al + (size_t)(bm + r0) * K + o0;
    const unsigned short* pAl1 = Al + (size_t)(bm + r1) * K + o1;
    const unsigned short* pBh0 = Bh + (size_t)(bn + r0) * K + o0;
    const unsigned short* pBh1 = Bh + (size_t)(bn + r1) * K + o1;
    const unsigned short* pBl0 = Bl + (size_t)(bn + r0) * K + o0;
    const unsigned short* pBl1 = Bl + (size_t)(bn + r1) * K + o1;

    f32x4 acc[2][4];
#pragma unroll
    for (int i = 0; i < 2; i++)
#pragma unroll
        for (int j = 0; j < 4; j++)
            acc[i][j] = (f32x4){0.f, 0.f, 0.f, 0.f};

    float4 vAh0 = *(const float4*)pAh0, vAh1 = *(const float4*)pAh1;
    float4 vAl0 = *(const float4*)pAl0, vAl1 = *(const float4*)pAl1;
    float4 vBh0 = *(const float4*)pBh0, vBh1 = *(const float4*)pBh1;
    float4 vBl0 = *(const float4*)pBl0, vBl1 = *(const float4*)pBl1;

    for (int k0 = 0;; k0 += 32) {
        __syncthreads();
        *(float4*)&Ahs[r0 * 40 + o0] = vAh0; *(float4*)&Ahs[r1 * 40 + o1] = vAh1;
        *(float4*)&Als[r0 * 40 + o0] = vAl0; *(float4*)&Als[r1 * 40 + o1] = vAl1;
        *(float4*)&Bhs[r0 * 40 + o0] = vBh0; *(float4*)&Bhs[r1 * 40 + o1] = vBh1;
        *(float4*)&Bls[r0 * 40 + o0] = vBl0; *(float4*)&Bls[r1 * 40 + o1] = vBl1;
        __syncthreads();

        const bool more = (k0 + 32) < K;
        if (more) {
            const int kn = k0 + 32;
            vAh0 = *(const float4*)(pAh0 + kn); vAh1 = *(const float4*)(pAh1 + kn);
            vAl0 = *(const float4*)(pAl0 + kn); vAl1 = *(const float4*)(pAl1 + kn);
            vBh0 = *(const float4*)(pBh0 + kn); vBh1 = *(const float4*)(pBh1 + kn);
            vBl0 = *(const float4*)(pBl0 + kn); vBl1 = *(const float4*)(pBl1 + kn);
        }

        short8 fah[2], fal[2], fbh[4], fbl[4];
#pragma unroll
        for (int mt = 0; mt < 2; mt++) {
            const int row = w * 32 + mt * 16 + m16;
            fah[mt] = *(const short8*)&Ahs[row * 40 + q * 8];
            fal[mt] = *(const short8*)&Als[row * 40 + q * 8];
        }
#pragma unroll
        for (int nt = 0; nt < 4; nt++) {
            const int row = nt * 16 + m16;
            fbh[nt] = *(const short8*)&Bhs[row * 40 + q * 8];
            fbl[nt] = *(const short8*)&Bls[row * 40 + q * 8];
        }
#pragma unroll
        for (int mt = 0; mt < 2; mt++)
#pragma unroll
            for (int nt = 0; nt < 4; nt++) {
                acc[mt][nt] = __builtin_amdgcn_mfma_f32_16x16x32_bf16(
                    fah[mt], fbh[nt], acc[mt][nt], 0, 0, 0);
                acc[mt][nt] = __builtin_amdgcn_mfma_f32_16x16x32_bf16(
                    fah[mt], fbl[nt], acc[mt][nt], 0, 0, 0);
                acc[mt][nt] = __builtin_amdgcn_mfma_f32_16x16x32_bf16(
                    fal[mt], fbh[nt], acc[mt][nt], 0, 0, 0);
            }
        if (!more) break;
    }

#pragma unroll
    for (int mt = 0; mt < 2; mt++)
#pragma unroll
        for (int nt = 0; nt < 4; nt++) {
            const int mrow = bm + w * 32 + mt * 16 + q * 4;
            const int ncol = bn + nt * 16 + m16;
#pragma unroll
            for (int r = 0; r < 4; r++)
                C[(size_t)(mrow + r) * N + ncol] = acc[mt][nt][r];
        }
}

// ---------------------------------------------------------------------------
// RMSNorm rows -> bf16 hi/lo outputs
// ---------------------------------------------------------------------------
__global__ __launch_bounds__(256) void rmsnorm_bf(
    const float* __restrict__ in, int in_stride, const float* __restrict__ w,
    unsigned short* __restrict__ oh, unsigned short* __restrict__ ol,
    int ncols, float inv_n)
{
    const int t = blockIdx.x;
    const int tid = threadIdx.x;
    const float* row = in + (size_t)t * in_stride;
    float ss = 0.f;
    for (int c = tid; c < ncols; c += 256) { float v = row[c]; ss += v * v; }
#pragma unroll
    for (int m = 1; m < 64; m <<= 1) ss += __shfl_xor(ss, m);
    __shared__ float red[4];
    if ((tid & 63) == 0) red[tid >> 6] = ss;
    __syncthreads();
    float tot = red[0] + red[1] + red[2] + red[3];
    float scale = rsqrtf(tot * inv_n + 1e-5f);
    for (int c = tid; c < ncols; c += 256) {
        float v = row[c] * scale * w[c];
        unsigned short h = f2bf_rn(v);
        oh[(size_t)t * ncols + c] = h;
        ol[(size_t)t * ncols + c] = f2bf_rn(v - bf2f(h));
    }
}

// ---------------------------------------------------------------------------
// la = log_sigmoid(gpre + bias), HEAD-MAJOR: la_h[h][t][192]
// ---------------------------------------------------------------------------
__global__ __launch_bounds__(256) void logsig_relayout(
    const float* __restrict__ g, const float* __restrict__ bias,
    float* __restrict__ la_h)
{
    int i = blockIdx.x * 256 + threadIdx.x;   // < TT*HDK
    int t = i / HDK, col = i - t * HDK;
    int h = col / DK, d = col - h * DK;
    float z = g[i] + bias[col];
    float la = fminf(z, 0.f) - log1pf(__expf(-fabsf(z)));
    la_h[((size_t)h * TT + t) * DK + d] = la;
}

// ---------------------------------------------------------------------------
__global__ __launch_bounds__(256) void beta_kernel(
    const float* __restrict__ x, const float* __restrict__ wb,
    float* __restrict__ beta)
{
    const int lane = threadIdx.x & 63, wv = threadIdx.x >> 6;
    const int p = blockIdx.x * 4 + wv;        // p = t*8 + h
    const int t = p >> 3, h = p & 7;
    const float* xr = x + (size_t)t * DIM;
    float s = 0.f;
    for (int e = lane; e < DIM; e += 64) s += xr[e] * wb[e * HH + h];
#pragma unroll
    for (int m = 1; m < 64; m <<= 1) s += __shfl_xor(s, m);
    if (lane == 0) beta[p] = 1.f / (1.f + expf(-s));
}

// ---------------------------------------------------------------------------
// l2norm(q)*DK^-0.5 and build+l2norm k; outputs HEAD-MAJOR [h][t][192].
// ---------------------------------------------------------------------------
__global__ __launch_bounds__(256) void prep_qk(
    const float* __restrict__ qraw, const float* __restrict__ kvb,
    const float* __restrict__ kv_all, float* __restrict__ q_h,
    float* __restrict__ k_h)
{
    const int lane = threadIdx.x & 63, wv = threadIdx.x >> 6;
    const int p = blockIdx.x * 4 + wv;
    const int t = p >> 3, h = p & 7;

    const float* qrow = qraw + (size_t)t * HDK + h * DK;
    float q0 = qrow[lane], q1 = qrow[lane + 64], q2 = qrow[lane + 128];
    float ss = q0 * q0 + q1 * q1 + q2 * q2;
#pragma unroll
    for (int m = 1; m < 64; m <<= 1) ss += __shfl_xor(ss, m);
    float sc = rsqrtf(ss + 1e-6f) * 0.07216878364870323f;  // * DK^-0.5
    float* qo = q_h + ((size_t)h * TT + t) * DK;
    qo[lane] = q0 * sc; qo[lane + 64] = q1 * sc; qo[lane + 128] = q2 * sc;

    const float* knope = kvb + (size_t)t * HKV + h * (DNOPE + DV);
    float k0 = knope[lane], k1 = knope[lane + 64];
    float k2 = kv_all[(size_t)t * (KVLR + DROPE) + KVLR + lane];
    float ks = k0 * k0 + k1 * k1 + k2 * k2;
#pragma unroll
    for (int m = 1; m < 64; m <<= 1) ks += __shfl_xor(ks, m);
    float kc = rsqrtf(ks + 1e-6f);
    float* ko = k_h + ((size_t)h * TT + t) * DK;
    ko[lane] = k0 * kc; ko[lane + 64] = k1 * kc; ko[lane + 128] = k2 * kc;
}

// ---------------------------------------------------------------------------
__device__ __forceinline__ float dpp_xor1(float x) {
    return __int_as_float(__builtin_amdgcn_update_dpp(
        0, __float_as_int(x), 0xB1, 0xF, 0xF, false));
}
__device__ __forceinline__ float dpp_xor2(float x) {
    return __int_as_float(__builtin_amdgcn_update_dpp(
        0, __float_as_int(x), 0x4E, 0xF, 0xF, false));
}
__device__ __forceinline__ float red16(float x) {
    x += dpp_xor1(x);
    x += dpp_xor2(x);
    x += __int_as_float(__builtin_amdgcn_update_dpp(0, __float_as_int(x), 0x141, 0xF, 0xF, false));
    x += __int_as_float(__builtin_amdgcn_update_dpp(0, __float_as_int(x), 0x140, 0xF, 0xF, false));
    return x;
}

__device__ __forceinline__ void gl_lds16(const float* g, float* l) {
    __builtin_amdgcn_global_load_lds(
        (const __attribute__((address_space(1))) void*)g,
        (__attribute__((address_space(3))) void*)l, 16, 0, 0);
}
__device__ __forceinline__ void gl_lds4(const float* g, float* l) {
    __builtin_amdgcn_global_load_lds(
        (const __attribute__((address_space(1))) void*)g,
        (__attribute__((address_space(3))) void*)l, 4, 0, 0);
}

// ---------------------------------------------------------------------------
// Phase A: per-(chunk,head) S-independent quantities (unchanged).
// ---------------------------------------------------------------------------
__global__ __launch_bounds__(256) void chunk_prep(
    const float* __restrict__ k_h, const float* __restrict__ la_h,
    const float* __restrict__ q_h, const float* __restrict__ kvb,
    const float* __restrict__ betab, float* __restrict__ pa)
{
    __shared__ float Ls[16][196];
    __shared__ float Ks[16][196];
    __shared__ float Qs[16][196];
    __shared__ float Ws[16][196];
    __shared__ float Xs[16][196];
    __shared__ float Ms[16][16];
    __shared__ float bs[16];

    const int tid = threadIdx.x;
    const int n = blockIdx.x >> 3, h = blockIdx.x & 7;
    const size_t g0 = ((size_t)h * TT + n * 16) * DK;
    float* blob = pa + (size_t)blockIdx.x * PABLK;

#pragma unroll
    for (int s = 0; s < 3; s++) {
        int off = (tid * 3 + s) * 4;
        int r = off / 192, c = off - r * 192;
        *(float4*)&Ks[r][c] = *(const float4*)(k_h + g0 + off);
        *(float4*)&Ls[r][c] = *(const float4*)(la_h + g0 + off);
        *(float4*)&Qs[r][c] = *(const float4*)(q_h + g0 + off);
    }
    if (tid < 16) bs[tid] = betab[(size_t)(n * 16 + tid) * HH + h];
    __syncthreads();

    if (tid < 192) {
        float g = 0.f;
#pragma unroll
        for (int i = 0; i < 16; i++) { g += Ls[i][tid]; Ls[i][tid] = g; }
    }
    __syncthreads();

#pragma unroll
    for (int s = 0; s < 12; s++) {
        int idx = s * 256 + tid;
        int i = idx / 192, d = idx - i * 192;
        float G = Ls[i][d];
        float eg = __expf(G), en = __expf(-G);
        float kk = Ks[i][d];
        Ws[i][d] = bs[i] * kk * eg;
        Qs[i][d] *= eg;
        Ks[i][d] = kk * en;
    }
    __syncthreads();

#pragma unroll
    for (int s = 0; s < 3; s++) {
        int off = (tid * 3 + s) * 4;
        int r = off / 192, c = off - r * 192;
        *(float4*)(blob + OQ + off) = *(const float4*)&Qs[r][c];
    }
    if (tid < 192) {
        float lam = __expf(Ls[15][tid]);
        blob[OLAM + tid] = lam;
#pragma unroll
        for (int j4 = 0; j4 < 4; j4++) {
            float4 v;
            v.x = Ks[j4 * 4 + 0][tid] * lam; v.y = Ks[j4 * 4 + 1][tid] * lam;
            v.z = Ks[j4 * 4 + 2][tid] * lam; v.w = Ks[j4 * 4 + 3][tid] * lam;
            *(float4*)(blob + OC + tid * 20 + j4 * 4) = v;
        }
        blob[OC + tid * 20 + 16] = 0.f; blob[OC + tid * 20 + 17] = 0.f;
        blob[OC + tid * 20 + 18] = 0.f; blob[OC + tid * 20 + 19] = 0.f;
    }
    {
        const int i = tid >> 4, j = tid & 15;
        float m = 0.f, p = 0.f;
#pragma unroll
        for (int d4 = 0; d4 < 48; d4++) {
            float4 w  = *(const float4*)&Ws[i][d4 * 4];
            float4 ka = *(const float4*)&Ks[j][d4 * 4];
            float4 qa = *(const float4*)&Qs[i][d4 * 4];
            m += w.x * ka.x + w.y * ka.y + w.z * ka.z + w.w * ka.w;
            p += qa.x * ka.x + qa.y * ka.y + qa.z * ka.z + qa.w * ka.w;
        }
        Ms[i][j] = (j < i) ? m : 0.f;
        blob[OPL + tid] = (j <= i) ? p : 0.f;
    }
    __syncthreads();

    float y[16], uu[16];
    const bool doY = (tid < 192);
    const bool doU = (tid >= 128);
    const int dcol = tid, ccol = tid - 128;
    if (doY) {
#pragma unroll
        for (int i = 0; i < 16; i++) y[i] = Ws[i][dcol];
#pragma unroll
        for (int i = 1; i < 16; i++)
#pragma unroll
            for (int j = 0; j < i; j++)
                y[i] = fmaf(-Ms[i][j], y[j], y[i]);
    }
    if (doU) {
#pragma unroll
        for (int i = 0; i < 16; i++)
            uu[i] = bs[i] * kvb[(size_t)(n * 16 + i) * HKV + h * (DNOPE + DV) + DNOPE + ccol];
#pragma unroll
        for (int i = 1; i < 16; i++)
#pragma unroll
            for (int j = 0; j < i; j++)
                uu[i] = fmaf(-Ms[i][j], uu[j], uu[i]);
    }
    if (doY) {
#pragma unroll
        for (int i = 0; i < 16; i++) Xs[i][dcol] = y[i];
    }
    __syncthreads();
#pragma unroll
    for (int s = 0; s < 3; s++) {
        int off = (tid * 3 + s) * 4;
        int r = off / 192, c = off - r * 192;
        *(float4*)(blob + OY + off) = *(const float4*)&Xs[r][c];
    }
    __syncthreads();
    if (doU) {
#pragma unroll
        for (int i = 0; i < 16; i++) Xs[i][ccol] = uu[i];
    }
    __syncthreads();
#pragma unroll
    for (int s = 0; s < 2; s++) {
        int off = (tid * 2 + s) * 4;
        int r = off / 128, c = off - r * 128;
        *(float4*)(blob + OU + off) = *(const float4*)&Xs[r][c];
    }
}

// ---------------------------------------------------------------------------
// Phase B v3: TRIPLE-buffered staging issued right after barrier A (so the
// vmcnt(0) drain at the next barrier hits loads issued a full phase earlier),
// barrier C removed (3 buffers -> staging never overwrites a live buffer;
// barrier A orders Ss-update and us-overwrite). 2 barriers/chunk.
// ---------------------------------------------------------------------------
__global__ __launch_bounds__(256) void kda_chunk(
    const float* __restrict__ pa, unsigned short* __restrict__ obh,
    unsigned short* __restrict__ obl)
{
    __shared__ float Yb[3][3136];
    __shared__ float Qb[3][3136];
    __shared__ float Cb[3][3840];
    __shared__ float Pb[3][256];
    __shared__ float ubs[3][64];
    __shared__ float lbs[3][192];
    __shared__ float Ss[784];
    __shared__ float us[80];

    const int tid = threadIdx.x;
    const int w = tid >> 6, lane = tid & 63;
    const int h = blockIdx.x >> 5, cg = blockIdx.x & 31;
    const int c0 = cg * 4;

    const int dg  = tid & 15;
    const int ccg = (tid >> 4) & 1;
    const int tig = tid >> 5;

    auto stage = [&](int buf, int n) {
        const float* blob = pa + (size_t)(n * 8 + h) * PABLK;
        if (w == 0) {
            if (lane < 48)
#pragma unroll
                for (int r = 0; r < 16; r++)
                    gl_lds16(blob + OY + r * 192 + lane * 4, &Yb[buf][r * 196]);
        } else if (w == 1) {
            if (lane < 48)
#pragma unroll
                for (int r = 0; r < 16; r++)
                    gl_lds16(blob + OQ + r * 192 + lane * 4, &Qb[buf][r * 196]);
        } else if (w == 2) {
#pragma unroll
            for (int s = 0; s < 15; s++)
                gl_lds16(blob + OC + s * 256 + lane * 4, &Cb[buf][s * 256]);
        } else {
            gl_lds16(blob + OPL + lane * 4, &Pb[buf][0]);
            gl_lds4(blob + OU + (lane >> 2) * 128 + c0 + (lane & 3), &ubs[buf][0]);
            if (lane < 48)
                gl_lds16(blob + OLAM + lane * 4, &lbs[buf][0]);
        }
    };

    for (int idx = tid; idx < 784; idx += 256) Ss[idx] = 0.f;
    stage(0, 0);
    stage(1, 1);

    const int c2 = tid & 3, dseg = tid >> 2;

    int buf = 0;
    for (int n = 0; n < TT / 16; n++) {
        __syncthreads();   // A: buf resident (drained >=1 barrier ago), Ss vis.

        // issue NEXT+1 staging now -> a full phase of slack before any drain
        if (n + 2 < TT / 16) {
            int b2 = buf + 2; if (b2 >= 3) b2 -= 3;
            stage(b2, n + 2);
        }

        const int dbase = dg * 12;
        float4 sv[2][3];
#pragma unroll
        for (int j = 0; j < 2; j++)
#pragma unroll
            for (int s = 0; s < 3; s++)
                sv[j][s] = *(const float4*)&Ss[(ccg * 2 + j) * 196 + dbase + s * 4];

        float py[2][2] = {{0.f, 0.f}, {0.f, 0.f}};
        float pq[2][2] = {{0.f, 0.f}, {0.f, 0.f}};
#pragma unroll
        for (int i = 0; i < 2; i++) {
            const float* Yr = &Yb[buf][(tig * 2 + i) * 196 + dbase];
            const float* Qr = &Qb[buf][(tig * 2 + i) * 196 + dbase];
#pragma unroll
            for (int s = 0; s < 3; s++) {
                float4 yv = *(const float4*)(Yr + s * 4);
                float4 qv = *(const float4*)(Qr + s * 4);
#pragma unroll
                for (int j = 0; j < 2; j++) {
                    float4 s4 = sv[j][s];
                    py[i][j] = fmaf(yv.x, s4.x, py[i][j]);
                    py[i][j] = fmaf(yv.y, s4.y, py[i][j]);
                    py[i][j] = fmaf(yv.z, s4.z, py[i][j]);
                    py[i][j] = fmaf(yv.w, s4.w, py[i][j]);
                    pq[i][j] = fmaf(qv.x, s4.x, pq[i][j]);
                    pq[i][j] = fmaf(qv.y, s4.y, pq[i][j]);
                    pq[i][j] = fmaf(qv.z, s4.z, pq[i][j]);
                    pq[i][j] = fmaf(qv.w, s4.w, pq[i][j]);
                }
            }
        }
        float zy[2][2], zq[2][2];
#pragma unroll
        for (int i = 0; i < 2; i++)
#pragma unroll
            for (int j = 0; j < 2; j++) {
                zy[i][j] = red16(py[i][j]);
                zq[i][j] = red16(pq[i][j]);
            }

        float uv[2][2];
#pragma unroll
        for (int i = 0; i < 2; i++)
#pragma unroll
            for (int j = 0; j < 2; j++)
                uv[i][j] = ubs[buf][(tig * 2 + i) * 4 + (ccg * 2 + j)] - zy[i][j];
        {
            const int m = dg >> 2;
            if ((dg & 3) == 0) {
                const int ii = m >> 1, jj = m & 1;
                float val = (m == 0) ? uv[0][0] : (m == 1) ? uv[0][1]
                          : (m == 2) ? uv[1][0] : uv[1][1];
                us[(ccg * 2 + jj) * 20 + (tig * 2 + ii)] = val;
            }
        }
        __syncthreads();   // B: us ready

        {
            const int m = dg >> 2, qtr = dg & 3;
            const int ii = m >> 1, jj = m & 1;
            const int ti = tig * 2 + ii, cc = ccg * 2 + jj;
            float acc = 0.f;
            for (int j = qtr; j <= ti; j += 4)
                acc = fmaf(Pb[buf][ti * 16 + j], us[cc * 20 + j], acc);
            acc += dpp_xor1(acc);
            acc += dpp_xor2(acc);
            if (qtr == 0) {
                float zqv = (m == 0) ? zq[0][0] : (m == 1) ? zq[0][1]
                          : (m == 2) ? zq[1][0] : zq[1][1];
                float ov = zqv + acc;
                if (isnan(ov)) ov = 0.f;
                else if (isinf(ov)) ov = ov > 0.f ? 1e4f : -1e4f;
                size_t oi = (size_t)(n * 16 + ti) * (HH * DV) + h * DV + c0 + cc;
                unsigned short hb = f2bf_rn(ov);
                obh[oi] = hb;
                obl[oi] = f2bf_rn(ov - bf2f(hb));
            }
        }

        const float4* up = (const float4*)&us[c2 * 20];
        float4 u0 = up[0], u1 = up[1], u2v = up[2], u3 = up[3];
#pragma unroll
        for (int s = 0; s < 3; s++) {
            int d = dseg * 3 + s;
            float svv = Ss[c2 * 196 + d];
            float a2 = lbs[buf][d] * svv;
            const float4* C4 = (const float4*)&Cb[buf][d * 20];
            float4 k0 = C4[0], k1 = C4[1], k2 = C4[2], k3 = C4[3];
            a2 = fmaf(k0.x, u0.x,  a2); a2 = fmaf(k0.y, u0.y,  a2);
            a2 = fmaf(k0.z, u0.z,  a2); a2 = fmaf(k0.w, u0.w,  a2);
            a2 = fmaf(k1.x, u1.x,  a2); a2 = fmaf(k1.y, u1.y,  a2);
            a2 = fmaf(k1.z, u1.z,  a2); a2 = fmaf(k1.w, u1.w,  a2);
            a2 = fmaf(k2.x, u2v.x, a2); a2 = fmaf(k2.y, u2v.y, a2);
            a2 = fmaf(k2.z, u2v.z, a2); a2 = fmaf(k2.w, u2v.w, a2);
            a2 = fmaf(k3.x, u3.x,  a2); a2 = fmaf(k3.y, u3.y,  a2);
            a2 = fmaf(k3.z, u3.z,  a2); a2 = fmaf(k3.w, u3.w,  a2);
            Ss[c2 * 196 + d] = a2;
        }
        // no barrier C: next iteration's barrier A orders everything
        buf = (buf + 1 == 3) ? 0 : buf + 1;
    }
}

// ---------------------------------------------------------------------------
extern "C" void kernel_launch(void* const* d_in, const int* in_sizes, int n_in,
                              void* d_out, int out_size, void* d_ws, size_t ws_size,
                              hipStream_t stream)
{
    const float* x         = (const float*)d_in[0];
    // d_in[1] = cos, d_in[2] = sin : unused by the reference
    const float* wq_a      = (const float*)d_in[3];
    const float* q_norm_w  = (const float*)d_in[4];
    const float* wq_b      = (const float*)d_in[5];
    const float* wkv_a     = (const float*)d_in[6];
    const float* kv_norm_w = (const float*)d_in[7];
    const float* wkv_b     = (const float*)d_in[8];
    const float* wg_w      = (const float*)d_in[9];
    const float* wg_b      = (const float*)d_in[10];
    const float* wb        = (const float*)d_in[11];
    const float* wo        = (const float*)d_in[12];
    float* out = (float*)d_out;

    float* ws = (float*)d_ws;
    float* xq     = ws;                        // T x 768 (f32, gemm1 out)
    float* kv_all = xq     + TT * QLR;         // T x 576
    float* agraw  = kv_all + TT * (KVLR + DROPE); // T x 1536 (dead after logsig)
    float* qnraw  = agraw  + TT * HDK;         // T x 1536
    float* kvb    = qnraw  + TT * HDK;         // T x 2048
    float* la_h   = kvb    + TT * HKV;         // 8 x 1024 x 192
    float* q_h    = la_h   + TT * HDK;
    float* k_h    = q_h    + TT * HDK;
    float* betab  = k_h    + TT * HDK;         // T x 8
    float* pa     = betab  + TT * HH;          // 512 x PABLK (25.6 MB)
    float* tail   = pa     + 512 * PABLK;

    unsigned short* wo_h  = (unsigned short*)tail;          // 1024*1024
    unsigned short* wo_l  = wo_h  + 1048576;
    unsigned short* xh    = wo_l  + 1048576;                // 1024*1024
    unsigned short* xl    = xh    + 1048576;
    unsigned short* xqh   = xl    + 1048576;                // 1024*768
    unsigned short* xql   = xqh   + 786432;
    unsigned short* kvnh  = xql   + 786432;                 // 1024*512
    unsigned short* kvnl  = kvnh  + 524288;

    unsigned short* wqa_h  = (unsigned short*)pa;           // 768n x 1024k
    unsigned short* wqa_l  = wqa_h  + 786432;
    unsigned short* wkva_h = wqa_l  + 786432;               // 576n x 1024k
    unsigned short* wkva_l = wkva_h + 589824;
    unsigned short* wgw_h  = wkva_l + 589824;               // 1536n x 1024k
    unsigned short* wgw_l  = wgw_h  + 1572864;
    unsigned short* wqb_h  = wgw_l  + 1572864;              // 1536n x 768k
    unsigned short* wqb_l  = wqb_h  + 1179648;
    unsigned short* wkvb_h = wqb_l  + 1179648;              // 2048n x 512k
    unsigned short* wkvb_l = wkvb_h + 1048576;

    unsigned short* obh = (unsigned short*)agraw;           // 1024*1024
    unsigned short* obl = obh + 1048576;

    dim3 blk(256);

    wconv<<<dim3(192 + 144 + 384), blk, 0, stream>>>(
        wq_a, wqa_h, wqa_l, DIM, QLR, 192,
        wkv_a, wkva_h, wkva_l, DIM, KVLR + DROPE, 144,
        wg_w, wgw_h, wgw_l, DIM, HDK, 384);
    wconv<<<dim3(288 + 256 + 256), blk, 0, stream>>>(
        wq_b, wqb_h, wqb_l, QLR, HDK, 288,
        wkv_b, wkvb_h, wkvb_l, KVLR, HKV, 256,
        wo, wo_h, wo_l, DIM, DIM, 256);

    aconv<<<dim3(TT * DIM / (256 * 8)), blk, 0, stream>>>(x, xh, xl);

    gemm_bt<<<dim3(12 + 9 + 24, 16), dim3(128), 0, stream>>>(
        xh, xl, wqa_h, wqa_l, xq, DIM, QLR, 12,
        xh, xl, wkva_h, wkva_l, kv_all, DIM, KVLR + DROPE, 9,
        xh, xl, wgw_h, wgw_l, agraw, DIM, HDK, 24);

    rmsnorm_bf<<<TT, blk, 0, stream>>>(xq, QLR, q_norm_w, xqh, xql, QLR, 1.f / QLR);
    rmsnorm_bf<<<TT, blk, 0, stream>>>(kv_all, KVLR + DROPE, kv_norm_w, kvnh, kvnl, KVLR, 1.f / KVLR);

    gemm_bt<<<dim3(24 + 32, 16), dim3(128), 0, stream>>>(
        xqh, xql, wqb_h, wqb_l, qnraw, QLR, HDK, 24,
        kvnh, kvnl, wkvb_h, wkvb_l, kvb, KVLR, HKV, 32,
        xh, xl, wqa_h, wqa_l, xq, DIM, QLR, 0);

    logsig_relayout<<<(TT * HDK + 255) / 256, blk, 0, stream>>>(agraw, wg_b, la_h);
    beta_kernel<<<TT * HH / 4, blk, 0, stream>>>(x, wb, betab);

    prep_qk<<<TT * HH / 4, blk, 0, stream>>>(qnraw, kvb, kv_all, q_h, k_h);

    chunk_prep<<<512, blk, 0, stream>>>(k_h, la_h, q_h, kvb, betab, pa);
    kda_chunk<<<256, blk, 0, stream>>>(pa, obh, obl);

    gemm_bt<<<dim3(16, 16), dim3(128), 0, stream>>>(
        obh, obl, wo_h, wo_l, out, DIM, DIM, 16,
        xh, xl, wqa_h, wqa_l, xq, DIM, QLR, 0,
        xh, xl, wqa_h, wqa_l, xq, DIM, QLR, 0);
}